// Round 1
// baseline (999.799 us; speedup 1.0000x reference)
//
#include <hip/hip_runtime.h>
#include <math.h>

#define NN 50000
#define NE 400000
#define NG 128

// ---------------------------------------------------------------------------
// prep: fused weights  Wp1[64,128] (c=h*16+d) = sum_j Wq1[m,h*16+j]*We1[d,h*16+j]
//       bp1[128],  Wp2[128,16],  bp2[16]
// ---------------------------------------------------------------------------
__global__ void prep_kernel(const float* __restrict__ Wq1, const float* __restrict__ bq1,
                            const float* __restrict__ We1,
                            const float* __restrict__ Wq2, const float* __restrict__ bq2,
                            const float* __restrict__ We2,
                            float* __restrict__ Wp1, float* __restrict__ bp1,
                            float* __restrict__ Wp2, float* __restrict__ bp2)
{
    int idx = blockIdx.x * blockDim.x + threadIdx.x;
    if (idx < 64 * 128) {
        int m = idx >> 7, c = idx & 127;
        int h = c >> 4, d = c & 15;
        float s = 0.f;
        #pragma unroll
        for (int j = 0; j < 16; ++j)
            s += Wq1[m * 128 + h * 16 + j] * We1[d * 128 + h * 16 + j];
        Wp1[idx] = s;
    } else if (idx < 64 * 128 + 128) {
        int c = idx - 64 * 128;
        int h = c >> 4, d = c & 15;
        float s = 0.f;
        #pragma unroll
        for (int j = 0; j < 16; ++j)
            s += bq1[h * 16 + j] * We1[d * 128 + h * 16 + j];
        bp1[c] = s;
    } else if (idx < 64 * 128 + 128 + 128 * 16) {
        int i = idx - (64 * 128 + 128);
        int m = i >> 4, d = i & 15;
        float s = 0.f;
        for (int j = 0; j < 128; ++j)
            s += Wq2[m * 128 + j] * We2[d * 128 + j];
        Wp2[m * 16 + d] = s;
    } else if (idx < 64 * 128 + 128 + 128 * 16 + 16) {
        int d = idx - (64 * 128 + 128 + 128 * 16);
        float s = 0.f;
        for (int j = 0; j < 128; ++j)
            s += bq2[j] * We2[d * 128 + j];
        bp2[d] = s;
    }
}

// ---------------------------------------------------------------------------
// CSR build by dst
// ---------------------------------------------------------------------------
__global__ void count_kernel(const int* __restrict__ dst, int* __restrict__ counts)
{
    int e = blockIdx.x * blockDim.x + threadIdx.x;
    if (e < NE) atomicAdd(&counts[dst[e]], 1);
}

__global__ void scan_kernel(const int* __restrict__ counts,
                            int* __restrict__ row_start, int* __restrict__ cursor)
{
    __shared__ int lds[1024];
    int t = threadIdx.x;
    const int CH = (NN + 1023) / 1024;  // 49
    int base = t * CH;
    int s = 0;
    for (int i = 0; i < CH; ++i) {
        int idx = base + i;
        if (idx < NN) s += counts[idx];
    }
    lds[t] = s;
    __syncthreads();
    for (int off = 1; off < 1024; off <<= 1) {
        int v = (t >= off) ? lds[t - off] : 0;
        __syncthreads();
        lds[t] += v;
        __syncthreads();
    }
    int run = (t > 0) ? lds[t - 1] : 0;
    for (int i = 0; i < CH; ++i) {
        int idx = base + i;
        if (idx < NN) {
            row_start[idx] = run;
            cursor[idx] = run;
            run += counts[idx];
        }
    }
    if (t == 0) row_start[NN] = NE;
}

__global__ void scatter_kernel(const int* __restrict__ dst,
                               int* __restrict__ cursor, int* __restrict__ eid)
{
    int e = blockIdx.x * blockDim.x + threadIdx.x;
    if (e < NE) {
        int p = atomicAdd(&cursor[dst[e]], 1);
        eid[p] = e;
    }
}

// ---------------------------------------------------------------------------
// GEMM1: x[N,64] @ [Wq1|Wk1|Wv1|Ws1|Wp1][64,640] + biases -> bufA[N,640]
// ---------------------------------------------------------------------------
__global__ void gemm1_kernel(const float* __restrict__ x,
                             const float* __restrict__ Wq, const float* __restrict__ bq,
                             const float* __restrict__ Wk, const float* __restrict__ bk,
                             const float* __restrict__ Wv, const float* __restrict__ bv,
                             const float* __restrict__ Ws, const float* __restrict__ bs,
                             const float* __restrict__ Wp, const float* __restrict__ bp,
                             float* __restrict__ out)
{
    __shared__ float xs[8][64];
    int t = threadIdx.x;
    int n0 = blockIdx.x * 8;
    for (int i = t; i < 8 * 64; i += 256) {
        int r = i >> 6, c = i & 63;
        int n = n0 + r;
        xs[r][c] = (n < NN) ? x[(size_t)n * 64 + c] : 0.f;
    }
    __syncthreads();
    int c = t & 127, half = t >> 7;
    const float* Wseg[5] = {Wq, Wk, Wv, Ws, Wp};
    const float* Bseg[5] = {bq, bk, bv, bs, bp};
    #pragma unroll
    for (int cb = 0; cb < 5; ++cb) {
        const float* W = Wseg[cb];
        float b = Bseg[cb][c];
        float a0 = b, a1 = b, a2 = b, a3 = b;
        for (int m = 0; m < 64; ++m) {
            float w = W[m * 128 + c];
            a0 += w * xs[half * 4 + 0][m];
            a1 += w * xs[half * 4 + 1][m];
            a2 += w * xs[half * 4 + 2][m];
            a3 += w * xs[half * 4 + 3][m];
        }
        int col = cb * 128 + c;
        int nb = n0 + half * 4;
        if (nb + 0 < NN) out[(size_t)(nb + 0) * 640 + col] = a0;
        if (nb + 1 < NN) out[(size_t)(nb + 1) * 640 + col] = a1;
        if (nb + 2 < NN) out[(size_t)(nb + 2) * 640 + col] = a2;
        if (nb + 3 < NN) out[(size_t)(nb + 3) * 640 + col] = a3;
    }
}

// ---------------------------------------------------------------------------
// agg1: thread per (node, head).  bufA row: [Q|K|V|S|P] stride 640.
// ---------------------------------------------------------------------------
__global__ void agg1_kernel(const float* __restrict__ bufA,
                            const int* __restrict__ row_start, const int* __restrict__ eid,
                            const int* __restrict__ src, const float* __restrict__ ea,
                            const float* __restrict__ We1, float* __restrict__ h1)
{
    int u = blockIdx.x * blockDim.x + threadIdx.x;
    if (u >= NN * 8) return;
    int n = u >> 3, h = u & 7;
    const float* base = bufA + (size_t)n * 640;
    float q[16], P[16];
    #pragma unroll
    for (int j4 = 0; j4 < 4; ++j4) {
        float4 qq = *(const float4*)(base + h * 16 + j4 * 4);
        q[j4 * 4 + 0] = qq.x; q[j4 * 4 + 1] = qq.y; q[j4 * 4 + 2] = qq.z; q[j4 * 4 + 3] = qq.w;
        float4 pp = *(const float4*)(base + 512 + h * 16 + j4 * 4);
        P[j4 * 4 + 0] = pp.x; P[j4 * 4 + 1] = pp.y; P[j4 * 4 + 2] = pp.z; P[j4 * 4 + 3] = pp.w;
    }
    float accv[16], acce[16];
    #pragma unroll
    for (int j = 0; j < 16; ++j) { accv[j] = 0.f; acce[j] = 0.f; }
    float denom = 0.f;
    int e0 = row_start[n], e1 = row_start[n + 1];
    for (int idx = e0; idx < e1; ++idx) {
        int e = eid[idx];
        int s = src[e];
        const float* kb = bufA + (size_t)s * 640 + 128 + h * 16;
        const float* vb = bufA + (size_t)s * 640 + 256 + h * 16;
        const float* eb = ea + (size_t)e * 16;
        float kk[16], vv[16], ee[16];
        #pragma unroll
        for (int j4 = 0; j4 < 4; ++j4) {
            float4 a = *(const float4*)(kb + j4 * 4);
            kk[j4 * 4 + 0] = a.x; kk[j4 * 4 + 1] = a.y; kk[j4 * 4 + 2] = a.z; kk[j4 * 4 + 3] = a.w;
            float4 b = *(const float4*)(vb + j4 * 4);
            vv[j4 * 4 + 0] = b.x; vv[j4 * 4 + 1] = b.y; vv[j4 * 4 + 2] = b.z; vv[j4 * 4 + 3] = b.w;
            float4 cc = *(const float4*)(eb + j4 * 4);
            ee[j4 * 4 + 0] = cc.x; ee[j4 * 4 + 1] = cc.y; ee[j4 * 4 + 2] = cc.z; ee[j4 * 4 + 3] = cc.w;
        }
        float logit = 0.f;
        #pragma unroll
        for (int j = 0; j < 16; ++j) logit += q[j] * kk[j] + P[j] * ee[j];
        logit *= 0.25f;  // 1/sqrt(16)
        float w = expf(logit);
        denom += w;
        #pragma unroll
        for (int j = 0; j < 16; ++j) { accv[j] += w * vv[j]; acce[j] += w * ee[j]; }
    }
    const float* sb = base + 384 + h * 16;
    float inv = (denom > 0.f) ? 1.f / denom : 0.f;
    #pragma unroll
    for (int j = 0; j < 16; ++j) {
        float es = 0.f;
        #pragma unroll
        for (int d = 0; d < 16; ++d) es += acce[d] * We1[d * 128 + h * 16 + j];
        float val = (accv[j] + es) * inv + sb[j];
        h1[(size_t)n * 128 + h * 16 + j] = (val > 0.f) ? val : 0.01f * val;
    }
}

// ---------------------------------------------------------------------------
// GEMM2: h1[N,128] @ [Wq2|Wk2|Wv2|Ws2|Wp2][128,528] + biases -> bufB[N,528]
// ---------------------------------------------------------------------------
__global__ void gemm2_kernel(const float* __restrict__ h1,
                             const float* __restrict__ Wq, const float* __restrict__ bq,
                             const float* __restrict__ Wk, const float* __restrict__ bk,
                             const float* __restrict__ Wv, const float* __restrict__ bv,
                             const float* __restrict__ Ws, const float* __restrict__ bs,
                             const float* __restrict__ Wp2, const float* __restrict__ bp2,
                             float* __restrict__ out)
{
    __shared__ float hs[8][128];
    int t = threadIdx.x;
    int n0 = blockIdx.x * 8;
    for (int i = t; i < 8 * 128; i += 256) {
        int r = i >> 7, c = i & 127;
        int n = n0 + r;
        hs[r][c] = (n < NN) ? h1[(size_t)n * 128 + c] : 0.f;
    }
    __syncthreads();
    int c = t & 127, half = t >> 7;
    const float* Wseg[4] = {Wq, Wk, Wv, Ws};
    const float* Bseg[4] = {bq, bk, bv, bs};
    #pragma unroll
    for (int cb = 0; cb < 4; ++cb) {
        const float* W = Wseg[cb];
        float b = Bseg[cb][c];
        float a0 = b, a1 = b, a2 = b, a3 = b;
        for (int m = 0; m < 128; ++m) {
            float w = W[m * 128 + c];
            a0 += w * hs[half * 4 + 0][m];
            a1 += w * hs[half * 4 + 1][m];
            a2 += w * hs[half * 4 + 2][m];
            a3 += w * hs[half * 4 + 3][m];
        }
        int col = cb * 128 + c;
        int nb = n0 + half * 4;
        if (nb + 0 < NN) out[(size_t)(nb + 0) * 528 + col] = a0;
        if (nb + 1 < NN) out[(size_t)(nb + 1) * 528 + col] = a1;
        if (nb + 2 < NN) out[(size_t)(nb + 2) * 528 + col] = a2;
        if (nb + 3 < NN) out[(size_t)(nb + 3) * 528 + col] = a3;
    }
    if (t < 16) {
        for (int i = 0; i < 8; ++i) {
            int n = n0 + i;
            if (n >= NN) break;
            float acc = bp2[t];
            for (int m = 0; m < 128; ++m) acc += hs[i][m] * Wp2[m * 16 + t];
            out[(size_t)n * 528 + 512 + t] = acc;
        }
    }
}

// ---------------------------------------------------------------------------
// agg2: wave per node; heads=1, dh=128. bufB row: [Q|K|V|S|P2(16)] stride 528.
// ---------------------------------------------------------------------------
__global__ void agg2_kernel(const float* __restrict__ bufB,
                            const int* __restrict__ row_start, const int* __restrict__ eid,
                            const int* __restrict__ src, const float* __restrict__ ea,
                            const float* __restrict__ We2, float* __restrict__ h2)
{
    int wid = (blockIdx.x * blockDim.x + threadIdx.x) >> 6;
    int l = threadIdx.x & 63;
    if (wid >= NN) return;
    int n = wid;
    const float* base = bufB + (size_t)n * 528;
    float q0 = base[l], q1 = base[64 + l];
    float p2 = (l < 16) ? base[512 + l] : 0.f;
    float av0 = 0.f, av1 = 0.f, ae = 0.f, denom = 0.f;
    int e0 = row_start[n], e1 = row_start[n + 1];
    for (int idx = e0; idx < e1; ++idx) {
        int e = eid[idx];
        int s = src[e];
        const float* kb = bufB + (size_t)s * 528;
        float k0 = kb[128 + l], k1 = kb[192 + l];
        float v0 = kb[256 + l], v1 = kb[320 + l];
        float eav = (l < 16) ? ea[(size_t)e * 16 + l] : 0.f;
        float part = q0 * k0 + q1 * k1 + p2 * eav;
        #pragma unroll
        for (int off = 32; off; off >>= 1) part += __shfl_xor(part, off, 64);
        float w = expf(part * 0.08838834764831845f);  // 1/sqrt(128)
        denom += w;
        av0 += w * v0;
        av1 += w * v1;
        ae += w * eav;
    }
    float inv = (denom > 0.f) ? 1.f / denom : 0.f;
    float t0 = 0.f, t1 = 0.f;
    #pragma unroll
    for (int d = 0; d < 16; ++d) {
        float aed = __shfl(ae, d, 64);
        t0 += aed * We2[d * 128 + l];
        t1 += aed * We2[d * 128 + 64 + l];
    }
    float o0 = (av0 + t0) * inv + base[384 + l];
    float o1 = (av1 + t1) * inv + base[448 + l];
    h2[(size_t)n * 128 + l] = o0;
    h2[(size_t)n * 128 + 64 + l] = o1;
}

// ---------------------------------------------------------------------------
// pooling: sorted batch -> register-accumulated flushes
// ---------------------------------------------------------------------------
__global__ void pool_kernel(const float* __restrict__ h2, const int* __restrict__ batch,
                            float* __restrict__ sums, float* __restrict__ cnt)
{
    int t = threadIdx.x;
    int c = t & 127, half = t >> 7;
    int n0 = blockIdx.x * 64;
    float acc = 0.f, cacc = 0.f;
    int curg = -1;
    for (int r = half; r < 64; r += 2) {
        int n = n0 + r;
        if (n >= NN) break;
        int g = batch[n];
        if (g != curg) {
            if (curg >= 0) {
                atomicAdd(&sums[curg * 128 + c], acc);
                if (c == 0) atomicAdd(&cnt[curg], cacc);
            }
            curg = g; acc = 0.f; cacc = 0.f;
        }
        acc += h2[(size_t)n * 128 + c];
        cacc += 1.f;
    }
    if (curg >= 0) {
        atomicAdd(&sums[curg * 128 + c], acc);
        if (c == 0) atomicAdd(&cnt[curg], cacc);
    }
}

// Gp[g,c] = b1[c] + sum_m pool[g,m] * W1[272+m, c]
__global__ void gp_kernel(const float* __restrict__ sums, const float* __restrict__ cnt,
                          const float* __restrict__ W1, const float* __restrict__ b1,
                          float* __restrict__ Gp)
{
    __shared__ float pr[128];
    int g = blockIdx.x, c = threadIdx.x;
    float inv = 1.f / fmaxf(cnt[g], 1.f);
    pr[c] = sums[g * 128 + c] * inv;
    __syncthreads();
    float acc = b1[c];
    for (int m = 0; m < 128; ++m) acc += pr[m] * W1[(272 + m) * 128 + c];
    Gp[g * 128 + c] = acc;
}

// ---------------------------------------------------------------------------
// GEMM3: h2[N,128] @ [W1a|W1b][128,256] -> AB[N,256]
// ---------------------------------------------------------------------------
__global__ void gemm3_kernel(const float* __restrict__ h2, const float* __restrict__ W1,
                             float* __restrict__ AB)
{
    __shared__ float hs[8][128];
    int t = threadIdx.x;
    int n0 = blockIdx.x * 8;
    for (int i = t; i < 8 * 128; i += 256) {
        int r = i >> 7, c = i & 127;
        int n = n0 + r;
        hs[r][c] = (n < NN) ? h2[(size_t)n * 128 + c] : 0.f;
    }
    __syncthreads();
    int seg = t >> 7, cc = t & 127;
    float acc[8];
    #pragma unroll
    for (int i = 0; i < 8; ++i) acc[i] = 0.f;
    for (int m = 0; m < 128; ++m) {
        float w = W1[(size_t)(seg * 128 + m) * 128 + cc];
        #pragma unroll
        for (int i = 0; i < 8; ++i) acc[i] += w * hs[i][m];
    }
    #pragma unroll
    for (int i = 0; i < 8; ++i) {
        int n = n0 + i;
        if (n < NN) AB[(size_t)n * 256 + t] = acc[i];
    }
}

// ---------------------------------------------------------------------------
// final: wave per edge: hid = A[s] + B[d] + Gp[batch[s]] + ea@W1c; relu; dot W2
// ---------------------------------------------------------------------------
__global__ void edge_out_kernel(const float* __restrict__ AB, const float* __restrict__ Gp,
                                const float* __restrict__ ea,
                                const int* __restrict__ src, const int* __restrict__ dst,
                                const int* __restrict__ batch,
                                const float* __restrict__ W1, const float* __restrict__ W2,
                                const float* __restrict__ b2, float* __restrict__ out)
{
    __shared__ float w1c[16 * 128];
    __shared__ float w2s[128];
    int t = threadIdx.x;
    for (int i = t; i < 2048; i += 256) w1c[i] = W1[(size_t)(256 + (i >> 7)) * 128 + (i & 127)];
    if (t < 128) w2s[t] = W2[t];
    __syncthreads();
    int wv = t >> 6, l = t & 63;
    int e = blockIdx.x * 4 + wv;
    if (e >= NE) return;
    int s = src[e], d = dst[e], g = batch[s];
    float h0 = AB[(size_t)s * 256 + l] + AB[(size_t)d * 256 + 128 + l] + Gp[g * 128 + l];
    float h1v = AB[(size_t)s * 256 + 64 + l] + AB[(size_t)d * 256 + 192 + l] + Gp[g * 128 + 64 + l];
    float eal = ea[(size_t)e * 16 + (l & 15)];
    #pragma unroll
    for (int d16 = 0; d16 < 16; ++d16) {
        float ev = __shfl(eal, d16, 64);
        h0 += ev * w1c[d16 * 128 + l];
        h1v += ev * w1c[d16 * 128 + 64 + l];
    }
    h0 = fmaxf(h0, 0.f);
    h1v = fmaxf(h1v, 0.f);
    float r = h0 * w2s[l] + h1v * w2s[64 + l];
    #pragma unroll
    for (int off = 32; off; off >>= 1) r += __shfl_xor(r, off, 64);
    if (l == 0) out[e] = r + b2[0];
}

// ---------------------------------------------------------------------------
extern "C" void kernel_launch(void* const* d_in, const int* in_sizes, int n_in,
                              void* d_out, int out_size, void* d_ws, size_t ws_size,
                              hipStream_t stream)
{
    const float* x   = (const float*)d_in[0];
    const int* ei    = (const int*)d_in[1];
    const float* ea  = (const float*)d_in[2];
    const int* batch = (const int*)d_in[3];
    const float* Wq1 = (const float*)d_in[4];  const float* bq1 = (const float*)d_in[5];
    const float* Wk1 = (const float*)d_in[6];  const float* bk1 = (const float*)d_in[7];
    const float* Wv1 = (const float*)d_in[8];  const float* bv1 = (const float*)d_in[9];
    const float* We1 = (const float*)d_in[10];
    const float* Ws1 = (const float*)d_in[11]; const float* bs1 = (const float*)d_in[12];
    const float* Wq2 = (const float*)d_in[13]; const float* bq2 = (const float*)d_in[14];
    const float* Wk2 = (const float*)d_in[15]; const float* bk2 = (const float*)d_in[16];
    const float* Wv2 = (const float*)d_in[17]; const float* bv2 = (const float*)d_in[18];
    const float* We2 = (const float*)d_in[19];
    const float* Ws2 = (const float*)d_in[20]; const float* bs2 = (const float*)d_in[21];
    const float* W1  = (const float*)d_in[22]; const float* b1  = (const float*)d_in[23];
    const float* W2  = (const float*)d_in[24]; const float* b2  = (const float*)d_in[25];

    const int* src = ei;
    const int* dst = ei + NE;

    float* ws = (float*)d_ws;
    size_t off = 0;
    float* bufA = ws + off; off += (size_t)NN * 640;   // L1 node feats; reused (stride 528) for L2
    float* h1   = ws + off; off += (size_t)NN * 128;
    float* h2   = ws + off; off += (size_t)NN * 128;
    float* AB   = ws + off; off += (size_t)NN * 256;
    float* sums = ws + off; off += NG * 128;
    float* cntf = ws + off; off += NG;
    float* Gp   = ws + off; off += NG * 128;
    float* Wp1  = ws + off; off += 64 * 128;
    float* bp1  = ws + off; off += 128;
    float* Wp2  = ws + off; off += 128 * 16;
    float* bp2  = ws + off; off += 16;
    int* cnt_arr   = (int*)(ws + off); off += NN;
    int* row_start = (int*)(ws + off); off += NN + 1;
    int* cursor    = (int*)(ws + off); off += NN;
    int* eid       = (int*)(ws + off); off += NE;

    hipMemsetAsync(cnt_arr, 0, NN * sizeof(int), stream);
    hipMemsetAsync(sums, 0, (NG * 128 + NG) * sizeof(float), stream);

    prep_kernel<<<41, 256, 0, stream>>>(Wq1, bq1, We1, Wq2, bq2, We2, Wp1, bp1, Wp2, bp2);
    count_kernel<<<(NE + 255) / 256, 256, 0, stream>>>(dst, cnt_arr);
    scan_kernel<<<1, 1024, 0, stream>>>(cnt_arr, row_start, cursor);
    scatter_kernel<<<(NE + 255) / 256, 256, 0, stream>>>(dst, cursor, eid);

    gemm1_kernel<<<(NN + 7) / 8, 256, 0, stream>>>(x, Wq1, bq1, Wk1, bk1, Wv1, bv1,
                                                   Ws1, bs1, Wp1, bp1, bufA);
    agg1_kernel<<<(NN * 8 + 255) / 256, 256, 0, stream>>>(bufA, row_start, eid, src, ea, We1, h1);
    gemm2_kernel<<<(NN + 7) / 8, 256, 0, stream>>>(h1, Wq2, bq2, Wk2, bk2, Wv2, bv2,
                                                   Ws2, bs2, Wp2, bp2, bufA);
    agg2_kernel<<<(NN * 64 + 255) / 256, 256, 0, stream>>>(bufA, row_start, eid, src, ea, We2, h2);
    pool_kernel<<<(NN + 63) / 64, 256, 0, stream>>>(h2, batch, sums, cntf);
    gp_kernel<<<NG, 128, 0, stream>>>(sums, cntf, W1, b1, Gp);
    gemm3_kernel<<<(NN + 7) / 8, 256, 0, stream>>>(h2, W1, AB);
    edge_out_kernel<<<(NE + 3) / 4, 256, 0, stream>>>(AB, Gp, ea, src, dst, batch,
                                                      W1, W2, b2, (float*)d_out);
}

// Round 2
// 982.170 us; speedup vs baseline: 1.0179x; 1.0179x over previous
//
#include <hip/hip_runtime.h>
#include <math.h>

#define NN 50000
#define NE 400000
#define NG 128

// ---------------------------------------------------------------------------
// prep: fused weights  Wp1[64,128] (c=h*16+d) = sum_j Wq1[m,h*16+j]*We1[d,h*16+j]
//       bp1[128],  Wp2[128,16],  bp2[16]
// ---------------------------------------------------------------------------
__global__ void prep_kernel(const float* __restrict__ Wq1, const float* __restrict__ bq1,
                            const float* __restrict__ We1,
                            const float* __restrict__ Wq2, const float* __restrict__ bq2,
                            const float* __restrict__ We2,
                            float* __restrict__ Wp1, float* __restrict__ bp1,
                            float* __restrict__ Wp2, float* __restrict__ bp2)
{
    int idx = blockIdx.x * blockDim.x + threadIdx.x;
    if (idx < 64 * 128) {
        int m = idx >> 7, c = idx & 127;
        int h = c >> 4, d = c & 15;
        float s = 0.f;
        #pragma unroll
        for (int j = 0; j < 16; ++j)
            s += Wq1[m * 128 + h * 16 + j] * We1[d * 128 + h * 16 + j];
        Wp1[idx] = s;
    } else if (idx < 64 * 128 + 128) {
        int c = idx - 64 * 128;
        int h = c >> 4, d = c & 15;
        float s = 0.f;
        #pragma unroll
        for (int j = 0; j < 16; ++j)
            s += bq1[h * 16 + j] * We1[d * 128 + h * 16 + j];
        bp1[c] = s;
    } else if (idx < 64 * 128 + 128 + 128 * 16) {
        int i = idx - (64 * 128 + 128);
        int m = i >> 4, d = i & 15;
        float s = 0.f;
        for (int j = 0; j < 128; ++j)
            s += Wq2[m * 128 + j] * We2[d * 128 + j];
        Wp2[m * 16 + d] = s;
    } else if (idx < 64 * 128 + 128 + 128 * 16 + 16) {
        int d = idx - (64 * 128 + 128 + 128 * 16);
        float s = 0.f;
        for (int j = 0; j < 128; ++j)
            s += bq2[j] * We2[d * 128 + j];
        bp2[d] = s;
    }
}

// ---------------------------------------------------------------------------
// CSR build by dst
// ---------------------------------------------------------------------------
__global__ void count_kernel(const int* __restrict__ dst, int* __restrict__ counts)
{
    int e = blockIdx.x * blockDim.x + threadIdx.x;
    if (e < NE) atomicAdd(&counts[dst[e]], 1);
}

__global__ void scan_kernel(const int* __restrict__ counts,
                            int* __restrict__ row_start, int* __restrict__ cursor)
{
    __shared__ int lds[1024];
    int t = threadIdx.x;
    const int CH = (NN + 1023) / 1024;  // 49
    int base = t * CH;
    int s = 0;
    for (int i = 0; i < CH; ++i) {
        int idx = base + i;
        if (idx < NN) s += counts[idx];
    }
    lds[t] = s;
    __syncthreads();
    for (int off = 1; off < 1024; off <<= 1) {
        int v = (t >= off) ? lds[t - off] : 0;
        __syncthreads();
        lds[t] += v;
        __syncthreads();
    }
    int run = (t > 0) ? lds[t - 1] : 0;
    for (int i = 0; i < CH; ++i) {
        int idx = base + i;
        if (idx < NN) {
            row_start[idx] = run;
            cursor[idx] = run;
            run += counts[idx];
        }
    }
    if (t == 0) row_start[NN] = NE;
}

__global__ void scatter_kernel(const int* __restrict__ dst,
                               int* __restrict__ cursor, int* __restrict__ eid)
{
    int e = blockIdx.x * blockDim.x + threadIdx.x;
    if (e < NE) {
        int p = atomicAdd(&cursor[dst[e]], 1);
        eid[p] = e;
    }
}

// ---------------------------------------------------------------------------
// GEMM1: x[N,64] @ [Wq1|Wk1|Wv1|Ws1|Wp1][64,640] + biases
//   -> QPS[N,384] (Q|S|P)  and  KV[N,256] (K|V)
// ---------------------------------------------------------------------------
__global__ void gemm1_kernel(const float* __restrict__ x,
                             const float* __restrict__ Wq, const float* __restrict__ bq,
                             const float* __restrict__ Wk, const float* __restrict__ bk,
                             const float* __restrict__ Wv, const float* __restrict__ bv,
                             const float* __restrict__ Ws, const float* __restrict__ bs,
                             const float* __restrict__ Wp, const float* __restrict__ bp,
                             float* __restrict__ QPS, float* __restrict__ KV)
{
    __shared__ float xs[8][64];
    int t = threadIdx.x;
    int n0 = blockIdx.x * 8;
    for (int i = t; i < 8 * 64; i += 256) {
        int r = i >> 6, c = i & 63;
        int n = n0 + r;
        xs[r][c] = (n < NN) ? x[(size_t)n * 64 + c] : 0.f;
    }
    __syncthreads();
    int c = t & 127, half = t >> 7;
    const float* Wseg[5] = {Wq, Wk, Wv, Ws, Wp};
    const float* Bseg[5] = {bq, bk, bv, bs, bp};
    #pragma unroll
    for (int cb = 0; cb < 5; ++cb) {
        const float* W = Wseg[cb];
        float b = Bseg[cb][c];
        float a0 = b, a1 = b, a2 = b, a3 = b;
        for (int m = 0; m < 64; ++m) {
            float w = W[m * 128 + c];
            a0 += w * xs[half * 4 + 0][m];
            a1 += w * xs[half * 4 + 1][m];
            a2 += w * xs[half * 4 + 2][m];
            a3 += w * xs[half * 4 + 3][m];
        }
        float* dstp; int stride, col;
        switch (cb) {
            case 0: dstp = QPS; stride = 384; col = c;        break; // Q
            case 1: dstp = KV;  stride = 256; col = c;        break; // K
            case 2: dstp = KV;  stride = 256; col = 128 + c;  break; // V
            case 3: dstp = QPS; stride = 384; col = 128 + c;  break; // S
            default:dstp = QPS; stride = 384; col = 256 + c;  break; // P
        }
        int nb = n0 + half * 4;
        if (nb + 0 < NN) dstp[(size_t)(nb + 0) * stride + col] = a0;
        if (nb + 1 < NN) dstp[(size_t)(nb + 1) * stride + col] = a1;
        if (nb + 2 < NN) dstp[(size_t)(nb + 2) * stride + col] = a2;
        if (nb + 3 < NN) dstp[(size_t)(nb + 3) * stride + col] = a3;
    }
}

// ---------------------------------------------------------------------------
// agg1: wave per node. lane = h*8 + p; each lane owns j = 2p, 2p+1 of head h.
// QPS row: [Q(128)|S(128)|P(128)], KV row: [K(128)|V(128)]
// ---------------------------------------------------------------------------
__global__ void agg1_kernel(const float* __restrict__ QPS, const float* __restrict__ KV,
                            const int* __restrict__ row_start, const int* __restrict__ eid,
                            const int* __restrict__ src, const float* __restrict__ ea,
                            const float* __restrict__ We1, float* __restrict__ h1)
{
    __shared__ float we[16 * 128];
    int t = threadIdx.x;
    for (int i = t; i < 2048; i += 256) we[i] = We1[i];
    __syncthreads();
    int wv = t >> 6, l = t & 63;
    int n = blockIdx.x * 4 + wv;
    if (n >= NN) return;
    int h = l >> 3, p = l & 7;
    int j0 = p * 2;
    const float* qb = QPS + (size_t)n * 384;
    float2 q = *(const float2*)(qb + h * 16 + j0);
    float2 P = *(const float2*)(qb + 256 + h * 16 + j0);
    float2 accv = make_float2(0.f, 0.f), acce = make_float2(0.f, 0.f);
    float denom = 0.f;
    int e0 = row_start[n], e1 = row_start[n + 1];
    for (int idx = e0; idx < e1; ++idx) {
        int e = eid[idx];
        int s = src[e];
        const float* kvb = KV + (size_t)s * 256;
        float2 kk = *(const float2*)(kvb + h * 16 + j0);
        float2 vv = *(const float2*)(kvb + 128 + h * 16 + j0);
        float2 ee = *(const float2*)(ea + (size_t)e * 16 + j0);
        float part = q.x * kk.x + q.y * kk.y + P.x * ee.x + P.y * ee.y;
        part += __shfl_xor(part, 1, 64);
        part += __shfl_xor(part, 2, 64);
        part += __shfl_xor(part, 4, 64);
        float w = __expf(part * 0.25f);
        denom += w;
        accv.x += w * vv.x; accv.y += w * vv.y;
        acce.x += w * ee.x; acce.y += w * ee.y;
    }
    float inv = (denom > 0.f) ? 1.f / denom : 0.f;
    float es0 = 0.f, es1 = 0.f;
    int gbase = h * 8;
    #pragma unroll
    for (int dd = 0; dd < 8; ++dd) {
        float a0 = __shfl(acce.x, gbase + dd, 64);
        float a1 = __shfl(acce.y, gbase + dd, 64);
        es0 += a0 * we[(2 * dd) * 128 + h * 16 + j0]     + a1 * we[(2 * dd + 1) * 128 + h * 16 + j0];
        es1 += a0 * we[(2 * dd) * 128 + h * 16 + j0 + 1] + a1 * we[(2 * dd + 1) * 128 + h * 16 + j0 + 1];
    }
    float2 sk = *(const float2*)(qb + 128 + h * 16 + j0);
    float o0 = (accv.x + es0) * inv + sk.x;
    float o1 = (accv.y + es1) * inv + sk.y;
    o0 = (o0 > 0.f) ? o0 : 0.01f * o0;
    o1 = (o1 > 0.f) ? o1 : 0.01f * o1;
    *(float2*)(h1 + (size_t)n * 128 + h * 16 + j0) = make_float2(o0, o1);
}

// ---------------------------------------------------------------------------
// GEMM2: h1[N,128] @ [Wq2|Wk2|Wv2|Ws2|Wp2][128,528] + biases
//   -> QPS2[N,272] (Q|S|P2) and KV2[N,256] (K|V)
// ---------------------------------------------------------------------------
__global__ void gemm2_kernel(const float* __restrict__ h1,
                             const float* __restrict__ Wq, const float* __restrict__ bq,
                             const float* __restrict__ Wk, const float* __restrict__ bk,
                             const float* __restrict__ Wv, const float* __restrict__ bv,
                             const float* __restrict__ Ws, const float* __restrict__ bs,
                             const float* __restrict__ Wp2, const float* __restrict__ bp2,
                             float* __restrict__ QPS2, float* __restrict__ KV2)
{
    __shared__ float hs[8][128];
    int t = threadIdx.x;
    int n0 = blockIdx.x * 8;
    for (int i = t; i < 8 * 128; i += 256) {
        int r = i >> 7, c = i & 127;
        int n = n0 + r;
        hs[r][c] = (n < NN) ? h1[(size_t)n * 128 + c] : 0.f;
    }
    __syncthreads();
    int c = t & 127, half = t >> 7;
    const float* Wseg[4] = {Wq, Wk, Wv, Ws};
    const float* Bseg[4] = {bq, bk, bv, bs};
    #pragma unroll
    for (int cb = 0; cb < 4; ++cb) {
        const float* W = Wseg[cb];
        float b = Bseg[cb][c];
        float a0 = b, a1 = b, a2 = b, a3 = b;
        for (int m = 0; m < 128; ++m) {
            float w = W[m * 128 + c];
            a0 += w * hs[half * 4 + 0][m];
            a1 += w * hs[half * 4 + 1][m];
            a2 += w * hs[half * 4 + 2][m];
            a3 += w * hs[half * 4 + 3][m];
        }
        float* dstp; int stride, col;
        switch (cb) {
            case 0: dstp = QPS2; stride = 272; col = c;       break; // Q
            case 1: dstp = KV2;  stride = 256; col = c;       break; // K
            case 2: dstp = KV2;  stride = 256; col = 128 + c; break; // V
            default:dstp = QPS2; stride = 272; col = 128 + c; break; // S
        }
        int nb = n0 + half * 4;
        if (nb + 0 < NN) dstp[(size_t)(nb + 0) * stride + col] = a0;
        if (nb + 1 < NN) dstp[(size_t)(nb + 1) * stride + col] = a1;
        if (nb + 2 < NN) dstp[(size_t)(nb + 2) * stride + col] = a2;
        if (nb + 3 < NN) dstp[(size_t)(nb + 3) * stride + col] = a3;
    }
    if (t < 16) {
        for (int i = 0; i < 8; ++i) {
            int n = n0 + i;
            if (n >= NN) break;
            float acc = bp2[t];
            for (int m = 0; m < 128; ++m) acc += hs[i][m] * Wp2[m * 16 + t];
            QPS2[(size_t)n * 272 + 256 + t] = acc;
        }
    }
}

// ---------------------------------------------------------------------------
// agg2: wave per node; heads=1, dh=128.
// QPS2 row: [Q(128)|S(128)|P2(16)], KV2 row: [K(128)|V(128)]
// ---------------------------------------------------------------------------
__global__ void agg2_kernel(const float* __restrict__ QPS2, const float* __restrict__ KV2,
                            const int* __restrict__ row_start, const int* __restrict__ eid,
                            const int* __restrict__ src, const float* __restrict__ ea,
                            const float* __restrict__ We2, float* __restrict__ h2)
{
    int wid = (blockIdx.x * blockDim.x + threadIdx.x) >> 6;
    int l = threadIdx.x & 63;
    if (wid >= NN) return;
    int n = wid;
    const float* base = QPS2 + (size_t)n * 272;
    float q0 = base[l], q1 = base[64 + l];
    float p2 = (l < 16) ? base[256 + l] : 0.f;
    float av0 = 0.f, av1 = 0.f, ae = 0.f, denom = 0.f;
    int e0 = row_start[n], e1 = row_start[n + 1];
    for (int idx = e0; idx < e1; ++idx) {
        int e = eid[idx];
        int s = src[e];
        const float* kb = KV2 + (size_t)s * 256;
        float k0 = kb[l], k1 = kb[64 + l];
        float v0 = kb[128 + l], v1 = kb[192 + l];
        float eav = (l < 16) ? ea[(size_t)e * 16 + l] : 0.f;
        float part = q0 * k0 + q1 * k1 + p2 * eav;
        #pragma unroll
        for (int off = 32; off; off >>= 1) part += __shfl_xor(part, off, 64);
        float w = __expf(part * 0.08838834764831845f);  // 1/sqrt(128)
        denom += w;
        av0 += w * v0;
        av1 += w * v1;
        ae += w * eav;
    }
    float inv = (denom > 0.f) ? 1.f / denom : 0.f;
    float t0 = 0.f, t1 = 0.f;
    #pragma unroll
    for (int d = 0; d < 16; ++d) {
        float aed = __shfl(ae, d, 64);
        t0 += aed * We2[d * 128 + l];
        t1 += aed * We2[d * 128 + 64 + l];
    }
    float o0 = (av0 + t0) * inv + base[128 + l];
    float o1 = (av1 + t1) * inv + base[192 + l];
    h2[(size_t)n * 128 + l] = o0;
    h2[(size_t)n * 128 + 64 + l] = o1;
}

// ---------------------------------------------------------------------------
// pooling: sorted batch -> register-accumulated flushes
// ---------------------------------------------------------------------------
__global__ void pool_kernel(const float* __restrict__ h2, const int* __restrict__ batch,
                            float* __restrict__ sums, float* __restrict__ cnt)
{
    int t = threadIdx.x;
    int c = t & 127, half = t >> 7;
    int n0 = blockIdx.x * 64;
    float acc = 0.f, cacc = 0.f;
    int curg = -1;
    for (int r = half; r < 64; r += 2) {
        int n = n0 + r;
        if (n >= NN) break;
        int g = batch[n];
        if (g != curg) {
            if (curg >= 0) {
                atomicAdd(&sums[curg * 128 + c], acc);
                if (c == 0) atomicAdd(&cnt[curg], cacc);
            }
            curg = g; acc = 0.f; cacc = 0.f;
        }
        acc += h2[(size_t)n * 128 + c];
        cacc += 1.f;
    }
    if (curg >= 0) {
        atomicAdd(&sums[curg * 128 + c], acc);
        if (c == 0) atomicAdd(&cnt[curg], cacc);
    }
}

// Gp[g,c] = b1[c] + sum_m pool[g,m] * W1[272+m, c]
__global__ void gp_kernel(const float* __restrict__ sums, const float* __restrict__ cnt,
                          const float* __restrict__ W1, const float* __restrict__ b1,
                          float* __restrict__ Gp)
{
    __shared__ float pr[128];
    int g = blockIdx.x, c = threadIdx.x;
    float inv = 1.f / fmaxf(cnt[g], 1.f);
    pr[c] = sums[g * 128 + c] * inv;
    __syncthreads();
    float acc = b1[c];
    for (int m = 0; m < 128; ++m) acc += pr[m] * W1[(272 + m) * 128 + c];
    Gp[g * 128 + c] = acc;
}

// ---------------------------------------------------------------------------
// GEMM3: h2[N,128] @ [W1a|W1b][128,256] -> AB[N,256]
// ---------------------------------------------------------------------------
__global__ void gemm3_kernel(const float* __restrict__ h2, const float* __restrict__ W1,
                             float* __restrict__ AB)
{
    __shared__ float hs[8][128];
    int t = threadIdx.x;
    int n0 = blockIdx.x * 8;
    for (int i = t; i < 8 * 128; i += 256) {
        int r = i >> 7, c = i & 127;
        int n = n0 + r;
        hs[r][c] = (n < NN) ? h2[(size_t)n * 128 + c] : 0.f;
    }
    __syncthreads();
    int seg = t >> 7, cc = t & 127;
    float acc[8];
    #pragma unroll
    for (int i = 0; i < 8; ++i) acc[i] = 0.f;
    for (int m = 0; m < 128; ++m) {
        float w = W1[(size_t)(seg * 128 + m) * 128 + cc];
        #pragma unroll
        for (int i = 0; i < 8; ++i) acc[i] += w * hs[i][m];
    }
    #pragma unroll
    for (int i = 0; i < 8; ++i) {
        int n = n0 + i;
        if (n < NN) AB[(size_t)n * 256 + t] = acc[i];
    }
}

// ---------------------------------------------------------------------------
// final: wave per CSR slot (dst-sorted for d-side locality)
// hid = A[s] + B[d] + Gp[batch[s]] + ea@W1c; relu; dot W2
// ---------------------------------------------------------------------------
__global__ void edge_out_kernel(const float* __restrict__ AB, const float* __restrict__ Gp,
                                const float* __restrict__ ea,
                                const int* __restrict__ src, const int* __restrict__ dst,
                                const int* __restrict__ batch,
                                const int* __restrict__ eid,
                                const float* __restrict__ W1, const float* __restrict__ W2,
                                const float* __restrict__ b2, float* __restrict__ out)
{
    __shared__ float w1c[16 * 128];
    __shared__ float w2s[128];
    int t = threadIdx.x;
    for (int i = t; i < 2048; i += 256) w1c[i] = W1[(size_t)(256 + (i >> 7)) * 128 + (i & 127)];
    if (t < 128) w2s[t] = W2[t];
    __syncthreads();
    int wv = t >> 6, l = t & 63;
    int idx = blockIdx.x * 4 + wv;
    if (idx >= NE) return;
    int e = eid[idx];
    int s = src[e], d = dst[e], g = batch[s];
    float h0 = AB[(size_t)s * 256 + l] + AB[(size_t)d * 256 + 128 + l] + Gp[g * 128 + l];
    float h1v = AB[(size_t)s * 256 + 64 + l] + AB[(size_t)d * 256 + 192 + l] + Gp[g * 128 + 64 + l];
    float eal = ea[(size_t)e * 16 + (l & 15)];
    #pragma unroll
    for (int d16 = 0; d16 < 16; ++d16) {
        float ev = __shfl(eal, d16, 64);
        h0 += ev * w1c[d16 * 128 + l];
        h1v += ev * w1c[d16 * 128 + 64 + l];
    }
    h0 = fmaxf(h0, 0.f);
    h1v = fmaxf(h1v, 0.f);
    float r = h0 * w2s[l] + h1v * w2s[64 + l];
    #pragma unroll
    for (int off = 32; off; off >>= 1) r += __shfl_xor(r, off, 64);
    if (l == 0) out[e] = r + b2[0];
}

// ---------------------------------------------------------------------------
extern "C" void kernel_launch(void* const* d_in, const int* in_sizes, int n_in,
                              void* d_out, int out_size, void* d_ws, size_t ws_size,
                              hipStream_t stream)
{
    const float* x   = (const float*)d_in[0];
    const int* ei    = (const int*)d_in[1];
    const float* ea  = (const float*)d_in[2];
    const int* batch = (const int*)d_in[3];
    const float* Wq1 = (const float*)d_in[4];  const float* bq1 = (const float*)d_in[5];
    const float* Wk1 = (const float*)d_in[6];  const float* bk1 = (const float*)d_in[7];
    const float* Wv1 = (const float*)d_in[8];  const float* bv1 = (const float*)d_in[9];
    const float* We1 = (const float*)d_in[10];
    const float* Ws1 = (const float*)d_in[11]; const float* bs1 = (const float*)d_in[12];
    const float* Wq2 = (const float*)d_in[13]; const float* bq2 = (const float*)d_in[14];
    const float* Wk2 = (const float*)d_in[15]; const float* bk2 = (const float*)d_in[16];
    const float* Wv2 = (const float*)d_in[17]; const float* bv2 = (const float*)d_in[18];
    const float* We2 = (const float*)d_in[19];
    const float* Ws2 = (const float*)d_in[20]; const float* bs2 = (const float*)d_in[21];
    const float* W1  = (const float*)d_in[22]; const float* b1  = (const float*)d_in[23];
    const float* W2  = (const float*)d_in[24]; const float* b2  = (const float*)d_in[25];

    const int* src = ei;
    const int* dst = ei + NE;

    float* ws = (float*)d_ws;
    size_t off = 0;
    float* QPS  = ws + off; off += (size_t)NN * 384;  // L1: Q|S|P; reused as QPS2 (stride 272)
    float* KV   = ws + off; off += (size_t)NN * 256;  // L1: K|V; reused as KV2
    float* h1   = ws + off; off += (size_t)NN * 128;
    float* h2   = ws + off; off += (size_t)NN * 128;
    float* AB   = ws + off; off += (size_t)NN * 256;
    float* sums = ws + off; off += NG * 128;
    float* cntf = ws + off; off += NG;
    float* Gp   = ws + off; off += NG * 128;
    float* Wp1  = ws + off; off += 64 * 128;
    float* bp1  = ws + off; off += 128;
    float* Wp2  = ws + off; off += 128 * 16;
    float* bp2  = ws + off; off += 16;
    int* cnt_arr   = (int*)(ws + off); off += NN;
    int* row_start = (int*)(ws + off); off += NN + 1;
    int* cursor    = (int*)(ws + off); off += NN;
    int* eid       = (int*)(ws + off); off += NE;

    hipMemsetAsync(cnt_arr, 0, NN * sizeof(int), stream);
    hipMemsetAsync(sums, 0, (NG * 128 + NG) * sizeof(float), stream);

    prep_kernel<<<41, 256, 0, stream>>>(Wq1, bq1, We1, Wq2, bq2, We2, Wp1, bp1, Wp2, bp2);
    count_kernel<<<(NE + 255) / 256, 256, 0, stream>>>(dst, cnt_arr);
    scan_kernel<<<1, 1024, 0, stream>>>(cnt_arr, row_start, cursor);
    scatter_kernel<<<(NE + 255) / 256, 256, 0, stream>>>(dst, cursor, eid);

    gemm1_kernel<<<(NN + 7) / 8, 256, 0, stream>>>(x, Wq1, bq1, Wk1, bk1, Wv1, bv1,
                                                   Ws1, bs1, Wp1, bp1, QPS, KV);
    agg1_kernel<<<(NN + 3) / 4, 256, 0, stream>>>(QPS, KV, row_start, eid, src, ea, We1, h1);
    gemm2_kernel<<<(NN + 7) / 8, 256, 0, stream>>>(h1, Wq2, bq2, Wk2, bk2, Wv2, bv2,
                                                   Ws2, bs2, Wp2, bp2, QPS, KV);
    agg2_kernel<<<(NN * 64 + 255) / 256, 256, 0, stream>>>(QPS, KV, row_start, eid, src, ea, We2, h2);
    pool_kernel<<<(NN + 63) / 64, 256, 0, stream>>>(h2, batch, sums, cntf);
    gp_kernel<<<NG, 128, 0, stream>>>(sums, cntf, W1, b1, Gp);
    gemm3_kernel<<<(NN + 7) / 8, 256, 0, stream>>>(h2, W1, AB);
    edge_out_kernel<<<(NE + 3) / 4, 256, 0, stream>>>(AB, Gp, ea, src, dst, batch, eid,
                                                      W1, W2, b2, (float*)d_out);
}

// Round 3
// 838.556 us; speedup vs baseline: 1.1923x; 1.1713x over previous
//
#include <hip/hip_runtime.h>
#include <math.h>

#define NN 50000
#define NE 400000
#define NG 128

// bijective XCD-chunked swizzle (m204): each XCD gets a contiguous chunk
__device__ __forceinline__ int xcd_swz(int bid, int nwg)
{
    int q = nwg >> 3, r = nwg & 7;
    int xcd = bid & 7, off = bid >> 3;
    return (xcd < r ? xcd * (q + 1) : r * (q + 1) + (xcd - r) * q) + off;
}

// ---------------------------------------------------------------------------
// prep: fused weights  Wp1[64,128] (c=h*16+d) = sum_j Wq1[m,h*16+j]*We1[d,h*16+j]
//       bp1[128],  Wp2[128,16],  bp2[16]
// ---------------------------------------------------------------------------
__global__ void prep_kernel(const float* __restrict__ Wq1, const float* __restrict__ bq1,
                            const float* __restrict__ We1,
                            const float* __restrict__ Wq2, const float* __restrict__ bq2,
                            const float* __restrict__ We2,
                            float* __restrict__ Wp1, float* __restrict__ bp1,
                            float* __restrict__ Wp2, float* __restrict__ bp2)
{
    int idx = blockIdx.x * blockDim.x + threadIdx.x;
    if (idx < 64 * 128) {
        int m = idx >> 7, c = idx & 127;
        int h = c >> 4, d = c & 15;
        float s = 0.f;
        #pragma unroll
        for (int j = 0; j < 16; ++j)
            s += Wq1[m * 128 + h * 16 + j] * We1[d * 128 + h * 16 + j];
        Wp1[idx] = s;
    } else if (idx < 64 * 128 + 128) {
        int c = idx - 64 * 128;
        int h = c >> 4, d = c & 15;
        float s = 0.f;
        #pragma unroll
        for (int j = 0; j < 16; ++j)
            s += bq1[h * 16 + j] * We1[d * 128 + h * 16 + j];
        bp1[c] = s;
    } else if (idx < 64 * 128 + 128 + 128 * 16) {
        int i = idx - (64 * 128 + 128);
        int m = i >> 4, d = i & 15;
        float s = 0.f;
        for (int j = 0; j < 128; ++j)
            s += Wq2[m * 128 + j] * We2[d * 128 + j];
        Wp2[m * 16 + d] = s;
    } else if (idx < 64 * 128 + 128 + 128 * 16 + 16) {
        int d = idx - (64 * 128 + 128 + 128 * 16);
        float s = 0.f;
        for (int j = 0; j < 128; ++j)
            s += bq2[j] * We2[d * 128 + j];
        bp2[d] = s;
    }
}

// ---------------------------------------------------------------------------
// CSR build by dst (+ CSR-ordered src/dst/edge-id side arrays)
// ---------------------------------------------------------------------------
__global__ void count_kernel(const int* __restrict__ dst, int* __restrict__ counts)
{
    int e = blockIdx.x * blockDim.x + threadIdx.x;
    if (e < NE) atomicAdd(&counts[dst[e]], 1);
}

__global__ void scan_kernel(const int* __restrict__ counts,
                            int* __restrict__ row_start, int* __restrict__ cursor)
{
    __shared__ int lds[1024];
    int t = threadIdx.x;
    const int CH = (NN + 1023) / 1024;  // 49
    int base = t * CH;
    int s = 0;
    for (int i = 0; i < CH; ++i) {
        int idx = base + i;
        if (idx < NN) s += counts[idx];
    }
    lds[t] = s;
    __syncthreads();
    for (int off = 1; off < 1024; off <<= 1) {
        int v = (t >= off) ? lds[t - off] : 0;
        __syncthreads();
        lds[t] += v;
        __syncthreads();
    }
    int run = (t > 0) ? lds[t - 1] : 0;
    for (int i = 0; i < CH; ++i) {
        int idx = base + i;
        if (idx < NN) {
            row_start[idx] = run;
            cursor[idx] = run;
            run += counts[idx];
        }
    }
    if (t == 0) row_start[NN] = NE;
}

__global__ void scatter_kernel(const int* __restrict__ src, const int* __restrict__ dst,
                               int* __restrict__ cursor, int* __restrict__ eid,
                               int* __restrict__ se, int* __restrict__ de)
{
    int e = blockIdx.x * blockDim.x + threadIdx.x;
    if (e < NE) {
        int d = dst[e];
        int p = atomicAdd(&cursor[d], 1);
        eid[p] = e;
        se[p] = src[e];
        de[p] = d;
    }
}

// eac[idx,16] = ea[eid[idx],16]  (gather-read, coalesced write)
__global__ void eacopy_kernel(const int* __restrict__ eid, const float* __restrict__ ea,
                              float* __restrict__ eac)
{
    int g = blockIdx.x * blockDim.x + threadIdx.x;  // NE*16 threads
    int idx = g >> 4, c = g & 15;
    eac[g] = ea[(size_t)eid[idx] * 16 + c];
}

// ---------------------------------------------------------------------------
// GEMM1: x[N,64] @ [Wq1|Wk1|Wv1|Ws1|Wp1][64,640] + biases
//   -> QPS[N,384] (Q|S|P)  and  KV[N,256] (K|V)
// ---------------------------------------------------------------------------
__global__ void gemm1_kernel(const float* __restrict__ x,
                             const float* __restrict__ Wq, const float* __restrict__ bq,
                             const float* __restrict__ Wk, const float* __restrict__ bk,
                             const float* __restrict__ Wv, const float* __restrict__ bv,
                             const float* __restrict__ Ws, const float* __restrict__ bs,
                             const float* __restrict__ Wp, const float* __restrict__ bp,
                             float* __restrict__ QPS, float* __restrict__ KV)
{
    __shared__ float xs[8][64];
    int t = threadIdx.x;
    int n0 = blockIdx.x * 8;
    for (int i = t; i < 8 * 64; i += 256) {
        int r = i >> 6, c = i & 63;
        int n = n0 + r;
        xs[r][c] = (n < NN) ? x[(size_t)n * 64 + c] : 0.f;
    }
    __syncthreads();
    int c = t & 127, half = t >> 7;
    const float* Wseg[5] = {Wq, Wk, Wv, Ws, Wp};
    const float* Bseg[5] = {bq, bk, bv, bs, bp};
    #pragma unroll
    for (int cb = 0; cb < 5; ++cb) {
        const float* W = Wseg[cb];
        float b = Bseg[cb][c];
        float a0 = b, a1 = b, a2 = b, a3 = b;
        for (int m = 0; m < 64; ++m) {
            float w = W[m * 128 + c];
            a0 += w * xs[half * 4 + 0][m];
            a1 += w * xs[half * 4 + 1][m];
            a2 += w * xs[half * 4 + 2][m];
            a3 += w * xs[half * 4 + 3][m];
        }
        float* dstp; int stride, col;
        switch (cb) {
            case 0: dstp = QPS; stride = 384; col = c;        break; // Q
            case 1: dstp = KV;  stride = 256; col = c;        break; // K
            case 2: dstp = KV;  stride = 256; col = 128 + c;  break; // V
            case 3: dstp = QPS; stride = 384; col = 128 + c;  break; // S
            default:dstp = QPS; stride = 384; col = 256 + c;  break; // P
        }
        int nb = n0 + half * 4;
        if (nb + 0 < NN) dstp[(size_t)(nb + 0) * stride + col] = a0;
        if (nb + 1 < NN) dstp[(size_t)(nb + 1) * stride + col] = a1;
        if (nb + 2 < NN) dstp[(size_t)(nb + 2) * stride + col] = a2;
        if (nb + 3 < NN) dstp[(size_t)(nb + 3) * stride + col] = a3;
    }
}

// ---------------------------------------------------------------------------
// agg1: wave per node. lane = h*8 + p; lane owns j = 2p, 2p+1 of head h.
// 2-way unrolled over edges; se/eac sequential (no pointer chase).
// ---------------------------------------------------------------------------
__global__ void agg1_kernel(const float* __restrict__ QPS, const float* __restrict__ KV,
                            const int* __restrict__ row_start,
                            const int* __restrict__ se, const float* __restrict__ eac,
                            const float* __restrict__ We1, float* __restrict__ h1)
{
    __shared__ float we[16 * 128];
    int t = threadIdx.x;
    for (int i = t; i < 2048; i += 256) we[i] = We1[i];
    __syncthreads();
    int bid = xcd_swz(blockIdx.x, gridDim.x);
    int wv = t >> 6, l = t & 63;
    int n = bid * 4 + wv;
    if (n >= NN) return;
    int h = l >> 3, p = l & 7;
    int j0 = p * 2;
    const float* qb = QPS + (size_t)n * 384;
    float2 q = *(const float2*)(qb + h * 16 + j0);
    float2 P = *(const float2*)(qb + 256 + h * 16 + j0);
    float2 accv = make_float2(0.f, 0.f), acce = make_float2(0.f, 0.f);
    float denom = 0.f;
    int e0 = row_start[n], e1 = row_start[n + 1];
    int idx = e0;
    for (; idx + 1 < e1; idx += 2) {
        int sA = se[idx], sB = se[idx + 1];
        const float* kvA = KV + (size_t)sA * 256;
        const float* kvB = KV + (size_t)sB * 256;
        float2 kA = *(const float2*)(kvA + h * 16 + j0);
        float2 vA = *(const float2*)(kvA + 128 + h * 16 + j0);
        float2 eA = *(const float2*)(eac + (size_t)idx * 16 + j0);
        float2 kB = *(const float2*)(kvB + h * 16 + j0);
        float2 vB = *(const float2*)(kvB + 128 + h * 16 + j0);
        float2 eB = *(const float2*)(eac + (size_t)(idx + 1) * 16 + j0);
        float pa = q.x * kA.x + q.y * kA.y + P.x * eA.x + P.y * eA.y;
        float pb = q.x * kB.x + q.y * kB.y + P.x * eB.x + P.y * eB.y;
        pa += __shfl_xor(pa, 1, 64); pb += __shfl_xor(pb, 1, 64);
        pa += __shfl_xor(pa, 2, 64); pb += __shfl_xor(pb, 2, 64);
        pa += __shfl_xor(pa, 4, 64); pb += __shfl_xor(pb, 4, 64);
        float wA = __expf(pa * 0.25f);
        float wB = __expf(pb * 0.25f);
        denom += wA + wB;
        accv.x += wA * vA.x + wB * vB.x;
        accv.y += wA * vA.y + wB * vB.y;
        acce.x += wA * eA.x + wB * eB.x;
        acce.y += wA * eA.y + wB * eB.y;
    }
    if (idx < e1) {
        int s = se[idx];
        const float* kvb = KV + (size_t)s * 256;
        float2 kk = *(const float2*)(kvb + h * 16 + j0);
        float2 vv = *(const float2*)(kvb + 128 + h * 16 + j0);
        float2 ee = *(const float2*)(eac + (size_t)idx * 16 + j0);
        float part = q.x * kk.x + q.y * kk.y + P.x * ee.x + P.y * ee.y;
        part += __shfl_xor(part, 1, 64);
        part += __shfl_xor(part, 2, 64);
        part += __shfl_xor(part, 4, 64);
        float w = __expf(part * 0.25f);
        denom += w;
        accv.x += w * vv.x; accv.y += w * vv.y;
        acce.x += w * ee.x; acce.y += w * ee.y;
    }
    float inv = (denom > 0.f) ? 1.f / denom : 0.f;
    float es0 = 0.f, es1 = 0.f;
    int gbase = h * 8;
    #pragma unroll
    for (int dd = 0; dd < 8; ++dd) {
        float a0 = __shfl(acce.x, gbase + dd, 64);
        float a1 = __shfl(acce.y, gbase + dd, 64);
        es0 += a0 * we[(2 * dd) * 128 + h * 16 + j0]     + a1 * we[(2 * dd + 1) * 128 + h * 16 + j0];
        es1 += a0 * we[(2 * dd) * 128 + h * 16 + j0 + 1] + a1 * we[(2 * dd + 1) * 128 + h * 16 + j0 + 1];
    }
    float2 sk = *(const float2*)(qb + 128 + h * 16 + j0);
    float o0 = (accv.x + es0) * inv + sk.x;
    float o1 = (accv.y + es1) * inv + sk.y;
    o0 = (o0 > 0.f) ? o0 : 0.01f * o0;
    o1 = (o1 > 0.f) ? o1 : 0.01f * o1;
    *(float2*)(h1 + (size_t)n * 128 + h * 16 + j0) = make_float2(o0, o1);
}

// ---------------------------------------------------------------------------
// GEMM2: h1[N,128] @ [Wq2|Wk2|Wv2|Ws2|Wp2][128,528] + biases
//   -> QPS2[N,272] (Q|S|P2) and KV2[N,256] (K|V)
// ---------------------------------------------------------------------------
__global__ void gemm2_kernel(const float* __restrict__ h1,
                             const float* __restrict__ Wq, const float* __restrict__ bq,
                             const float* __restrict__ Wk, const float* __restrict__ bk,
                             const float* __restrict__ Wv, const float* __restrict__ bv,
                             const float* __restrict__ Ws, const float* __restrict__ bs,
                             const float* __restrict__ Wp2, const float* __restrict__ bp2,
                             float* __restrict__ QPS2, float* __restrict__ KV2)
{
    __shared__ float hs[8][128];
    int t = threadIdx.x;
    int n0 = blockIdx.x * 8;
    for (int i = t; i < 8 * 128; i += 256) {
        int r = i >> 7, c = i & 127;
        int n = n0 + r;
        hs[r][c] = (n < NN) ? h1[(size_t)n * 128 + c] : 0.f;
    }
    __syncthreads();
    int c = t & 127, half = t >> 7;
    const float* Wseg[4] = {Wq, Wk, Wv, Ws};
    const float* Bseg[4] = {bq, bk, bv, bs};
    #pragma unroll
    for (int cb = 0; cb < 4; ++cb) {
        const float* W = Wseg[cb];
        float b = Bseg[cb][c];
        float a0 = b, a1 = b, a2 = b, a3 = b;
        for (int m = 0; m < 128; ++m) {
            float w = W[m * 128 + c];
            a0 += w * hs[half * 4 + 0][m];
            a1 += w * hs[half * 4 + 1][m];
            a2 += w * hs[half * 4 + 2][m];
            a3 += w * hs[half * 4 + 3][m];
        }
        float* dstp; int stride, col;
        switch (cb) {
            case 0: dstp = QPS2; stride = 272; col = c;       break; // Q
            case 1: dstp = KV2;  stride = 256; col = c;       break; // K
            case 2: dstp = KV2;  stride = 256; col = 128 + c; break; // V
            default:dstp = QPS2; stride = 272; col = 128 + c; break; // S
        }
        int nb = n0 + half * 4;
        if (nb + 0 < NN) dstp[(size_t)(nb + 0) * stride + col] = a0;
        if (nb + 1 < NN) dstp[(size_t)(nb + 1) * stride + col] = a1;
        if (nb + 2 < NN) dstp[(size_t)(nb + 2) * stride + col] = a2;
        if (nb + 3 < NN) dstp[(size_t)(nb + 3) * stride + col] = a3;
    }
    if (t < 16) {
        for (int i = 0; i < 8; ++i) {
            int n = n0 + i;
            if (n >= NN) break;
            float acc = bp2[t];
            for (int m = 0; m < 128; ++m) acc += hs[i][m] * Wp2[m * 16 + t];
            QPS2[(size_t)n * 272 + 256 + t] = acc;
        }
    }
}

// ---------------------------------------------------------------------------
// agg2: wave per node, half-wave per edge (2 edges in flight).
// lane = half*32 + c; lane owns dims {c, c+32, c+64, c+96}.
// ---------------------------------------------------------------------------
__global__ void agg2_kernel(const float* __restrict__ QPS2, const float* __restrict__ KV2,
                            const int* __restrict__ row_start,
                            const int* __restrict__ se, const float* __restrict__ eac,
                            const float* __restrict__ We2, float* __restrict__ h2)
{
    int bid = xcd_swz(blockIdx.x, gridDim.x);
    int t = threadIdx.x;
    int wv = t >> 6, l = t & 63;
    int n = bid * 4 + wv;
    if (n >= NN) return;
    int half = l >> 5, c = l & 31;
    const float* base = QPS2 + (size_t)n * 272;
    float q0 = base[c], q1 = base[32 + c], q2 = base[64 + c], q3 = base[96 + c];
    float p2 = (c < 16) ? base[256 + c] : 0.f;
    float av0 = 0.f, av1 = 0.f, av2 = 0.f, av3 = 0.f, ae = 0.f, denom = 0.f;
    int e0 = row_start[n], e1 = row_start[n + 1];
    for (int idx = e0 + half; idx < e1; idx += 2) {
        int s = se[idx];
        const float* kb = KV2 + (size_t)s * 256;
        float k0 = kb[c], k1 = kb[32 + c], k2 = kb[64 + c], k3 = kb[96 + c];
        float v0 = kb[128 + c], v1 = kb[160 + c], v2 = kb[192 + c], v3 = kb[224 + c];
        float eav = (c < 16) ? eac[(size_t)idx * 16 + c] : 0.f;
        float part = q0 * k0 + q1 * k1 + q2 * k2 + q3 * k3 + p2 * eav;
        part += __shfl_xor(part, 1, 64);
        part += __shfl_xor(part, 2, 64);
        part += __shfl_xor(part, 4, 64);
        part += __shfl_xor(part, 8, 64);
        part += __shfl_xor(part, 16, 64);
        float w = __expf(part * 0.08838834764831845f);  // 1/sqrt(128)
        denom += w;
        av0 += w * v0; av1 += w * v1; av2 += w * v2; av3 += w * v3;
        ae += w * eav;
    }
    // combine halves
    denom += __shfl_xor(denom, 32, 64);
    av0 += __shfl_xor(av0, 32, 64);
    av1 += __shfl_xor(av1, 32, 64);
    av2 += __shfl_xor(av2, 32, 64);
    av3 += __shfl_xor(av3, 32, 64);
    ae  += __shfl_xor(ae, 32, 64);
    float inv = (denom > 0.f) ? 1.f / denom : 0.f;
    float t0 = 0.f, t1 = 0.f, t2 = 0.f, t3 = 0.f;
    #pragma unroll
    for (int d = 0; d < 16; ++d) {
        float aed = __shfl(ae, d, 64);
        t0 += aed * We2[d * 128 + c];
        t1 += aed * We2[d * 128 + 32 + c];
        t2 += aed * We2[d * 128 + 64 + c];
        t3 += aed * We2[d * 128 + 96 + c];
    }
    if (half == 0) {
        float* hp = h2 + (size_t)n * 128;
        hp[c]      = (av0 + t0) * inv + base[128 + c];
        hp[32 + c] = (av1 + t1) * inv + base[160 + c];
        hp[64 + c] = (av2 + t2) * inv + base[192 + c];
        hp[96 + c] = (av3 + t3) * inv + base[224 + c];
    }
}

// ---------------------------------------------------------------------------
// pooling: sorted batch -> register-accumulated flushes
// ---------------------------------------------------------------------------
__global__ void pool_kernel(const float* __restrict__ h2, const int* __restrict__ batch,
                            float* __restrict__ sums, float* __restrict__ cnt)
{
    int t = threadIdx.x;
    int c = t & 127, half = t >> 7;
    int n0 = blockIdx.x * 64;
    float acc = 0.f, cacc = 0.f;
    int curg = -1;
    for (int r = half; r < 64; r += 2) {
        int n = n0 + r;
        if (n >= NN) break;
        int g = batch[n];
        if (g != curg) {
            if (curg >= 0) {
                atomicAdd(&sums[curg * 128 + c], acc);
                if (c == 0) atomicAdd(&cnt[curg], cacc);
            }
            curg = g; acc = 0.f; cacc = 0.f;
        }
        acc += h2[(size_t)n * 128 + c];
        cacc += 1.f;
    }
    if (curg >= 0) {
        atomicAdd(&sums[curg * 128 + c], acc);
        if (c == 0) atomicAdd(&cnt[curg], cacc);
    }
}

// Gp[g,c] = b1[c] + sum_m pool[g,m] * W1[272+m, c]
__global__ void gp_kernel(const float* __restrict__ sums, const float* __restrict__ cnt,
                          const float* __restrict__ W1, const float* __restrict__ b1,
                          float* __restrict__ Gp)
{
    __shared__ float pr[128];
    int g = blockIdx.x, c = threadIdx.x;
    float inv = 1.f / fmaxf(cnt[g], 1.f);
    pr[c] = sums[g * 128 + c] * inv;
    __syncthreads();
    float acc = b1[c];
    for (int m = 0; m < 128; ++m) acc += pr[m] * W1[(272 + m) * 128 + c];
    Gp[g * 128 + c] = acc;
}

// ---------------------------------------------------------------------------
// GEMM3: h2[N,128] @ [W1a|W1b][128,256] -> AB[N,256]
// ---------------------------------------------------------------------------
__global__ void gemm3_kernel(const float* __restrict__ h2, const float* __restrict__ W1,
                             float* __restrict__ AB)
{
    __shared__ float hs[8][128];
    int t = threadIdx.x;
    int n0 = blockIdx.x * 8;
    for (int i = t; i < 8 * 128; i += 256) {
        int r = i >> 7, c = i & 127;
        int n = n0 + r;
        hs[r][c] = (n < NN) ? h2[(size_t)n * 128 + c] : 0.f;
    }
    __syncthreads();
    int seg = t >> 7, cc = t & 127;
    float acc[8];
    #pragma unroll
    for (int i = 0; i < 8; ++i) acc[i] = 0.f;
    for (int m = 0; m < 128; ++m) {
        float w = W1[(size_t)(seg * 128 + m) * 128 + cc];
        #pragma unroll
        for (int i = 0; i < 8; ++i) acc[i] += w * hs[i][m];
    }
    #pragma unroll
    for (int i = 0; i < 8; ++i) {
        int n = n0 + i;
        if (n < NN) AB[(size_t)n * 256 + t] = acc[i];
    }
}

// ---------------------------------------------------------------------------
// final: half-wave per CSR slot; lane owns dims {c,c+32,c+64,c+96}.
// hid = A[s] + B[d] + Gp[batch[s]] + ea@W1c; relu; dot W2
// ---------------------------------------------------------------------------
__global__ void edge_out_kernel(const float* __restrict__ AB, const float* __restrict__ Gp,
                                const int* __restrict__ eid, const int* __restrict__ se,
                                const int* __restrict__ de, const float* __restrict__ eac,
                                const int* __restrict__ batch,
                                const float* __restrict__ W1, const float* __restrict__ W2,
                                const float* __restrict__ b2, float* __restrict__ out)
{
    __shared__ float w1c[16 * 128];
    __shared__ float w2s[128];
    int t = threadIdx.x;
    for (int i = t; i < 2048; i += 256) w1c[i] = W1[(size_t)(256 + (i >> 7)) * 128 + (i & 127)];
    if (t < 128) w2s[t] = W2[t];
    __syncthreads();
    int bid = xcd_swz(blockIdx.x, gridDim.x);
    int wv = t >> 6, l = t & 63;
    int half = l >> 5, c = l & 31;
    int idx = bid * 8 + wv * 2 + half;   // NE == gridDim*8 exactly
    int e = eid[idx];
    int s = se[idx], d = de[idx], g = batch[s];
    const float* As = AB + (size_t)s * 256;
    const float* Bd = AB + (size_t)d * 256 + 128;
    const float* Gg = Gp + g * 128;
    float h0 = As[c]      + Bd[c]      + Gg[c];
    float h1v = As[32 + c] + Bd[32 + c] + Gg[32 + c];
    float h2v = As[64 + c] + Bd[64 + c] + Gg[64 + c];
    float h3v = As[96 + c] + Bd[96 + c] + Gg[96 + c];
    float eal = (c < 16) ? eac[(size_t)idx * 16 + c] : 0.f;
    int sbase = half << 5;
    #pragma unroll
    for (int d16 = 0; d16 < 16; ++d16) {
        float ev = __shfl(eal, sbase + d16, 64);
        h0  += ev * w1c[d16 * 128 + c];
        h1v += ev * w1c[d16 * 128 + 32 + c];
        h2v += ev * w1c[d16 * 128 + 64 + c];
        h3v += ev * w1c[d16 * 128 + 96 + c];
    }
    h0 = fmaxf(h0, 0.f); h1v = fmaxf(h1v, 0.f);
    h2v = fmaxf(h2v, 0.f); h3v = fmaxf(h3v, 0.f);
    float r = h0 * w2s[c] + h1v * w2s[32 + c] + h2v * w2s[64 + c] + h3v * w2s[96 + c];
    r += __shfl_xor(r, 1, 64);
    r += __shfl_xor(r, 2, 64);
    r += __shfl_xor(r, 4, 64);
    r += __shfl_xor(r, 8, 64);
    r += __shfl_xor(r, 16, 64);
    if (c == 0) out[e] = r + b2[0];
}

// ---------------------------------------------------------------------------
extern "C" void kernel_launch(void* const* d_in, const int* in_sizes, int n_in,
                              void* d_out, int out_size, void* d_ws, size_t ws_size,
                              hipStream_t stream)
{
    const float* x   = (const float*)d_in[0];
    const int* ei    = (const int*)d_in[1];
    const float* ea  = (const float*)d_in[2];
    const int* batch = (const int*)d_in[3];
    const float* Wq1 = (const float*)d_in[4];  const float* bq1 = (const float*)d_in[5];
    const float* Wk1 = (const float*)d_in[6];  const float* bk1 = (const float*)d_in[7];
    const float* Wv1 = (const float*)d_in[8];  const float* bv1 = (const float*)d_in[9];
    const float* We1 = (const float*)d_in[10];
    const float* Ws1 = (const float*)d_in[11]; const float* bs1 = (const float*)d_in[12];
    const float* Wq2 = (const float*)d_in[13]; const float* bq2 = (const float*)d_in[14];
    const float* Wk2 = (const float*)d_in[15]; const float* bk2 = (const float*)d_in[16];
    const float* Wv2 = (const float*)d_in[17]; const float* bv2 = (const float*)d_in[18];
    const float* We2 = (const float*)d_in[19];
    const float* Ws2 = (const float*)d_in[20]; const float* bs2 = (const float*)d_in[21];
    const float* W1  = (const float*)d_in[22]; const float* b1  = (const float*)d_in[23];
    const float* W2  = (const float*)d_in[24]; const float* b2  = (const float*)d_in[25];

    const int* src = ei;
    const int* dst = ei + NE;

    float* ws = (float*)d_ws;
    size_t off = 0;
    float* QPS  = ws + off; off += (size_t)NN * 384;  // L1 Q|S|P; L2 QPS2 (272); then AB (256)
    float* KV   = ws + off; off += (size_t)NN * 256;  // K|V both layers
    float* h1   = ws + off; off += (size_t)NN * 128;
    float* h2   = ws + off; off += (size_t)NN * 128;
    float* eac  = ws + off; off += (size_t)NE * 16;
    float* sums = ws + off; off += NG * 128;
    float* cntf = ws + off; off += NG;
    float* Gp   = ws + off; off += NG * 128;
    float* Wp1  = ws + off; off += 64 * 128;
    float* bp1  = ws + off; off += 128;
    float* Wp2  = ws + off; off += 128 * 16;
    float* bp2  = ws + off; off += 16;
    int* cnt_arr   = (int*)(ws + off); off += NN;
    int* row_start = (int*)(ws + off); off += NN + 1;
    int* cursor    = (int*)(ws + off); off += NN;
    int* eid       = (int*)(ws + off); off += NE;
    int* se        = (int*)(ws + off); off += NE;
    int* de        = (int*)(ws + off); off += NE;
    float* AB = QPS;  // alias: QPS dead after agg2, AB written by gemm3 afterwards

    hipMemsetAsync(cnt_arr, 0, NN * sizeof(int), stream);
    hipMemsetAsync(sums, 0, (NG * 128 + NG) * sizeof(float), stream);

    prep_kernel<<<41, 256, 0, stream>>>(Wq1, bq1, We1, Wq2, bq2, We2, Wp1, bp1, Wp2, bp2);
    count_kernel<<<(NE + 255) / 256, 256, 0, stream>>>(dst, cnt_arr);
    scan_kernel<<<1, 1024, 0, stream>>>(cnt_arr, row_start, cursor);
    scatter_kernel<<<(NE + 255) / 256, 256, 0, stream>>>(src, dst, cursor, eid, se, de);
    eacopy_kernel<<<NE * 16 / 256, 256, 0, stream>>>(eid, ea, eac);

    gemm1_kernel<<<(NN + 7) / 8, 256, 0, stream>>>(x, Wq1, bq1, Wk1, bk1, Wv1, bv1,
                                                   Ws1, bs1, Wp1, bp1, QPS, KV);
    agg1_kernel<<<(NN + 3) / 4, 256, 0, stream>>>(QPS, KV, row_start, se, eac, We1, h1);
    gemm2_kernel<<<(NN + 7) / 8, 256, 0, stream>>>(h1, Wq2, bq2, Wk2, bk2, Wv2, bv2,
                                                   Ws2, bs2, Wp2, bp2, QPS, KV);
    agg2_kernel<<<(NN + 3) / 4, 256, 0, stream>>>(QPS, KV, row_start, se, eac, We2, h2);
    pool_kernel<<<(NN + 63) / 64, 256, 0, stream>>>(h2, batch, sums, cntf);
    gp_kernel<<<NG, 128, 0, stream>>>(sums, cntf, W1, b1, Gp);
    gemm3_kernel<<<(NN + 7) / 8, 256, 0, stream>>>(h2, W1, AB);
    edge_out_kernel<<<NE / 8, 256, 0, stream>>>(AB, Gp, eid, se, de, eac, batch,
                                                W1, W2, b2, (float*)d_out);
}

// Round 4
// 627.733 us; speedup vs baseline: 1.5927x; 1.3358x over previous
//
#include <hip/hip_runtime.h>
#include <math.h>

#define NN 50000
#define NE 400000
#define NG 128

typedef __bf16 bf16x8 __attribute__((ext_vector_type(8)));
typedef float f32x4 __attribute__((ext_vector_type(4)));

// bijective XCD-chunked swizzle (m204): each XCD gets a contiguous chunk
__device__ __forceinline__ int xcd_swz(int bid, int nwg)
{
    int q = nwg >> 3, r = nwg & 7;
    int xcd = bid & 7, off = bid >> 3;
    return (xcd < r ? xcd * (q + 1) : r * (q + 1) + (xcd - r) * q) + off;
}

// ---------------------------------------------------------------------------
// prep: fused weights Wp1[64,128], Wp2[128,16]; concatenated biases
//   bcat1[640] = [bq1|bk1|bv1|bs1|bp1],  bcat2[528] = [bq2|bk2|bv2|bs2|bp2]
// ---------------------------------------------------------------------------
__global__ void prep_kernel(const float* __restrict__ Wq1, const float* __restrict__ bq1,
                            const float* __restrict__ bk1, const float* __restrict__ bv1,
                            const float* __restrict__ bs1, const float* __restrict__ We1,
                            const float* __restrict__ Wq2, const float* __restrict__ bq2,
                            const float* __restrict__ bk2, const float* __restrict__ bv2,
                            const float* __restrict__ bs2, const float* __restrict__ We2,
                            float* __restrict__ Wp1, float* __restrict__ Wp2,
                            float* __restrict__ bcat1, float* __restrict__ bcat2)
{
    int idx = blockIdx.x * blockDim.x + threadIdx.x;
    if (idx < 8192) {                       // Wp1[64,128]
        int m = idx >> 7, c = idx & 127;
        int h = c >> 4, d = c & 15;
        float s = 0.f;
        #pragma unroll
        for (int j = 0; j < 16; ++j)
            s += Wq1[m * 128 + h * 16 + j] * We1[d * 128 + h * 16 + j];
        Wp1[idx] = s;
    } else if (idx < 8320) {                // bp1 -> bcat1[512..640)
        int c = idx - 8192;
        int h = c >> 4, d = c & 15;
        float s = 0.f;
        #pragma unroll
        for (int j = 0; j < 16; ++j)
            s += bq1[h * 16 + j] * We1[d * 128 + h * 16 + j];
        bcat1[512 + c] = s;
    } else if (idx < 10368) {               // Wp2[128,16]
        int i = idx - 8320;
        int m = i >> 4, d = i & 15;
        float s = 0.f;
        for (int j = 0; j < 128; ++j)
            s += Wq2[m * 128 + j] * We2[d * 128 + j];
        Wp2[m * 16 + d] = s;
    } else if (idx < 10384) {               // bp2 -> bcat2[512..528)
        int d = idx - 10368;
        float s = 0.f;
        for (int j = 0; j < 128; ++j)
            s += bq2[j] * We2[d * 128 + j];
        bcat2[512 + d] = s;
    } else if (idx < 10896) {               // bcat1[0..512)
        int i = idx - 10384;
        int seg = i >> 7, c = i & 127;
        const float* b = (seg == 0) ? bq1 : (seg == 1) ? bk1 : (seg == 2) ? bv1 : bs1;
        bcat1[i] = b[c];
    } else if (idx < 11408) {               // bcat2[0..512)
        int i = idx - 10896;
        int seg = i >> 7, c = i & 127;
        const float* b = (seg == 0) ? bq2 : (seg == 1) ? bk2 : (seg == 2) ? bv2 : bs2;
        bcat2[i] = b[c];
    }
}

// ---------------------------------------------------------------------------
// pack: build MFMA fragment-ready hi/lo bf16 weight blocks.
// Block b covers (mat, kt, ct); layout per block: [2(hi/lo)][lane(64)][j(8)].
//   mat0: gemm1 Wcat[64,640]  (2 kt x 40 ct, blocks 0..79)
//   mat1: gemm2 Wcat[128,528] (4 kt x 33 ct, blocks 80..211)
//   mat2: gemm3 Wcat[128,256] (4 kt x 16 ct, blocks 212..275)
// ---------------------------------------------------------------------------
__global__ void pack_kernel(const float* __restrict__ Wq1, const float* __restrict__ Wk1,
                            const float* __restrict__ Wv1, const float* __restrict__ Ws1,
                            const float* __restrict__ Wp1,
                            const float* __restrict__ Wq2, const float* __restrict__ Wk2,
                            const float* __restrict__ Wv2, const float* __restrict__ Ws2,
                            const float* __restrict__ Wp2,
                            const float* __restrict__ W1,
                            __bf16* __restrict__ pk)
{
    int b = blockIdx.x;
    int mat, kt, ct;
    if (b < 80)       { mat = 0; kt = b / 40;        ct = b % 40; }
    else if (b < 212) { mat = 1; kt = (b - 80) / 33; ct = (b - 80) % 33; }
    else              { mat = 2; kt = (b - 212) / 16; ct = (b - 212) % 16; }
    __bf16* blkp = pk + (size_t)b * 1024;
    for (int item = threadIdx.x; item < 512; item += 256) {
        int lane = item >> 3, j = item & 7;
        int k = kt * 32 + (lane >> 4) * 8 + j;
        int col = ct * 16 + (lane & 15);
        float v;
        if (mat == 0) {
            int seg = col >> 7, cc = col & 127;
            const float* W = (seg == 0) ? Wq1 : (seg == 1) ? Wk1 : (seg == 2) ? Wv1
                             : (seg == 3) ? Ws1 : Wp1;
            v = W[k * 128 + cc];
        } else if (mat == 1) {
            if (col < 512) {
                int seg = col >> 7, cc = col & 127;
                const float* W = (seg == 0) ? Wq2 : (seg == 1) ? Wk2 : (seg == 2) ? Wv2 : Ws2;
                v = W[k * 128 + cc];
            } else {
                v = Wp2[k * 16 + (col - 512)];
            }
        } else {
            v = (col < 128) ? W1[k * 128 + col] : W1[(size_t)(128 + k) * 128 + (col - 128)];
        }
        __bf16 h = (__bf16)v;
        __bf16 lo = (__bf16)(v - (float)h);
        blkp[lane * 8 + j] = h;
        blkp[512 + lane * 8 + j] = lo;
    }
}

// ---------------------------------------------------------------------------
// CSR build by dst (+ CSR-ordered src/dst and edge-attr copies)
// ---------------------------------------------------------------------------
__global__ void count_kernel(const int* __restrict__ dst, int* __restrict__ counts)
{
    int e = blockIdx.x * blockDim.x + threadIdx.x;
    if (e < NE) atomicAdd(&counts[dst[e]], 1);
}

__global__ void scan_kernel(const int* __restrict__ counts,
                            int* __restrict__ row_start, int* __restrict__ cursor)
{
    __shared__ int lds[1024];
    int t = threadIdx.x;
    const int CH = (NN + 1023) / 1024;  // 49
    int base = t * CH;
    int s = 0;
    for (int i = 0; i < CH; ++i) {
        int idx = base + i;
        if (idx < NN) s += counts[idx];
    }
    lds[t] = s;
    __syncthreads();
    for (int off = 1; off < 1024; off <<= 1) {
        int v = (t >= off) ? lds[t - off] : 0;
        __syncthreads();
        lds[t] += v;
        __syncthreads();
    }
    int run = (t > 0) ? lds[t - 1] : 0;
    for (int i = 0; i < CH; ++i) {
        int idx = base + i;
        if (idx < NN) {
            row_start[idx] = run;
            cursor[idx] = run;
            run += counts[idx];
        }
    }
    if (t == 0) row_start[NN] = NE;
}

__global__ void scatter_kernel(const int* __restrict__ src, const int* __restrict__ dst,
                               int* __restrict__ cursor, int* __restrict__ eid,
                               int* __restrict__ se, int* __restrict__ de)
{
    int e = blockIdx.x * blockDim.x + threadIdx.x;
    if (e < NE) {
        int d = dst[e];
        int p = atomicAdd(&cursor[d], 1);
        eid[p] = e;
        se[p] = src[e];
        de[p] = d;
    }
}

__global__ void eacopy_kernel(const int* __restrict__ eid, const float* __restrict__ ea,
                              float* __restrict__ eac)
{
    int g = blockIdx.x * blockDim.x + threadIdx.x;  // NE*16 threads
    int idx = g >> 4, c = g & 15;
    eac[g] = ea[(size_t)eid[idx] * 16 + c];
}

// ---------------------------------------------------------------------------
// MFMA GEMM: out[M, NCT*16] = A[M, KD] @ Wcat (+ bias), split-bf16 3-term.
// Block = 4 waves; wave computes 32 rows; rows/block = 128.
// ---------------------------------------------------------------------------
__device__ __forceinline__ void load_split(const float* ap, bool ok,
                                           bf16x8& hv, bf16x8& lv)
{
    float av[8];
    if (ok) {
        float4 f0 = *(const float4*)ap;
        float4 f1 = *(const float4*)(ap + 4);
        av[0] = f0.x; av[1] = f0.y; av[2] = f0.z; av[3] = f0.w;
        av[4] = f1.x; av[5] = f1.y; av[6] = f1.z; av[7] = f1.w;
    } else {
        #pragma unroll
        for (int j = 0; j < 8; ++j) av[j] = 0.f;
    }
    #pragma unroll
    for (int j = 0; j < 8; ++j) {
        __bf16 h = (__bf16)av[j];
        hv[j] = h;
        lv[j] = (__bf16)(av[j] - (float)h);
    }
}

template<int KD, int NCT, bool BIAS>
__global__ void mfma_gemm_kernel(const float* __restrict__ A, const __bf16* __restrict__ pk,
                                 const float* __restrict__ bias, float* __restrict__ out,
                                 int ldo)
{
    constexpr int NKT = KD / 32;
    int t = threadIdx.x, w = t >> 6, l = t & 63;
    int rbase = blockIdx.x * 128 + w * 32;
    int lr = l & 15, kq = l >> 4;
    int r0 = rbase + lr, r1 = rbase + 16 + lr;
    bool ok0 = r0 < NN, ok1 = r1 < NN;
    bf16x8 ah0[NKT], al0[NKT], ah1[NKT], al1[NKT];
    #pragma unroll
    for (int kt = 0; kt < NKT; ++kt) {
        load_split(A + (size_t)r0 * KD + kt * 32 + kq * 8, ok0, ah0[kt], al0[kt]);
        load_split(A + (size_t)r1 * KD + kt * 32 + kq * 8, ok1, ah1[kt], al1[kt]);
    }
    for (int ct = 0; ct < NCT; ++ct) {
        float b = BIAS ? bias[ct * 16 + lr] : 0.f;
        f32x4 acc0 = {b, b, b, b};
        f32x4 acc1 = {b, b, b, b};
        const __bf16* blk = pk + (size_t)ct * 1024;
        #pragma unroll
        for (int kt = 0; kt < NKT; ++kt) {
            bf16x8 bh = *(const bf16x8*)(blk + (size_t)kt * NCT * 1024 + l * 8);
            bf16x8 bl = *(const bf16x8*)(blk + (size_t)kt * NCT * 1024 + 512 + l * 8);
            acc0 = __builtin_amdgcn_mfma_f32_16x16x32_bf16(al0[kt], bh, acc0, 0, 0, 0);
            acc1 = __builtin_amdgcn_mfma_f32_16x16x32_bf16(al1[kt], bh, acc1, 0, 0, 0);
            acc0 = __builtin_amdgcn_mfma_f32_16x16x32_bf16(ah0[kt], bl, acc0, 0, 0, 0);
            acc1 = __builtin_amdgcn_mfma_f32_16x16x32_bf16(ah1[kt], bl, acc1, 0, 0, 0);
            acc0 = __builtin_amdgcn_mfma_f32_16x16x32_bf16(ah0[kt], bh, acc0, 0, 0, 0);
            acc1 = __builtin_amdgcn_mfma_f32_16x16x32_bf16(ah1[kt], bh, acc1, 0, 0, 0);
        }
        int col = ct * 16 + lr;
        #pragma unroll
        for (int i = 0; i < 4; ++i) {
            int ra = rbase + kq * 4 + i;
            int rb = ra + 16;
            if (ra < NN) out[(size_t)ra * ldo + col] = acc0[i];
            if (rb < NN) out[(size_t)rb * ldo + col] = acc1[i];
        }
    }
}

// ---------------------------------------------------------------------------
// agg1: wave per node. OUT1 row [Q|K|V|S|P] stride 640.
// lane = h*8 + p; lane owns j = 2p, 2p+1 of head h. 2-way edge unroll.
// ---------------------------------------------------------------------------
__global__ void agg1_kernel(const float* __restrict__ OUT1,
                            const int* __restrict__ row_start,
                            const int* __restrict__ se, const float* __restrict__ eac,
                            const float* __restrict__ We1, float* __restrict__ h1)
{
    __shared__ float we[16 * 128];
    int t = threadIdx.x;
    for (int i = t; i < 2048; i += 256) we[i] = We1[i];
    __syncthreads();
    int bid = xcd_swz(blockIdx.x, gridDim.x);
    int wv = t >> 6, l = t & 63;
    int n = bid * 4 + wv;
    if (n >= NN) return;
    int h = l >> 3, p = l & 7;
    int j0 = p * 2;
    const float* qb = OUT1 + (size_t)n * 640;
    float2 q = *(const float2*)(qb + h * 16 + j0);
    float2 P = *(const float2*)(qb + 512 + h * 16 + j0);
    float2 accv = make_float2(0.f, 0.f), acce = make_float2(0.f, 0.f);
    float denom = 0.f;
    int e0 = row_start[n], e1 = row_start[n + 1];
    int idx = e0;
    for (; idx + 1 < e1; idx += 2) {
        int sA = se[idx], sB = se[idx + 1];
        const float* kvA = OUT1 + (size_t)sA * 640 + 128;
        const float* kvB = OUT1 + (size_t)sB * 640 + 128;
        float2 kA = *(const float2*)(kvA + h * 16 + j0);
        float2 vA = *(const float2*)(kvA + 128 + h * 16 + j0);
        float2 eA = *(const float2*)(eac + (size_t)idx * 16 + j0);
        float2 kB = *(const float2*)(kvB + h * 16 + j0);
        float2 vB = *(const float2*)(kvB + 128 + h * 16 + j0);
        float2 eB = *(const float2*)(eac + (size_t)(idx + 1) * 16 + j0);
        float pa = q.x * kA.x + q.y * kA.y + P.x * eA.x + P.y * eA.y;
        float pb = q.x * kB.x + q.y * kB.y + P.x * eB.x + P.y * eB.y;
        pa += __shfl_xor(pa, 1, 64); pb += __shfl_xor(pb, 1, 64);
        pa += __shfl_xor(pa, 2, 64); pb += __shfl_xor(pb, 2, 64);
        pa += __shfl_xor(pa, 4, 64); pb += __shfl_xor(pb, 4, 64);
        float wA = __expf(pa * 0.25f);
        float wB = __expf(pb * 0.25f);
        denom += wA + wB;
        accv.x += wA * vA.x + wB * vB.x;
        accv.y += wA * vA.y + wB * vB.y;
        acce.x += wA * eA.x + wB * eB.x;
        acce.y += wA * eA.y + wB * eB.y;
    }
    if (idx < e1) {
        int s = se[idx];
        const float* kvb = OUT1 + (size_t)s * 640 + 128;
        float2 kk = *(const float2*)(kvb + h * 16 + j0);
        float2 vv = *(const float2*)(kvb + 128 + h * 16 + j0);
        float2 ee = *(const float2*)(eac + (size_t)idx * 16 + j0);
        float part = q.x * kk.x + q.y * kk.y + P.x * ee.x + P.y * ee.y;
        part += __shfl_xor(part, 1, 64);
        part += __shfl_xor(part, 2, 64);
        part += __shfl_xor(part, 4, 64);
        float w = __expf(part * 0.25f);
        denom += w;
        accv.x += w * vv.x; accv.y += w * vv.y;
        acce.x += w * ee.x; acce.y += w * ee.y;
    }
    float inv = (denom > 0.f) ? 1.f / denom : 0.f;
    float es0 = 0.f, es1 = 0.f;
    int gbase = h * 8;
    #pragma unroll
    for (int dd = 0; dd < 8; ++dd) {
        float a0 = __shfl(acce.x, gbase + dd, 64);
        float a1 = __shfl(acce.y, gbase + dd, 64);
        es0 += a0 * we[(2 * dd) * 128 + h * 16 + j0]     + a1 * we[(2 * dd + 1) * 128 + h * 16 + j0];
        es1 += a0 * we[(2 * dd) * 128 + h * 16 + j0 + 1] + a1 * we[(2 * dd + 1) * 128 + h * 16 + j0 + 1];
    }
    float2 sk = *(const float2*)(qb + 384 + h * 16 + j0);
    float o0 = (accv.x + es0) * inv + sk.x;
    float o1 = (accv.y + es1) * inv + sk.y;
    o0 = (o0 > 0.f) ? o0 : 0.01f * o0;
    o1 = (o1 > 0.f) ? o1 : 0.01f * o1;
    *(float2*)(h1 + (size_t)n * 128 + h * 16 + j0) = make_float2(o0, o1);
}

// ---------------------------------------------------------------------------
// agg2: wave per node, half-wave per edge. OUT2 row [Q|K|V|S|P2] stride 528.
// lane = half*32 + c; lane owns dims {c, c+32, c+64, c+96}.
// ---------------------------------------------------------------------------
__global__ void agg2_kernel(const float* __restrict__ OUT2,
                            const int* __restrict__ row_start,
                            const int* __restrict__ se, const float* __restrict__ eac,
                            const float* __restrict__ We2, float* __restrict__ h2)
{
    int bid = xcd_swz(blockIdx.x, gridDim.x);
    int t = threadIdx.x;
    int wv = t >> 6, l = t & 63;
    int n = bid * 4 + wv;
    if (n >= NN) return;
    int half = l >> 5, c = l & 31;
    const float* base = OUT2 + (size_t)n * 528;
    float q0 = base[c], q1 = base[32 + c], q2 = base[64 + c], q3 = base[96 + c];
    float p2 = (c < 16) ? base[512 + c] : 0.f;
    float av0 = 0.f, av1 = 0.f, av2 = 0.f, av3 = 0.f, ae = 0.f, denom = 0.f;
    int e0 = row_start[n], e1 = row_start[n + 1];
    for (int idx = e0 + half; idx < e1; idx += 2) {
        int s = se[idx];
        const float* kb = OUT2 + (size_t)s * 528 + 128;
        float k0 = kb[c], k1 = kb[32 + c], k2 = kb[64 + c], k3 = kb[96 + c];
        float v0 = kb[128 + c], v1 = kb[160 + c], v2 = kb[192 + c], v3 = kb[224 + c];
        float eav = (c < 16) ? eac[(size_t)idx * 16 + c] : 0.f;
        float part = q0 * k0 + q1 * k1 + q2 * k2 + q3 * k3 + p2 * eav;
        part += __shfl_xor(part, 1, 64);
        part += __shfl_xor(part, 2, 64);
        part += __shfl_xor(part, 4, 64);
        part += __shfl_xor(part, 8, 64);
        part += __shfl_xor(part, 16, 64);
        float w = __expf(part * 0.08838834764831845f);  // 1/sqrt(128)
        denom += w;
        av0 += w * v0; av1 += w * v1; av2 += w * v2; av3 += w * v3;
        ae += w * eav;
    }
    denom += __shfl_xor(denom, 32, 64);
    av0 += __shfl_xor(av0, 32, 64);
    av1 += __shfl_xor(av1, 32, 64);
    av2 += __shfl_xor(av2, 32, 64);
    av3 += __shfl_xor(av3, 32, 64);
    ae  += __shfl_xor(ae, 32, 64);
    float inv = (denom > 0.f) ? 1.f / denom : 0.f;
    float t0 = 0.f, t1 = 0.f, t2 = 0.f, t3 = 0.f;
    #pragma unroll
    for (int d = 0; d < 16; ++d) {
        float aed = __shfl(ae, d, 64);
        t0 += aed * We2[d * 128 + c];
        t1 += aed * We2[d * 128 + 32 + c];
        t2 += aed * We2[d * 128 + 64 + c];
        t3 += aed * We2[d * 128 + 96 + c];
    }
    if (half == 0) {
        float* hp = h2 + (size_t)n * 128;
        hp[c]      = (av0 + t0) * inv + base[384 + c];
        hp[32 + c] = (av1 + t1) * inv + base[416 + c];
        hp[64 + c] = (av2 + t2) * inv + base[448 + c];
        hp[96 + c] = (av3 + t3) * inv + base[480 + c];
    }
}

// ---------------------------------------------------------------------------
// pooling: sorted batch -> register-accumulated flushes
// ---------------------------------------------------------------------------
__global__ void pool_kernel(const float* __restrict__ h2, const int* __restrict__ batch,
                            float* __restrict__ sums, float* __restrict__ cnt)
{
    int t = threadIdx.x;
    int c = t & 127, half = t >> 7;
    int n0 = blockIdx.x * 64;
    float acc = 0.f, cacc = 0.f;
    int curg = -1;
    for (int r = half; r < 64; r += 2) {
        int n = n0 + r;
        if (n >= NN) break;
        int g = batch[n];
        if (g != curg) {
            if (curg >= 0) {
                atomicAdd(&sums[curg * 128 + c], acc);
                if (c == 0) atomicAdd(&cnt[curg], cacc);
            }
            curg = g; acc = 0.f; cacc = 0.f;
        }
        acc += h2[(size_t)n * 128 + c];
        cacc += 1.f;
    }
    if (curg >= 0) {
        atomicAdd(&sums[curg * 128 + c], acc);
        if (c == 0) atomicAdd(&cnt[curg], cacc);
    }
}

// Gp[g,c] = b1[c] + sum_m pool[g,m] * W1[272+m, c]
__global__ void gp_kernel(const float* __restrict__ sums, const float* __restrict__ cnt,
                          const float* __restrict__ W1, const float* __restrict__ b1,
                          float* __restrict__ Gp)
{
    __shared__ float pr[128];
    int g = blockIdx.x, c = threadIdx.x;
    float inv = 1.f / fmaxf(cnt[g], 1.f);
    pr[c] = sums[g * 128 + c] * inv;
    __syncthreads();
    float acc = b1[c];
    for (int m = 0; m < 128; ++m) acc += pr[m] * W1[(272 + m) * 128 + c];
    Gp[g * 128 + c] = acc;
}

// ---------------------------------------------------------------------------
// final: half-wave per CSR slot; lane owns dims {c,c+32,c+64,c+96}.
// hid = A[s] + B[d] + Gp[batch[s]] + ea@W1c; relu; dot W2
// ---------------------------------------------------------------------------
__global__ void edge_out_kernel(const float* __restrict__ AB, const float* __restrict__ Gp,
                                const int* __restrict__ eid, const int* __restrict__ se,
                                const int* __restrict__ de, const float* __restrict__ eac,
                                const int* __restrict__ batch,
                                const float* __restrict__ W1, const float* __restrict__ W2,
                                const float* __restrict__ b2, float* __restrict__ out)
{
    __shared__ float w1c[16 * 128];
    __shared__ float w2s[128];
    int t = threadIdx.x;
    for (int i = t; i < 2048; i += 256) w1c[i] = W1[(size_t)(256 + (i >> 7)) * 128 + (i & 127)];
    if (t < 128) w2s[t] = W2[t];
    __syncthreads();
    int bid = xcd_swz(blockIdx.x, gridDim.x);
    int wv = t >> 6, l = t & 63;
    int half = l >> 5, c = l & 31;
    int idx = bid * 8 + wv * 2 + half;   // NE == gridDim*8 exactly
    int e = eid[idx];
    int s = se[idx], d = de[idx], g = batch[s];
    const float* As = AB + (size_t)s * 256;
    const float* Bd = AB + (size_t)d * 256 + 128;
    const float* Gg = Gp + g * 128;
    float h0  = As[c]      + Bd[c]      + Gg[c];
    float h1v = As[32 + c] + Bd[32 + c] + Gg[32 + c];
    float h2v = As[64 + c] + Bd[64 + c] + Gg[64 + c];
    float h3v = As[96 + c] + Bd[96 + c] + Gg[96 + c];
    float eal = (c < 16) ? eac[(size_t)idx * 16 + c] : 0.f;
    int sbase = half << 5;
    #pragma unroll
    for (int d16 = 0; d16 < 16; ++d16) {
        float ev = __shfl(eal, sbase + d16, 64);
        h0  += ev * w1c[d16 * 128 + c];
        h1v += ev * w1c[d16 * 128 + 32 + c];
        h2v += ev * w1c[d16 * 128 + 64 + c];
        h3v += ev * w1c[d16 * 128 + 96 + c];
    }
    h0 = fmaxf(h0, 0.f); h1v = fmaxf(h1v, 0.f);
    h2v = fmaxf(h2v, 0.f); h3v = fmaxf(h3v, 0.f);
    float r = h0 * w2s[c] + h1v * w2s[32 + c] + h2v * w2s[64 + c] + h3v * w2s[96 + c];
    r += __shfl_xor(r, 1, 64);
    r += __shfl_xor(r, 2, 64);
    r += __shfl_xor(r, 4, 64);
    r += __shfl_xor(r, 8, 64);
    r += __shfl_xor(r, 16, 64);
    if (c == 0) out[e] = r + b2[0];
}

// ---------------------------------------------------------------------------
extern "C" void kernel_launch(void* const* d_in, const int* in_sizes, int n_in,
                              void* d_out, int out_size, void* d_ws, size_t ws_size,
                              hipStream_t stream)
{
    const float* x   = (const float*)d_in[0];
    const int* ei    = (const int*)d_in[1];
    const float* ea  = (const float*)d_in[2];
    const int* batch = (const int*)d_in[3];
    const float* Wq1 = (const float*)d_in[4];  const float* bq1 = (const float*)d_in[5];
    const float* Wk1 = (const float*)d_in[6];  const float* bk1 = (const float*)d_in[7];
    const float* Wv1 = (const float*)d_in[8];  const float* bv1 = (const float*)d_in[9];
    const float* We1 = (const float*)d_in[10];
    const float* Ws1 = (const float*)d_in[11]; const float* bs1 = (const float*)d_in[12];
    const float* Wq2 = (const float*)d_in[13]; const float* bq2 = (const float*)d_in[14];
    const float* Wk2 = (const float*)d_in[15]; const float* bk2 = (const float*)d_in[16];
    const float* Wv2 = (const float*)d_in[17]; const float* bv2 = (const float*)d_in[18];
    const float* We2 = (const float*)d_in[19];
    const float* Ws2 = (const float*)d_in[20]; const float* bs2 = (const float*)d_in[21];
    const float* W1  = (const float*)d_in[22]; const float* b1  = (const float*)d_in[23];
    const float* W2  = (const float*)d_in[24]; const float* b2  = (const float*)d_in[25];

    const int* src = ei;
    const int* dst = ei + NE;

    float* ws = (float*)d_ws;
    size_t off = 0;
    float* OUT  = ws + off; off += (size_t)NN * 640;  // OUT1(640) / OUT2(528) / OUT3(256) alias
    float* h1   = ws + off; off += (size_t)NN * 128;
    float* h2   = ws + off; off += (size_t)NN * 128;
    float* eac  = ws + off; off += (size_t)NE * 16;
    float* sums = ws + off; off += NG * 128;
    float* cntf = ws + off; off += NG;
    float* Gp   = ws + off; off += NG * 128;
    float* Wp1  = ws + off; off += 64 * 128;
    float* Wp2  = ws + off; off += 128 * 16;
    float* bcat1 = ws + off; off += 640;
    float* bcat2 = ws + off; off += 528;
    __bf16* pk  = (__bf16*)(ws + off); off += 276 * 1024 / 2;  // 276 blocks x 1024 bf16
    int* cnt_arr   = (int*)(ws + off); off += NN;
    int* row_start = (int*)(ws + off); off += NN + 1;
    int* cursor    = (int*)(ws + off); off += NN;
    int* eid       = (int*)(ws + off); off += NE;
    int* se        = (int*)(ws + off); off += NE;
    int* de        = (int*)(ws + off); off += NE;

    hipMemsetAsync(cnt_arr, 0, NN * sizeof(int), stream);
    hipMemsetAsync(sums, 0, (NG * 128 + NG) * sizeof(float), stream);

    prep_kernel<<<45, 256, 0, stream>>>(Wq1, bq1, bk1, bv1, bs1, We1,
                                        Wq2, bq2, bk2, bv2, bs2, We2,
                                        Wp1, Wp2, bcat1, bcat2);
    pack_kernel<<<276, 256, 0, stream>>>(Wq1, Wk1, Wv1, Ws1, Wp1,
                                         Wq2, Wk2, Wv2, Ws2, Wp2, W1, pk);
    count_kernel<<<(NE + 255) / 256, 256, 0, stream>>>(dst, cnt_arr);
    scan_kernel<<<1, 1024, 0, stream>>>(cnt_arr, row_start, cursor);
    scatter_kernel<<<(NE + 255) / 256, 256, 0, stream>>>(src, dst, cursor, eid, se, de);
    eacopy_kernel<<<NE * 16 / 256, 256, 0, stream>>>(eid, ea, eac);

    mfma_gemm_kernel<64, 40, true><<<(NN + 127) / 128, 256, 0, stream>>>(
        x, pk, bcat1, OUT, 640);
    agg1_kernel<<<(NN + 3) / 4, 256, 0, stream>>>(OUT, row_start, se, eac, We1, h1);
    mfma_gemm_kernel<128, 33, true><<<(NN + 127) / 128, 256, 0, stream>>>(
        h1, pk + (size_t)80 * 1024, bcat2, OUT, 528);
    agg2_kernel<<<(NN + 3) / 4, 256, 0, stream>>>(OUT, row_start, se, eac, We2, h2);
    pool_kernel<<<(NN + 63) / 64, 256, 0, stream>>>(h2, batch, sums, cntf);
    gp_kernel<<<NG, 128, 0, stream>>>(sums, cntf, W1, b1, Gp);
    mfma_gemm_kernel<128, 16, false><<<(NN + 127) / 128, 256, 0, stream>>>(
        h2, pk + (size_t)212 * 1024, nullptr, OUT, 256);
    edge_out_kernel<<<NE / 8, 256, 0, stream>>>(OUT, Gp, eid, se, de, eac, batch,
                                                W1, W2, b2, (float*)d_out);
}

// Round 5
// 483.004 us; speedup vs baseline: 2.0700x; 1.2996x over previous
//
#include <hip/hip_runtime.h>
#include <math.h>

#define NN 50000
#define NE 400000
#define NG 128
#define SCAN_B 49   // ceil(NN/1024)

typedef __bf16 bf16x8 __attribute__((ext_vector_type(8)));
typedef float f32x4 __attribute__((ext_vector_type(4)));
typedef _Float16 h16x2 __attribute__((ext_vector_type(2)));

// bijective XCD-chunked swizzle (m204): each XCD gets a contiguous chunk
__device__ __forceinline__ int xcd_swz(int bid, int nwg)
{
    int q = nwg >> 3, r = nwg & 7;
    int xcd = bid & 7, off = bid >> 3;
    return (xcd < r ? xcd * (q + 1) : r * (q + 1) + (xcd - r) * q) + off;
}

// ---------------------------------------------------------------------------
// prep: fused weights Wp1[64,128], Wp2[128,16]; concatenated biases
// ---------------------------------------------------------------------------
__global__ void prep_kernel(const float* __restrict__ Wq1, const float* __restrict__ bq1,
                            const float* __restrict__ bk1, const float* __restrict__ bv1,
                            const float* __restrict__ bs1, const float* __restrict__ We1,
                            const float* __restrict__ Wq2, const float* __restrict__ bq2,
                            const float* __restrict__ bk2, const float* __restrict__ bv2,
                            const float* __restrict__ bs2, const float* __restrict__ We2,
                            float* __restrict__ Wp1, float* __restrict__ Wp2,
                            float* __restrict__ bcat1, float* __restrict__ bcat2)
{
    int idx = blockIdx.x * blockDim.x + threadIdx.x;
    if (idx < 8192) {                       // Wp1[64,128]
        int m = idx >> 7, c = idx & 127;
        int h = c >> 4, d = c & 15;
        float s = 0.f;
        #pragma unroll
        for (int j = 0; j < 16; ++j)
            s += Wq1[m * 128 + h * 16 + j] * We1[d * 128 + h * 16 + j];
        Wp1[idx] = s;
    } else if (idx < 8320) {                // bp1 -> bcat1[512..640)
        int c = idx - 8192;
        int h = c >> 4, d = c & 15;
        float s = 0.f;
        #pragma unroll
        for (int j = 0; j < 16; ++j)
            s += bq1[h * 16 + j] * We1[d * 128 + h * 16 + j];
        bcat1[512 + c] = s;
    } else if (idx < 10368) {               // Wp2[128,16]
        int i = idx - 8320;
        int m = i >> 4, d = i & 15;
        float s = 0.f;
        for (int j = 0; j < 128; ++j)
            s += Wq2[m * 128 + j] * We2[d * 128 + j];
        Wp2[m * 16 + d] = s;
    } else if (idx < 10384) {               // bp2 -> bcat2[512..528)
        int d = idx - 10368;
        float s = 0.f;
        for (int j = 0; j < 128; ++j)
            s += bq2[j] * We2[d * 128 + j];
        bcat2[512 + d] = s;
    } else if (idx < 10896) {               // bcat1[0..512)
        int i = idx - 10384;
        int seg = i >> 7, c = i & 127;
        const float* b = (seg == 0) ? bq1 : (seg == 1) ? bk1 : (seg == 2) ? bv1 : bs1;
        bcat1[i] = b[c];
    } else if (idx < 11408) {               // bcat2[0..512)
        int i = idx - 10896;
        int seg = i >> 7, c = i & 127;
        const float* b = (seg == 0) ? bq2 : (seg == 1) ? bk2 : (seg == 2) ? bv2 : bs2;
        bcat2[i] = b[c];
    }
}

// ---------------------------------------------------------------------------
// pack: MFMA fragment-ready hi/lo bf16 weight blocks (see R3 layout comments)
// ---------------------------------------------------------------------------
__global__ void pack_kernel(const float* __restrict__ Wq1, const float* __restrict__ Wk1,
                            const float* __restrict__ Wv1, const float* __restrict__ Ws1,
                            const float* __restrict__ Wp1,
                            const float* __restrict__ Wq2, const float* __restrict__ Wk2,
                            const float* __restrict__ Wv2, const float* __restrict__ Ws2,
                            const float* __restrict__ Wp2,
                            const float* __restrict__ W1,
                            __bf16* __restrict__ pk)
{
    int b = blockIdx.x;
    int mat, kt, ct;
    if (b < 80)       { mat = 0; kt = b / 40;        ct = b % 40; }
    else if (b < 212) { mat = 1; kt = (b - 80) / 33; ct = (b - 80) % 33; }
    else              { mat = 2; kt = (b - 212) / 16; ct = (b - 212) % 16; }
    __bf16* blkp = pk + (size_t)b * 1024;
    for (int item = threadIdx.x; item < 512; item += 256) {
        int lane = item >> 3, j = item & 7;
        int k = kt * 32 + (lane >> 4) * 8 + j;
        int col = ct * 16 + (lane & 15);
        float v;
        if (mat == 0) {
            int seg = col >> 7, cc = col & 127;
            const float* W = (seg == 0) ? Wq1 : (seg == 1) ? Wk1 : (seg == 2) ? Wv1
                             : (seg == 3) ? Ws1 : Wp1;
            v = W[k * 128 + cc];
        } else if (mat == 1) {
            if (col < 512) {
                int seg = col >> 7, cc = col & 127;
                const float* W = (seg == 0) ? Wq2 : (seg == 1) ? Wk2 : (seg == 2) ? Wv2 : Ws2;
                v = W[k * 128 + cc];
            } else {
                v = Wp2[k * 16 + (col - 512)];
            }
        } else {
            v = (col < 128) ? W1[k * 128 + col] : W1[(size_t)(128 + k) * 128 + (col - 128)];
        }
        __bf16 h = (__bf16)v;
        __bf16 lo = (__bf16)(v - (float)h);
        blkp[lane * 8 + j] = h;
        blkp[512 + lane * 8 + j] = lo;
    }
}

// ---------------------------------------------------------------------------
// CSR build by dst — count, 3-phase parallel scan, scatter, ea copy
// ---------------------------------------------------------------------------
__global__ void count_kernel(const int* __restrict__ dst, int* __restrict__ counts)
{
    int e = blockIdx.x * blockDim.x + threadIdx.x;
    if (e < NE) atomicAdd(&counts[dst[e]], 1);
}

__global__ void scanA_kernel(const int* __restrict__ counts,
                             int* __restrict__ row_start, int* __restrict__ bsum)
{
    __shared__ int lds[1024];
    int t = threadIdx.x, b = blockIdx.x;
    int i = b * 1024 + t;
    int v = (i < NN) ? counts[i] : 0;
    lds[t] = v;
    __syncthreads();
    for (int off = 1; off < 1024; off <<= 1) {
        int u = (t >= off) ? lds[t - off] : 0;
        __syncthreads();
        lds[t] += u;
        __syncthreads();
    }
    if (i < NN) row_start[i] = lds[t] - v;     // block-local exclusive
    if (t == 1023) bsum[b] = lds[1023];
}

__global__ void scanB_kernel(const int* __restrict__ bsum, int* __restrict__ boff)
{
    int t = threadIdx.x;  // 64 lanes
    int orig = (t < SCAN_B) ? bsum[t] : 0;
    int v = orig;
    #pragma unroll
    for (int off = 1; off < 64; off <<= 1) {
        int u = __shfl_up(v, off, 64);
        if (t >= off) v += u;
    }
    if (t < SCAN_B) boff[t] = v - orig;        // exclusive
}

__global__ void scanC_kernel(int* __restrict__ row_start, const int* __restrict__ boff,
                             int* __restrict__ cursor)
{
    int i = blockIdx.x * 1024 + threadIdx.x;
    if (i < NN) {
        int rs = row_start[i] + boff[blockIdx.x];
        row_start[i] = rs;
        cursor[i] = rs;
    }
    if (i == 0) row_start[NN] = NE;
}

__global__ void scatter_kernel(const int* __restrict__ src, const int* __restrict__ dst,
                               int* __restrict__ cursor, int* __restrict__ eid,
                               int* __restrict__ se, int* __restrict__ de)
{
    int e = blockIdx.x * blockDim.x + threadIdx.x;
    if (e < NE) {
        int d = dst[e];
        int p = atomicAdd(&cursor[d], 1);
        eid[p] = e;
        se[p] = src[e];
        de[p] = d;
    }
}

__global__ void eacopy_kernel(const int* __restrict__ eid, const float* __restrict__ ea,
                              float* __restrict__ eac)
{
    int g = blockIdx.x * blockDim.x + threadIdx.x;  // NE*16 threads
    int idx = g >> 4, c = g & 15;
    eac[g] = ea[(size_t)eid[idx] * 16 + c];
}

// ---------------------------------------------------------------------------
// MFMA GEMM, split-bf16 3-term. Columns in [CLO,CHI) go to fp16 aux buffer
// (width CHI-CLO); other columns to fp32 out (stride ldo).
// ---------------------------------------------------------------------------
__device__ __forceinline__ void load_split(const float* ap, bool ok,
                                           bf16x8& hv, bf16x8& lv)
{
    float av[8];
    if (ok) {
        float4 f0 = *(const float4*)ap;
        float4 f1 = *(const float4*)(ap + 4);
        av[0] = f0.x; av[1] = f0.y; av[2] = f0.z; av[3] = f0.w;
        av[4] = f1.x; av[5] = f1.y; av[6] = f1.z; av[7] = f1.w;
    } else {
        #pragma unroll
        for (int j = 0; j < 8; ++j) av[j] = 0.f;
    }
    #pragma unroll
    for (int j = 0; j < 8; ++j) {
        __bf16 h = (__bf16)av[j];
        hv[j] = h;
        lv[j] = (__bf16)(av[j] - (float)h);
    }
}

template<int KD, int NCT, bool BIAS, int CLO, int CHI>
__global__ void mfma_gemm_kernel(const float* __restrict__ A, const __bf16* __restrict__ pk,
                                 const float* __restrict__ bias, float* __restrict__ out,
                                 int ldo, _Float16* __restrict__ auxh)
{
    constexpr int NKT = KD / 32;
    constexpr int AUXW = CHI - CLO;
    int t = threadIdx.x, w = t >> 6, l = t & 63;
    int rbase = blockIdx.x * 128 + w * 32;
    int lr = l & 15, kq = l >> 4;
    int r0 = rbase + lr, r1 = rbase + 16 + lr;
    bool ok0 = r0 < NN, ok1 = r1 < NN;
    bf16x8 ah0[NKT], al0[NKT], ah1[NKT], al1[NKT];
    #pragma unroll
    for (int kt = 0; kt < NKT; ++kt) {
        load_split(A + (size_t)r0 * KD + kt * 32 + kq * 8, ok0, ah0[kt], al0[kt]);
        load_split(A + (size_t)r1 * KD + kt * 32 + kq * 8, ok1, ah1[kt], al1[kt]);
    }
    for (int ct = 0; ct < NCT; ++ct) {
        float b = BIAS ? bias[ct * 16 + lr] : 0.f;
        f32x4 acc0 = {b, b, b, b};
        f32x4 acc1 = {b, b, b, b};
        const __bf16* blk = pk + (size_t)ct * 1024;
        #pragma unroll
        for (int kt = 0; kt < NKT; ++kt) {
            bf16x8 bh = *(const bf16x8*)(blk + (size_t)kt * NCT * 1024 + l * 8);
            bf16x8 bl = *(const bf16x8*)(blk + (size_t)kt * NCT * 1024 + 512 + l * 8);
            acc0 = __builtin_amdgcn_mfma_f32_16x16x32_bf16(al0[kt], bh, acc0, 0, 0, 0);
            acc1 = __builtin_amdgcn_mfma_f32_16x16x32_bf16(al1[kt], bh, acc1, 0, 0, 0);
            acc0 = __builtin_amdgcn_mfma_f32_16x16x32_bf16(ah0[kt], bl, acc0, 0, 0, 0);
            acc1 = __builtin_amdgcn_mfma_f32_16x16x32_bf16(ah1[kt], bl, acc1, 0, 0, 0);
            acc0 = __builtin_amdgcn_mfma_f32_16x16x32_bf16(ah0[kt], bh, acc0, 0, 0, 0);
            acc1 = __builtin_amdgcn_mfma_f32_16x16x32_bf16(ah1[kt], bh, acc1, 0, 0, 0);
        }
        int col = ct * 16 + lr;
        bool inAux = (col >= CLO) && (col < CHI);
        #pragma unroll
        for (int i = 0; i < 4; ++i) {
            int ra = rbase + kq * 4 + i;
            int rb = ra + 16;
            if (ra < NN) {
                if (inAux) auxh[(size_t)ra * AUXW + (col - CLO)] = (_Float16)acc0[i];
                else       out[(size_t)ra * ldo + col] = acc0[i];
            }
            if (rb < NN) {
                if (inAux) auxh[(size_t)rb * AUXW + (col - CLO)] = (_Float16)acc1[i];
                else       out[(size_t)rb * ldo + col] = acc1[i];
            }
        }
    }
}

// ---------------------------------------------------------------------------
// agg1: wave per node. f32 OUT1 row [Q|-|-|S|P] stride 640; fp16 KVh [K|V] 256.
// lane = h*8 + p; lane owns j = 2p, 2p+1 of head h. 2-way edge unroll.
// ---------------------------------------------------------------------------
__global__ void agg1_kernel(const float* __restrict__ OUT1, const _Float16* __restrict__ KVh,
                            const int* __restrict__ row_start,
                            const int* __restrict__ se, const float* __restrict__ eac,
                            const float* __restrict__ We1, float* __restrict__ h1)
{
    __shared__ float we[16 * 128];
    int t = threadIdx.x;
    for (int i = t; i < 2048; i += 256) we[i] = We1[i];
    __syncthreads();
    int bid = xcd_swz(blockIdx.x, gridDim.x);
    int wv = t >> 6, l = t & 63;
    int n = bid * 4 + wv;
    if (n >= NN) return;
    int h = l >> 3, p = l & 7;
    int j0 = p * 2;
    const float* qb = OUT1 + (size_t)n * 640;
    float2 q = *(const float2*)(qb + h * 16 + j0);
    float2 P = *(const float2*)(qb + 512 + h * 16 + j0);
    float2 accv = make_float2(0.f, 0.f), acce = make_float2(0.f, 0.f);
    float denom = 0.f;
    int e0 = row_start[n], e1 = row_start[n + 1];
    int idx = e0;
    for (; idx + 1 < e1; idx += 2) {
        int sA = se[idx], sB = se[idx + 1];
        const _Float16* kvA = KVh + (size_t)sA * 256;
        const _Float16* kvB = KVh + (size_t)sB * 256;
        h16x2 kAh = *(const h16x2*)(kvA + h * 16 + j0);
        h16x2 vAh = *(const h16x2*)(kvA + 128 + h * 16 + j0);
        float2 eA = *(const float2*)(eac + (size_t)idx * 16 + j0);
        h16x2 kBh = *(const h16x2*)(kvB + h * 16 + j0);
        h16x2 vBh = *(const h16x2*)(kvB + 128 + h * 16 + j0);
        float2 eB = *(const float2*)(eac + (size_t)(idx + 1) * 16 + j0);
        float pa = q.x * (float)kAh[0] + q.y * (float)kAh[1] + P.x * eA.x + P.y * eA.y;
        float pb = q.x * (float)kBh[0] + q.y * (float)kBh[1] + P.x * eB.x + P.y * eB.y;
        pa += __shfl_xor(pa, 1, 64); pb += __shfl_xor(pb, 1, 64);
        pa += __shfl_xor(pa, 2, 64); pb += __shfl_xor(pb, 2, 64);
        pa += __shfl_xor(pa, 4, 64); pb += __shfl_xor(pb, 4, 64);
        float wA = __expf(pa * 0.25f);
        float wB = __expf(pb * 0.25f);
        denom += wA + wB;
        accv.x += wA * (float)vAh[0] + wB * (float)vBh[0];
        accv.y += wA * (float)vAh[1] + wB * (float)vBh[1];
        acce.x += wA * eA.x + wB * eB.x;
        acce.y += wA * eA.y + wB * eB.y;
    }
    if (idx < e1) {
        int s = se[idx];
        const _Float16* kvb = KVh + (size_t)s * 256;
        h16x2 kk = *(const h16x2*)(kvb + h * 16 + j0);
        h16x2 vv = *(const h16x2*)(kvb + 128 + h * 16 + j0);
        float2 ee = *(const float2*)(eac + (size_t)idx * 16 + j0);
        float part = q.x * (float)kk[0] + q.y * (float)kk[1] + P.x * ee.x + P.y * ee.y;
        part += __shfl_xor(part, 1, 64);
        part += __shfl_xor(part, 2, 64);
        part += __shfl_xor(part, 4, 64);
        float w = __expf(part * 0.25f);
        denom += w;
        accv.x += w * (float)vv[0]; accv.y += w * (float)vv[1];
        acce.x += w * ee.x; acce.y += w * ee.y;
    }
    float inv = (denom > 0.f) ? 1.f / denom : 0.f;
    float es0 = 0.f, es1 = 0.f;
    int gbase = h * 8;
    #pragma unroll
    for (int dd = 0; dd < 8; ++dd) {
        float a0 = __shfl(acce.x, gbase + dd, 64);
        float a1 = __shfl(acce.y, gbase + dd, 64);
        es0 += a0 * we[(2 * dd) * 128 + h * 16 + j0]     + a1 * we[(2 * dd + 1) * 128 + h * 16 + j0];
        es1 += a0 * we[(2 * dd) * 128 + h * 16 + j0 + 1] + a1 * we[(2 * dd + 1) * 128 + h * 16 + j0 + 1];
    }
    float2 sk = *(const float2*)(qb + 384 + h * 16 + j0);
    float o0 = (accv.x + es0) * inv + sk.x;
    float o1 = (accv.y + es1) * inv + sk.y;
    o0 = (o0 > 0.f) ? o0 : 0.01f * o0;
    o1 = (o1 > 0.f) ? o1 : 0.01f * o1;
    *(float2*)(h1 + (size_t)n * 128 + h * 16 + j0) = make_float2(o0, o1);
}

// ---------------------------------------------------------------------------
// agg2: wave per node, half-wave per edge. f32 OUT2 [Q|-|-|S|P2] stride 528;
// fp16 KVh [K|V] 256. lane = half*32 + c; lane owns dims {c,c+32,c+64,c+96}.
// ---------------------------------------------------------------------------
__global__ void agg2_kernel(const float* __restrict__ OUT2, const _Float16* __restrict__ KVh,
                            const int* __restrict__ row_start,
                            const int* __restrict__ se, const float* __restrict__ eac,
                            const float* __restrict__ We2, float* __restrict__ h2)
{
    int bid = xcd_swz(blockIdx.x, gridDim.x);
    int t = threadIdx.x;
    int wv = t >> 6, l = t & 63;
    int n = bid * 4 + wv;
    if (n >= NN) return;
    int half = l >> 5, c = l & 31;
    const float* base = OUT2 + (size_t)n * 528;
    float q0 = base[c], q1 = base[32 + c], q2 = base[64 + c], q3 = base[96 + c];
    float p2 = (c < 16) ? base[512 + c] : 0.f;
    float av0 = 0.f, av1 = 0.f, av2 = 0.f, av3 = 0.f, ae = 0.f, denom = 0.f;
    int e0 = row_start[n], e1 = row_start[n + 1];
    for (int idx = e0 + half; idx < e1; idx += 2) {
        int s = se[idx];
        const _Float16* kb = KVh + (size_t)s * 256;
        float k0 = (float)kb[c], k1 = (float)kb[32 + c];
        float k2 = (float)kb[64 + c], k3 = (float)kb[96 + c];
        float v0 = (float)kb[128 + c], v1 = (float)kb[160 + c];
        float v2 = (float)kb[192 + c], v3 = (float)kb[224 + c];
        float eav = (c < 16) ? eac[(size_t)idx * 16 + c] : 0.f;
        float part = q0 * k0 + q1 * k1 + q2 * k2 + q3 * k3 + p2 * eav;
        part += __shfl_xor(part, 1, 64);
        part += __shfl_xor(part, 2, 64);
        part += __shfl_xor(part, 4, 64);
        part += __shfl_xor(part, 8, 64);
        part += __shfl_xor(part, 16, 64);
        float w = __expf(part * 0.08838834764831845f);  // 1/sqrt(128)
        denom += w;
        av0 += w * v0; av1 += w * v1; av2 += w * v2; av3 += w * v3;
        ae += w * eav;
    }
    denom += __shfl_xor(denom, 32, 64);
    av0 += __shfl_xor(av0, 32, 64);
    av1 += __shfl_xor(av1, 32, 64);
    av2 += __shfl_xor(av2, 32, 64);
    av3 += __shfl_xor(av3, 32, 64);
    ae  += __shfl_xor(ae, 32, 64);
    float inv = (denom > 0.f) ? 1.f / denom : 0.f;
    float t0 = 0.f, t1 = 0.f, t2 = 0.f, t3 = 0.f;
    #pragma unroll
    for (int d = 0; d < 16; ++d) {
        float aed = __shfl(ae, d, 64);
        t0 += aed * We2[d * 128 + c];
        t1 += aed * We2[d * 128 + 32 + c];
        t2 += aed * We2[d * 128 + 64 + c];
        t3 += aed * We2[d * 128 + 96 + c];
    }
    if (half == 0) {
        float* hp = h2 + (size_t)n * 128;
        hp[c]      = (av0 + t0) * inv + base[384 + c];
        hp[32 + c] = (av1 + t1) * inv + base[416 + c];
        hp[64 + c] = (av2 + t2) * inv + base[448 + c];
        hp[96 + c] = (av3 + t3) * inv + base[480 + c];
    }
}

// ---------------------------------------------------------------------------
// pooling: sorted batch -> register-accumulated flushes
// ---------------------------------------------------------------------------
__global__ void pool_kernel(const float* __restrict__ h2, const int* __restrict__ batch,
                            float* __restrict__ sums, float* __restrict__ cnt)
{
    int t = threadIdx.x;
    int c = t & 127, half = t >> 7;
    int n0 = blockIdx.x * 64;
    float acc = 0.f, cacc = 0.f;
    int curg = -1;
    for (int r = half; r < 64; r += 2) {
        int n = n0 + r;
        if (n >= NN) break;
        int g = batch[n];
        if (g != curg) {
            if (curg >= 0) {
                atomicAdd(&sums[curg * 128 + c], acc);
                if (c == 0) atomicAdd(&cnt[curg], cacc);
            }
            curg = g; acc = 0.f; cacc = 0.f;
        }
        acc += h2[(size_t)n * 128 + c];
        cacc += 1.f;
    }
    if (curg >= 0) {
        atomicAdd(&sums[curg * 128 + c], acc);
        if (c == 0) atomicAdd(&cnt[curg], cacc);
    }
}

// Gp[g,c] = b1[c] + sum_m pool[g,m] * W1[272+m, c]
__global__ void gp_kernel(const float* __restrict__ sums, const float* __restrict__ cnt,
                          const float* __restrict__ W1, const float* __restrict__ b1,
                          float* __restrict__ Gp)
{
    __shared__ float pr[128];
    int g = blockIdx.x, c = threadIdx.x;
    float inv = 1.f / fmaxf(cnt[g], 1.f);
    pr[c] = sums[g * 128 + c] * inv;
    __syncthreads();
    float acc = b1[c];
    for (int m = 0; m < 128; ++m) acc += pr[m] * W1[(272 + m) * 128 + c];
    Gp[g * 128 + c] = acc;
}

// ---------------------------------------------------------------------------
// final: half-wave per CSR slot; fp16 ABh [A|B] stride 256.
// hid = A[s] + B[d] + Gp[batch[s]] + ea@W1c; relu; dot W2
// ---------------------------------------------------------------------------
__global__ void edge_out_kernel(const _Float16* __restrict__ ABh, const float* __restrict__ Gp,
                                const int* __restrict__ eid, const int* __restrict__ se,
                                const int* __restrict__ de, const float* __restrict__ eac,
                                const int* __restrict__ batch,
                                const float* __restrict__ W1, const float* __restrict__ W2,
                                const float* __restrict__ b2, float* __restrict__ out)
{
    __shared__ float w1c[16 * 128];
    __shared__ float w2s[128];
    int t = threadIdx.x;
    for (int i = t; i < 2048; i += 256) w1c[i] = W1[(size_t)(256 + (i >> 7)) * 128 + (i & 127)];
    if (t < 128) w2s[t] = W2[t];
    __syncthreads();
    int bid = xcd_swz(blockIdx.x, gridDim.x);
    int wv = t >> 6, l = t & 63;
    int half = l >> 5, c = l & 31;
    int idx = bid * 8 + wv * 2 + half;   // NE == gridDim*8 exactly
    int e = eid[idx];
    int s = se[idx], d = de[idx], g = batch[s];
    const _Float16* As = ABh + (size_t)s * 256;
    const _Float16* Bd = ABh + (size_t)d * 256 + 128;
    const float* Gg = Gp + g * 128;
    float h0  = (float)As[c]      + (float)Bd[c]      + Gg[c];
    float h1v = (float)As[32 + c] + (float)Bd[32 + c] + Gg[32 + c];
    float h2v = (float)As[64 + c] + (float)Bd[64 + c] + Gg[64 + c];
    float h3v = (float)As[96 + c] + (float)Bd[96 + c] + Gg[96 + c];
    float eal = (c < 16) ? eac[(size_t)idx * 16 + c] : 0.f;
    int sbase = half << 5;
    #pragma unroll
    for (int d16 = 0; d16 < 16; ++d16) {
        float ev = __shfl(eal, sbase + d16, 64);
        h0  += ev * w1c[d16 * 128 + c];
        h1v += ev * w1c[d16 * 128 + 32 + c];
        h2v += ev * w1c[d16 * 128 + 64 + c];
        h3v += ev * w1c[d16 * 128 + 96 + c];
    }
    h0 = fmaxf(h0, 0.f); h1v = fmaxf(h1v, 0.f);
    h2v = fmaxf(h2v, 0.f); h3v = fmaxf(h3v, 0.f);
    float r = h0 * w2s[c] + h1v * w2s[32 + c] + h2v * w2s[64 + c] + h3v * w2s[96 + c];
    r += __shfl_xor(r, 1, 64);
    r += __shfl_xor(r, 2, 64);
    r += __shfl_xor(r, 4, 64);
    r += __shfl_xor(r, 8, 64);
    r += __shfl_xor(r, 16, 64);
    if (c == 0) out[e] = r + b2[0];
}

// ---------------------------------------------------------------------------
extern "C" void kernel_launch(void* const* d_in, const int* in_sizes, int n_in,
                              void* d_out, int out_size, void* d_ws, size_t ws_size,
                              hipStream_t stream)
{
    const float* x   = (const float*)d_in[0];
    const int* ei    = (const int*)d_in[1];
    const float* ea  = (const float*)d_in[2];
    const int* batch = (const int*)d_in[3];
    const float* Wq1 = (const float*)d_in[4];  const float* bq1 = (const float*)d_in[5];
    const float* Wk1 = (const float*)d_in[6];  const float* bk1 = (const float*)d_in[7];
    const float* Wv1 = (const float*)d_in[8];  const float* bv1 = (const float*)d_in[9];
    const float* We1 = (const float*)d_in[10];
    const float* Ws1 = (const float*)d_in[11]; const float* bs1 = (const float*)d_in[12];
    const float* Wq2 = (const float*)d_in[13]; const float* bq2 = (const float*)d_in[14];
    const float* Wk2 = (const float*)d_in[15]; const float* bk2 = (const float*)d_in[16];
    const float* Wv2 = (const float*)d_in[17]; const float* bv2 = (const float*)d_in[18];
    const float* We2 = (const float*)d_in[19];
    const float* Ws2 = (const float*)d_in[20]; const float* bs2 = (const float*)d_in[21];
    const float* W1  = (const float*)d_in[22]; const float* b1  = (const float*)d_in[23];
    const float* W2  = (const float*)d_in[24]; const float* b2  = (const float*)d_in[25];

    const int* src = ei;
    const int* dst = ei + NE;

    float* ws = (float*)d_ws;
    size_t off = 0;
    float* OUT  = ws + off; off += (size_t)NN * 640;  // OUT1(640)/OUT2(528); ABh aliases front
    float* h1   = ws + off; off += (size_t)NN * 128;
    float* h2   = ws + off; off += (size_t)NN * 128;
    float* eac  = ws + off; off += (size_t)NE * 16;
    _Float16* KVh = (_Float16*)(ws + off); off += (size_t)NN * 128;  // N x 256 half
    float* sums = ws + off; off += NG * 128;
    float* cntf = ws + off; off += NG;
    float* Gp   = ws + off; off += NG * 128;
    float* Wp1  = ws + off; off += 64 * 128;
    float* Wp2  = ws + off; off += 128 * 16;
    float* bcat1 = ws + off; off += 640;
    float* bcat2 = ws + off; off += 528;
    __bf16* pk  = (__bf16*)(ws + off); off += 276 * 1024 / 2;  // 276 blocks x 1024 bf16
    int* cnt_arr   = (int*)(ws + off); off += NN;
    int* row_start = (int*)(ws + off); off += NN + 1;
    int* cursor    = (int*)(ws + off); off += NN;
    int* eid       = (int*)(ws + off); off += NE;
    int* se        = (int*)(ws + off); off += NE;
    int* de        = (int*)(ws + off); off += NE;
    int* bsum      = (int*)(ws + off); off += 64;
    int* boff      = (int*)(ws + off); off += 64;
    _Float16* ABh = (_Float16*)OUT;   // alias: OUT dead after agg2; gemm3 writes fp16 only

    hipMemsetAsync(cnt_arr, 0, NN * sizeof(int), stream);
    hipMemsetAsync(sums, 0, (NG * 128 + NG) * sizeof(float), stream);

    prep_kernel<<<45, 256, 0, stream>>>(Wq1, bq1, bk1, bv1, bs1, We1,
                                        Wq2, bq2, bk2, bv2, bs2, We2,
                                        Wp1, Wp2, bcat1, bcat2);
    pack_kernel<<<276, 256, 0, stream>>>(Wq1, Wk1, Wv1, Ws1, Wp1,
                                         Wq2, Wk2, Wv2, Ws2, Wp2, W1, pk);
    count_kernel<<<(NE + 255) / 256, 256, 0, stream>>>(dst, cnt_arr);
    scanA_kernel<<<SCAN_B, 1024, 0, stream>>>(cnt_arr, row_start, bsum);
    scanB_kernel<<<1, 64, 0, stream>>>(bsum, boff);
    scanC_kernel<<<SCAN_B, 1024, 0, stream>>>(row_start, boff, cursor);
    scatter_kernel<<<(NE + 255) / 256, 256, 0, stream>>>(src, dst, cursor, eid, se, de);
    eacopy_kernel<<<NE * 16 / 256, 256, 0, stream>>>(eid, ea, eac);

    mfma_gemm_kernel<64, 40, true, 128, 384><<<(NN + 127) / 128, 256, 0, stream>>>(
        x, pk, bcat1, OUT, 640, KVh);
    agg1_kernel<<<(NN + 3) / 4, 256, 0, stream>>>(OUT, KVh, row_start, se, eac, We1, h1);
    mfma_gemm_kernel<128, 33, true, 128, 384><<<(NN + 127) / 128, 256, 0, stream>>>(
        h1, pk + (size_t)80 * 1024, bcat2, OUT, 528, KVh);
    agg2_kernel<<<(NN + 3) / 4, 256, 0, stream>>>(OUT, KVh, row_start, se, eac, We2, h2);
    pool_kernel<<<(NN + 63) / 64, 256, 0, stream>>>(h2, batch, sums, cntf);
    gp_kernel<<<NG, 128, 0, stream>>>(sums, cntf, W1, b1, Gp);
    mfma_gemm_kernel<128, 16, false, 0, 256><<<(NN + 127) / 128, 256, 0, stream>>>(
        h2, pk + (size_t)212 * 1024, nullptr, nullptr, 0, ABh);
    edge_out_kernel<<<NE / 8, 256, 0, stream>>>(ABh, Gp, eid, se, de, eac, batch,
                                                W1, W2, b2, (float*)d_out);
}

// Round 6
// 454.651 us; speedup vs baseline: 2.1990x; 1.0624x over previous
//
#include <hip/hip_runtime.h>
#include <math.h>

#define NN 50000
#define NE 400000
#define NG 128
#define SCAN_B 49   // ceil(NN/1024)

typedef __bf16 bf16x8 __attribute__((ext_vector_type(8)));
typedef float f32x4 __attribute__((ext_vector_type(4)));
typedef _Float16 h16x2 __attribute__((ext_vector_type(2)));

// bijective XCD-chunked swizzle (m204): each XCD gets a contiguous chunk
__device__ __forceinline__ int xcd_swz(int bid, int nwg)
{
    int q = nwg >> 3, r = nwg & 7;
    int xcd = bid & 7, off = bid >> 3;
    return (xcd < r ? xcd * (q + 1) : r * (q + 1) + (xcd - r) * q) + off;
}

// ---------------------------------------------------------------------------
// prep: fused weights Wp1[64,128], Wp2[128,16]; concatenated biases
// ---------------------------------------------------------------------------
__global__ void prep_kernel(const float* __restrict__ Wq1, const float* __restrict__ bq1,
                            const float* __restrict__ bk1, const float* __restrict__ bv1,
                            const float* __restrict__ bs1, const float* __restrict__ We1,
                            const float* __restrict__ Wq2, const float* __restrict__ bq2,
                            const float* __restrict__ bk2, const float* __restrict__ bv2,
                            const float* __restrict__ bs2, const float* __restrict__ We2,
                            float* __restrict__ Wp1, float* __restrict__ Wp2,
                            float* __restrict__ bcat1, float* __restrict__ bcat2)
{
    int idx = blockIdx.x * blockDim.x + threadIdx.x;
    if (idx < 8192) {                       // Wp1[64,128]
        int m = idx >> 7, c = idx & 127;
        int h = c >> 4, d = c & 15;
        float s = 0.f;
        #pragma unroll
        for (int j = 0; j < 16; ++j)
            s += Wq1[m * 128 + h * 16 + j] * We1[d * 128 + h * 16 + j];
        Wp1[idx] = s;
    } else if (idx < 8320) {                // bp1 -> bcat1[512..640)
        int c = idx - 8192;
        int h = c >> 4, d = c & 15;
        float s = 0.f;
        #pragma unroll
        for (int j = 0; j < 16; ++j)
            s += bq1[h * 16 + j] * We1[d * 128 + h * 16 + j];
        bcat1[512 + c] = s;
    } else if (idx < 10368) {               // Wp2[128,16]
        int i = idx - 8320;
        int m = i >> 4, d = i & 15;
        float s = 0.f;
        for (int j = 0; j < 128; ++j)
            s += Wq2[m * 128 + j] * We2[d * 128 + j];
        Wp2[m * 16 + d] = s;
    } else if (idx < 10384) {               // bp2 -> bcat2[512..528)
        int d = idx - 10368;
        float s = 0.f;
        for (int j = 0; j < 128; ++j)
            s += bq2[j] * We2[d * 128 + j];
        bcat2[512 + d] = s;
    } else if (idx < 10896) {               // bcat1[0..512)
        int i = idx - 10384;
        int seg = i >> 7, c = i & 127;
        const float* b = (seg == 0) ? bq1 : (seg == 1) ? bk1 : (seg == 2) ? bv1 : bs1;
        bcat1[i] = b[c];
    } else if (idx < 11408) {               // bcat2[0..512)
        int i = idx - 10896;
        int seg = i >> 7, c = i & 127;
        const float* b = (seg == 0) ? bq2 : (seg == 1) ? bk2 : (seg == 2) ? bv2 : bs2;
        bcat2[i] = b[c];
    }
}

// ---------------------------------------------------------------------------
// pack: MFMA fragment-ready hi/lo bf16 weight blocks (see R3 layout comments)
// ---------------------------------------------------------------------------
__global__ void pack_kernel(const float* __restrict__ Wq1, const float* __restrict__ Wk1,
                            const float* __restrict__ Wv1, const float* __restrict__ Ws1,
                            const float* __restrict__ Wp1,
                            const float* __restrict__ Wq2, const float* __restrict__ Wk2,
                            const float* __restrict__ Wv2, const float* __restrict__ Ws2,
                            const float* __restrict__ Wp2,
                            const float* __restrict__ W1,
                            __bf16* __restrict__ pk)
{
    int b = blockIdx.x;
    int mat, kt, ct;
    if (b < 80)       { mat = 0; kt = b / 40;        ct = b % 40; }
    else if (b < 212) { mat = 1; kt = (b - 80) / 33; ct = (b - 80) % 33; }
    else              { mat = 2; kt = (b - 212) / 16; ct = (b - 212) % 16; }
    __bf16* blkp = pk + (size_t)b * 1024;
    for (int item = threadIdx.x; item < 512; item += 256) {
        int lane = item >> 3, j = item & 7;
        int k = kt * 32 + (lane >> 4) * 8 + j;
        int col = ct * 16 + (lane & 15);
        float v;
        if (mat == 0) {
            int seg = col >> 7, cc = col & 127;
            const float* W = (seg == 0) ? Wq1 : (seg == 1) ? Wk1 : (seg == 2) ? Wv1
                             : (seg == 3) ? Ws1 : Wp1;
            v = W[k * 128 + cc];
        } else if (mat == 1) {
            if (col < 512) {
                int seg = col >> 7, cc = col & 127;
                const float* W = (seg == 0) ? Wq2 : (seg == 1) ? Wk2 : (seg == 2) ? Wv2 : Ws2;
                v = W[k * 128 + cc];
            } else {
                v = Wp2[k * 16 + (col - 512)];
            }
        } else {
            v = (col < 128) ? W1[k * 128 + col] : W1[(size_t)(128 + k) * 128 + (col - 128)];
        }
        __bf16 h = (__bf16)v;
        __bf16 lo = (__bf16)(v - (float)h);
        blkp[lane * 8 + j] = h;
        blkp[512 + lane * 8 + j] = lo;
    }
}

// ---------------------------------------------------------------------------
// CSR build by dst — count, 3-phase parallel scan, scatter, ea copy
// ---------------------------------------------------------------------------
__global__ void count_kernel(const int* __restrict__ dst, int* __restrict__ counts)
{
    int e = blockIdx.x * blockDim.x + threadIdx.x;
    if (e < NE) atomicAdd(&counts[dst[e]], 1);
}

__global__ void scanA_kernel(const int* __restrict__ counts,
                             int* __restrict__ row_start, int* __restrict__ bsum)
{
    __shared__ int lds[1024];
    int t = threadIdx.x, b = blockIdx.x;
    int i = b * 1024 + t;
    int v = (i < NN) ? counts[i] : 0;
    lds[t] = v;
    __syncthreads();
    for (int off = 1; off < 1024; off <<= 1) {
        int u = (t >= off) ? lds[t - off] : 0;
        __syncthreads();
        lds[t] += u;
        __syncthreads();
    }
    if (i < NN) row_start[i] = lds[t] - v;     // block-local exclusive
    if (t == 1023) bsum[b] = lds[1023];
}

__global__ void scanB_kernel(const int* __restrict__ bsum, int* __restrict__ boff)
{
    int t = threadIdx.x;  // 64 lanes
    int orig = (t < SCAN_B) ? bsum[t] : 0;
    int v = orig;
    #pragma unroll
    for (int off = 1; off < 64; off <<= 1) {
        int u = __shfl_up(v, off, 64);
        if (t >= off) v += u;
    }
    if (t < SCAN_B) boff[t] = v - orig;        // exclusive
}

__global__ void scanC_kernel(int* __restrict__ row_start, const int* __restrict__ boff,
                             int* __restrict__ cursor)
{
    int i = blockIdx.x * 1024 + threadIdx.x;
    if (i < NN) {
        int rs = row_start[i] + boff[blockIdx.x];
        row_start[i] = rs;
        cursor[i] = rs;
    }
    if (i == 0) row_start[NN] = NE;
}

__global__ void scatter_kernel(const int* __restrict__ src, const int* __restrict__ dst,
                               const int* __restrict__ batch,
                               int* __restrict__ cursor, int* __restrict__ eid,
                               int* __restrict__ se, int* __restrict__ de,
                               int* __restrict__ gb)
{
    int e = blockIdx.x * blockDim.x + threadIdx.x;
    if (e < NE) {
        int d = dst[e];
        int s = src[e];
        int p = atomicAdd(&cursor[d], 1);
        eid[p] = e;
        se[p] = s;
        de[p] = d;
        gb[p] = batch[s];
    }
}

__global__ void eacopy_kernel(const int* __restrict__ eid, const float* __restrict__ ea,
                              float* __restrict__ eac)
{
    int g = blockIdx.x * blockDim.x + threadIdx.x;  // NE*16 threads
    int idx = g >> 4, c = g & 15;
    eac[g] = ea[(size_t)eid[idx] * 16 + c];
}

// ---------------------------------------------------------------------------
// MFMA GEMM, split-bf16 3-term. Columns in [CLO,CHI) go to fp16 aux buffer
// (width CHI-CLO); other columns to fp32 out (stride ldo).
// ---------------------------------------------------------------------------
__device__ __forceinline__ void load_split(const float* ap, bool ok,
                                           bf16x8& hv, bf16x8& lv)
{
    float av[8];
    if (ok) {
        float4 f0 = *(const float4*)ap;
        float4 f1 = *(const float4*)(ap + 4);
        av[0] = f0.x; av[1] = f0.y; av[2] = f0.z; av[3] = f0.w;
        av[4] = f1.x; av[5] = f1.y; av[6] = f1.z; av[7] = f1.w;
    } else {
        #pragma unroll
        for (int j = 0; j < 8; ++j) av[j] = 0.f;
    }
    #pragma unroll
    for (int j = 0; j < 8; ++j) {
        __bf16 h = (__bf16)av[j];
        hv[j] = h;
        lv[j] = (__bf16)(av[j] - (float)h);
    }
}

template<int KD, int NCT, bool BIAS, int CLO, int CHI>
__global__ void mfma_gemm_kernel(const float* __restrict__ A, const __bf16* __restrict__ pk,
                                 const float* __restrict__ bias, float* __restrict__ out,
                                 int ldo, _Float16* __restrict__ auxh)
{
    constexpr int NKT = KD / 32;
    constexpr int AUXW = CHI - CLO;
    int t = threadIdx.x, w = t >> 6, l = t & 63;
    int rbase = blockIdx.x * 128 + w * 32;
    int lr = l & 15, kq = l >> 4;
    int r0 = rbase + lr, r1 = rbase + 16 + lr;
    bool ok0 = r0 < NN, ok1 = r1 < NN;
    bf16x8 ah0[NKT], al0[NKT], ah1[NKT], al1[NKT];
    #pragma unroll
    for (int kt = 0; kt < NKT; ++kt) {
        load_split(A + (size_t)r0 * KD + kt * 32 + kq * 8, ok0, ah0[kt], al0[kt]);
        load_split(A + (size_t)r1 * KD + kt * 32 + kq * 8, ok1, ah1[kt], al1[kt]);
    }
    for (int ct = 0; ct < NCT; ++ct) {
        float b = BIAS ? bias[ct * 16 + lr] : 0.f;
        f32x4 acc0 = {b, b, b, b};
        f32x4 acc1 = {b, b, b, b};
        const __bf16* blk = pk + (size_t)ct * 1024;
        #pragma unroll
        for (int kt = 0; kt < NKT; ++kt) {
            bf16x8 bh = *(const bf16x8*)(blk + (size_t)kt * NCT * 1024 + l * 8);
            bf16x8 bl = *(const bf16x8*)(blk + (size_t)kt * NCT * 1024 + 512 + l * 8);
            acc0 = __builtin_amdgcn_mfma_f32_16x16x32_bf16(al0[kt], bh, acc0, 0, 0, 0);
            acc1 = __builtin_amdgcn_mfma_f32_16x16x32_bf16(al1[kt], bh, acc1, 0, 0, 0);
            acc0 = __builtin_amdgcn_mfma_f32_16x16x32_bf16(ah0[kt], bl, acc0, 0, 0, 0);
            acc1 = __builtin_amdgcn_mfma_f32_16x16x32_bf16(ah1[kt], bl, acc1, 0, 0, 0);
            acc0 = __builtin_amdgcn_mfma_f32_16x16x32_bf16(ah0[kt], bh, acc0, 0, 0, 0);
            acc1 = __builtin_amdgcn_mfma_f32_16x16x32_bf16(ah1[kt], bh, acc1, 0, 0, 0);
        }
        int col = ct * 16 + lr;
        bool inAux = (col >= CLO) && (col < CHI);
        #pragma unroll
        for (int i = 0; i < 4; ++i) {
            int ra = rbase + kq * 4 + i;
            int rb = ra + 16;
            if (ra < NN) {
                if (inAux) auxh[(size_t)ra * AUXW + (col - CLO)] = (_Float16)acc0[i];
                else       out[(size_t)ra * ldo + col] = acc0[i];
            }
            if (rb < NN) {
                if (inAux) auxh[(size_t)rb * AUXW + (col - CLO)] = (_Float16)acc1[i];
                else       out[(size_t)rb * ldo + col] = acc1[i];
            }
        }
    }
}

// ---------------------------------------------------------------------------
// agg1: wave per node. f32 OUT1 row [Q|-|-|S|P] stride 640; fp16 KVh [K|V] 256.
// lane = h*8 + p; lane owns j = 2p, 2p+1 of head h. 2-way edge unroll.
// ---------------------------------------------------------------------------
__global__ void agg1_kernel(const float* __restrict__ OUT1, const _Float16* __restrict__ KVh,
                            const int* __restrict__ row_start,
                            const int* __restrict__ se, const float* __restrict__ eac,
                            const float* __restrict__ We1, float* __restrict__ h1)
{
    __shared__ float we[16 * 128];
    int t = threadIdx.x;
    for (int i = t; i < 2048; i += 256) we[i] = We1[i];
    __syncthreads();
    int bid = xcd_swz(blockIdx.x, gridDim.x);
    int wv = t >> 6, l = t & 63;
    int n = bid * 4 + wv;
    if (n >= NN) return;
    int h = l >> 3, p = l & 7;
    int j0 = p * 2;
    const float* qb = OUT1 + (size_t)n * 640;
    float2 q = *(const float2*)(qb + h * 16 + j0);
    float2 P = *(const float2*)(qb + 512 + h * 16 + j0);
    float2 accv = make_float2(0.f, 0.f), acce = make_float2(0.f, 0.f);
    float denom = 0.f;
    int e0 = row_start[n], e1 = row_start[n + 1];
    int idx = e0;
    for (; idx + 1 < e1; idx += 2) {
        int sA = se[idx], sB = se[idx + 1];
        const _Float16* kvA = KVh + (size_t)sA * 256;
        const _Float16* kvB = KVh + (size_t)sB * 256;
        h16x2 kAh = *(const h16x2*)(kvA + h * 16 + j0);
        h16x2 vAh = *(const h16x2*)(kvA + 128 + h * 16 + j0);
        float2 eA = *(const float2*)(eac + (size_t)idx * 16 + j0);
        h16x2 kBh = *(const h16x2*)(kvB + h * 16 + j0);
        h16x2 vBh = *(const h16x2*)(kvB + 128 + h * 16 + j0);
        float2 eB = *(const float2*)(eac + (size_t)(idx + 1) * 16 + j0);
        float pa = q.x * (float)kAh[0] + q.y * (float)kAh[1] + P.x * eA.x + P.y * eA.y;
        float pb = q.x * (float)kBh[0] + q.y * (float)kBh[1] + P.x * eB.x + P.y * eB.y;
        pa += __shfl_xor(pa, 1, 64); pb += __shfl_xor(pb, 1, 64);
        pa += __shfl_xor(pa, 2, 64); pb += __shfl_xor(pb, 2, 64);
        pa += __shfl_xor(pa, 4, 64); pb += __shfl_xor(pb, 4, 64);
        float wA = __expf(pa * 0.25f);
        float wB = __expf(pb * 0.25f);
        denom += wA + wB;
        accv.x += wA * (float)vAh[0] + wB * (float)vBh[0];
        accv.y += wA * (float)vAh[1] + wB * (float)vBh[1];
        acce.x += wA * eA.x + wB * eB.x;
        acce.y += wA * eA.y + wB * eB.y;
    }
    if (idx < e1) {
        int s = se[idx];
        const _Float16* kvb = KVh + (size_t)s * 256;
        h16x2 kk = *(const h16x2*)(kvb + h * 16 + j0);
        h16x2 vv = *(const h16x2*)(kvb + 128 + h * 16 + j0);
        float2 ee = *(const float2*)(eac + (size_t)idx * 16 + j0);
        float part = q.x * (float)kk[0] + q.y * (float)kk[1] + P.x * ee.x + P.y * ee.y;
        part += __shfl_xor(part, 1, 64);
        part += __shfl_xor(part, 2, 64);
        part += __shfl_xor(part, 4, 64);
        float w = __expf(part * 0.25f);
        denom += w;
        accv.x += w * (float)vv[0]; accv.y += w * (float)vv[1];
        acce.x += w * ee.x; acce.y += w * ee.y;
    }
    float inv = (denom > 0.f) ? 1.f / denom : 0.f;
    float es0 = 0.f, es1 = 0.f;
    int gbase = h * 8;
    #pragma unroll
    for (int dd = 0; dd < 8; ++dd) {
        float a0 = __shfl(acce.x, gbase + dd, 64);
        float a1 = __shfl(acce.y, gbase + dd, 64);
        es0 += a0 * we[(2 * dd) * 128 + h * 16 + j0]     + a1 * we[(2 * dd + 1) * 128 + h * 16 + j0];
        es1 += a0 * we[(2 * dd) * 128 + h * 16 + j0 + 1] + a1 * we[(2 * dd + 1) * 128 + h * 16 + j0 + 1];
    }
    float2 sk = *(const float2*)(qb + 384 + h * 16 + j0);
    float o0 = (accv.x + es0) * inv + sk.x;
    float o1 = (accv.y + es1) * inv + sk.y;
    o0 = (o0 > 0.f) ? o0 : 0.01f * o0;
    o1 = (o1 > 0.f) ? o1 : 0.01f * o1;
    *(float2*)(h1 + (size_t)n * 128 + h * 16 + j0) = make_float2(o0, o1);
}

// ---------------------------------------------------------------------------
// agg2: wave per node, half-wave per edge. f32 OUT2 [Q|-|-|S|P2] stride 528;
// fp16 KVh [K|V] 256. lane = half*32 + c; lane owns dims {c,c+32,c+64,c+96}.
// ---------------------------------------------------------------------------
__global__ void agg2_kernel(const float* __restrict__ OUT2, const _Float16* __restrict__ KVh,
                            const int* __restrict__ row_start,
                            const int* __restrict__ se, const float* __restrict__ eac,
                            const float* __restrict__ We2, float* __restrict__ h2)
{
    int bid = xcd_swz(blockIdx.x, gridDim.x);
    int t = threadIdx.x;
    int wv = t >> 6, l = t & 63;
    int n = bid * 4 + wv;
    if (n >= NN) return;
    int half = l >> 5, c = l & 31;
    const float* base = OUT2 + (size_t)n * 528;
    float q0 = base[c], q1 = base[32 + c], q2 = base[64 + c], q3 = base[96 + c];
    float p2 = (c < 16) ? base[512 + c] : 0.f;
    float av0 = 0.f, av1 = 0.f, av2 = 0.f, av3 = 0.f, ae = 0.f, denom = 0.f;
    int e0 = row_start[n], e1 = row_start[n + 1];
    for (int idx = e0 + half; idx < e1; idx += 2) {
        int s = se[idx];
        const _Float16* kb = KVh + (size_t)s * 256;
        float k0 = (float)kb[c], k1 = (float)kb[32 + c];
        float k2 = (float)kb[64 + c], k3 = (float)kb[96 + c];
        float v0 = (float)kb[128 + c], v1 = (float)kb[160 + c];
        float v2 = (float)kb[192 + c], v3 = (float)kb[224 + c];
        float eav = (c < 16) ? eac[(size_t)idx * 16 + c] : 0.f;
        float part = q0 * k0 + q1 * k1 + q2 * k2 + q3 * k3 + p2 * eav;
        part += __shfl_xor(part, 1, 64);
        part += __shfl_xor(part, 2, 64);
        part += __shfl_xor(part, 4, 64);
        part += __shfl_xor(part, 8, 64);
        part += __shfl_xor(part, 16, 64);
        float w = __expf(part * 0.08838834764831845f);  // 1/sqrt(128)
        denom += w;
        av0 += w * v0; av1 += w * v1; av2 += w * v2; av3 += w * v3;
        ae += w * eav;
    }
    denom += __shfl_xor(denom, 32, 64);
    av0 += __shfl_xor(av0, 32, 64);
    av1 += __shfl_xor(av1, 32, 64);
    av2 += __shfl_xor(av2, 32, 64);
    av3 += __shfl_xor(av3, 32, 64);
    ae  += __shfl_xor(ae, 32, 64);
    float inv = (denom > 0.f) ? 1.f / denom : 0.f;
    float t0 = 0.f, t1 = 0.f, t2 = 0.f, t3 = 0.f;
    #pragma unroll
    for (int d = 0; d < 16; ++d) {
        float aed = __shfl(ae, d, 64);
        t0 += aed * We2[d * 128 + c];
        t1 += aed * We2[d * 128 + 32 + c];
        t2 += aed * We2[d * 128 + 64 + c];
        t3 += aed * We2[d * 128 + 96 + c];
    }
    if (half == 0) {
        float* hp = h2 + (size_t)n * 128;
        hp[c]      = (av0 + t0) * inv + base[384 + c];
        hp[32 + c] = (av1 + t1) * inv + base[416 + c];
        hp[64 + c] = (av2 + t2) * inv + base[448 + c];
        hp[96 + c] = (av3 + t3) * inv + base[480 + c];
    }
}

// ---------------------------------------------------------------------------
// pooling: sorted batch -> register-accumulated flushes
// ---------------------------------------------------------------------------
__global__ void pool_kernel(const float* __restrict__ h2, const int* __restrict__ batch,
                            float* __restrict__ sums, float* __restrict__ cnt)
{
    int t = threadIdx.x;
    int c = t & 127, half = t >> 7;
    int n0 = blockIdx.x * 64;
    float acc = 0.f, cacc = 0.f;
    int curg = -1;
    for (int r = half; r < 64; r += 2) {
        int n = n0 + r;
        if (n >= NN) break;
        int g = batch[n];
        if (g != curg) {
            if (curg >= 0) {
                atomicAdd(&sums[curg * 128 + c], acc);
                if (c == 0) atomicAdd(&cnt[curg], cacc);
            }
            curg = g; acc = 0.f; cacc = 0.f;
        }
        acc += h2[(size_t)n * 128 + c];
        cacc += 1.f;
    }
    if (curg >= 0) {
        atomicAdd(&sums[curg * 128 + c], acc);
        if (c == 0) atomicAdd(&cnt[curg], cacc);
    }
}

// Gp[g,c] = b1[c] + sum_m pool[g,m] * W1[272+m, c]
__global__ void gp_kernel(const float* __restrict__ sums, const float* __restrict__ cnt,
                          const float* __restrict__ W1, const float* __restrict__ b1,
                          float* __restrict__ Gp)
{
    __shared__ float pr[128];
    int g = blockIdx.x, c = threadIdx.x;
    float inv = 1.f / fmaxf(cnt[g], 1.f);
    pr[c] = sums[g * 128 + c] * inv;
    __syncthreads();
    float acc = b1[c];
    for (int m = 0; m < 128; ++m) acc += pr[m] * W1[(272 + m) * 128 + c];
    Gp[g * 128 + c] = acc;
}

// ---------------------------------------------------------------------------
// final: half-wave per CSR slot; 128 slots/block; W1c cached in 64 VGPRs.
// hid = A[s] + B[d] + Gp[gb] + ea@W1c; relu; dot W2
// ---------------------------------------------------------------------------
__global__ void __launch_bounds__(256, 2)
edge_out_kernel(const _Float16* __restrict__ ABh, const float* __restrict__ Gp,
                const int* __restrict__ eid, const int* __restrict__ se,
                const int* __restrict__ de, const float* __restrict__ eac,
                const int* __restrict__ gb,
                const float* __restrict__ W1, const float* __restrict__ W2,
                const float* __restrict__ b2, float* __restrict__ out)
{
    int t = threadIdx.x;
    int wv = t >> 6, l = t & 63;
    int half = l >> 5, c = l & 31;
    // register-cache the W1c column slice this lane needs (coalesced loads)
    float wr0[16], wr1[16], wr2[16], wr3[16];
    #pragma unroll
    for (int d16 = 0; d16 < 16; ++d16) {
        const float* wrow = W1 + (size_t)(256 + d16) * 128;
        wr0[d16] = wrow[c];
        wr1[d16] = wrow[32 + c];
        wr2[d16] = wrow[64 + c];
        wr3[d16] = wrow[96 + c];
    }
    float w2r0 = W2[c], w2r1 = W2[32 + c], w2r2 = W2[64 + c], w2r3 = W2[96 + c];
    float bias2 = b2[0];
    int bid = xcd_swz(blockIdx.x, gridDim.x);
    int base = bid * 128 + wv * 32;           // NE == gridDim*128 exactly
    for (int it = 0; it < 16; ++it) {
        int idx = base + it * 2 + half;
        int e = eid[idx];
        int s = se[idx], d = de[idx], g = gb[idx];
        const _Float16* As = ABh + (size_t)s * 256;
        const _Float16* Bd = ABh + (size_t)d * 256 + 128;
        const float* Gg = Gp + g * 128;
        float h0  = (float)As[c]      + (float)Bd[c]      + Gg[c];
        float h1v = (float)As[32 + c] + (float)Bd[32 + c] + Gg[32 + c];
        float h2v = (float)As[64 + c] + (float)Bd[64 + c] + Gg[64 + c];
        float h3v = (float)As[96 + c] + (float)Bd[96 + c] + Gg[96 + c];
        float eal = (c < 16) ? eac[(size_t)idx * 16 + c] : 0.f;
        int sbase = half << 5;
        #pragma unroll
        for (int d16 = 0; d16 < 16; ++d16) {
            float ev = __shfl(eal, sbase + d16, 64);
            h0  += ev * wr0[d16];
            h1v += ev * wr1[d16];
            h2v += ev * wr2[d16];
            h3v += ev * wr3[d16];
        }
        h0 = fmaxf(h0, 0.f); h1v = fmaxf(h1v, 0.f);
        h2v = fmaxf(h2v, 0.f); h3v = fmaxf(h3v, 0.f);
        float r = h0 * w2r0 + h1v * w2r1 + h2v * w2r2 + h3v * w2r3;
        r += __shfl_xor(r, 1, 64);
        r += __shfl_xor(r, 2, 64);
        r += __shfl_xor(r, 4, 64);
        r += __shfl_xor(r, 8, 64);
        r += __shfl_xor(r, 16, 64);
        if (c == 0) out[e] = r + bias2;
    }
}

// ---------------------------------------------------------------------------
extern "C" void kernel_launch(void* const* d_in, const int* in_sizes, int n_in,
                              void* d_out, int out_size, void* d_ws, size_t ws_size,
                              hipStream_t stream)
{
    const float* x   = (const float*)d_in[0];
    const int* ei    = (const int*)d_in[1];
    const float* ea  = (const float*)d_in[2];
    const int* batch = (const int*)d_in[3];
    const float* Wq1 = (const float*)d_in[4];  const float* bq1 = (const float*)d_in[5];
    const float* Wk1 = (const float*)d_in[6];  const float* bk1 = (const float*)d_in[7];
    const float* Wv1 = (const float*)d_in[8];  const float* bv1 = (const float*)d_in[9];
    const float* We1 = (const float*)d_in[10];
    const float* Ws1 = (const float*)d_in[11]; const float* bs1 = (const float*)d_in[12];
    const float* Wq2 = (const float*)d_in[13]; const float* bq2 = (const float*)d_in[14];
    const float* Wk2 = (const float*)d_in[15]; const float* bk2 = (const float*)d_in[16];
    const float* Wv2 = (const float*)d_in[17]; const float* bv2 = (const float*)d_in[18];
    const float* We2 = (const float*)d_in[19];
    const float* Ws2 = (const float*)d_in[20]; const float* bs2 = (const float*)d_in[21];
    const float* W1  = (const float*)d_in[22]; const float* b1  = (const float*)d_in[23];
    const float* W2  = (const float*)d_in[24]; const float* b2  = (const float*)d_in[25];

    const int* src = ei;
    const int* dst = ei + NE;

    float* ws = (float*)d_ws;
    size_t off = 0;
    float* OUT  = ws + off; off += (size_t)NN * 640;  // OUT1(640)/OUT2(528); ABh aliases front
    float* h1   = ws + off; off += (size_t)NN * 128;
    float* h2   = ws + off; off += (size_t)NN * 128;
    float* eac  = ws + off; off += (size_t)NE * 16;
    _Float16* KVh = (_Float16*)(ws + off); off += (size_t)NN * 128;  // N x 256 half
    float* sums = ws + off; off += NG * 128;
    float* cntf = ws + off; off += NG;
    float* Gp   = ws + off; off += NG * 128;
    float* Wp1  = ws + off; off += 64 * 128;
    float* Wp2  = ws + off; off += 128 * 16;
    float* bcat1 = ws + off; off += 640;
    float* bcat2 = ws + off; off += 528;
    __bf16* pk  = (__bf16*)(ws + off); off += 276 * 1024 / 2;  // 276 blocks x 1024 bf16
    int* cnt_arr   = (int*)(ws + off); off += NN;
    int* row_start = (int*)(ws + off); off += NN + 1;
    int* cursor    = (int*)(ws + off); off += NN;
    int* eid       = (int*)(ws + off); off += NE;
    int* se        = (int*)(ws + off); off += NE;
    int* de        = (int*)(ws + off); off += NE;
    int* gb        = (int*)(ws + off); off += NE;
    int* bsum      = (int*)(ws + off); off += 64;
    int* boff      = (int*)(ws + off); off += 64;
    _Float16* ABh = (_Float16*)OUT;   // alias: OUT dead after agg2; gemm3 writes fp16 only

    hipMemsetAsync(cnt_arr, 0, NN * sizeof(int), stream);
    hipMemsetAsync(sums, 0, (NG * 128 + NG) * sizeof(float), stream);

    prep_kernel<<<45, 256, 0, stream>>>(Wq1, bq1, bk1, bv1, bs1, We1,
                                        Wq2, bq2, bk2, bv2, bs2, We2,
                                        Wp1, Wp2, bcat1, bcat2);
    pack_kernel<<<276, 256, 0, stream>>>(Wq1, Wk1, Wv1, Ws1, Wp1,
                                         Wq2, Wk2, Wv2, Ws2, Wp2, W1, pk);
    count_kernel<<<(NE + 255) / 256, 256, 0, stream>>>(dst, cnt_arr);
    scanA_kernel<<<SCAN_B, 1024, 0, stream>>>(cnt_arr, row_start, bsum);
    scanB_kernel<<<1, 64, 0, stream>>>(bsum, boff);
    scanC_kernel<<<SCAN_B, 1024, 0, stream>>>(row_start, boff, cursor);
    scatter_kernel<<<(NE + 255) / 256, 256, 0, stream>>>(src, dst, batch, cursor,
                                                         eid, se, de, gb);
    eacopy_kernel<<<NE * 16 / 256, 256, 0, stream>>>(eid, ea, eac);

    mfma_gemm_kernel<64, 40, true, 128, 384><<<(NN + 127) / 128, 256, 0, stream>>>(
        x, pk, bcat1, OUT, 640, KVh);
    agg1_kernel<<<(NN + 3) / 4, 256, 0, stream>>>(OUT, KVh, row_start, se, eac, We1, h1);
    mfma_gemm_kernel<128, 33, true, 128, 384><<<(NN + 127) / 128, 256, 0, stream>>>(
        h1, pk + (size_t)80 * 1024, bcat2, OUT, 528, KVh);
    agg2_kernel<<<(NN + 3) / 4, 256, 0, stream>>>(OUT, KVh, row_start, se, eac, We2, h2);
    pool_kernel<<<(NN + 63) / 64, 256, 0, stream>>>(h2, batch, sums, cntf);
    gp_kernel<<<NG, 128, 0, stream>>>(sums, cntf, W1, b1, Gp);
    mfma_gemm_kernel<128, 16, false, 0, 256><<<(NN + 127) / 128, 256, 0, stream>>>(
        h2, pk + (size_t)212 * 1024, nullptr, nullptr, 0, ABh);
    edge_out_kernel<<<NE / 128, 256, 0, stream>>>(ABh, Gp, eid, se, de, eac, gb,
                                                  W1, W2, b2, (float*)d_out);
}

// Round 7
// 445.392 us; speedup vs baseline: 2.2448x; 1.0208x over previous
//
#include <hip/hip_runtime.h>
#include <math.h>

#define NN 50000
#define NE 400000
#define NG 128
#define SCAN_B 49   // ceil(NN/1024)

typedef __bf16 bf16x8 __attribute__((ext_vector_type(8)));
typedef float f32x4 __attribute__((ext_vector_type(4)));
typedef _Float16 h16x2 __attribute__((ext_vector_type(2)));
typedef _Float16 h16x4 __attribute__((ext_vector_type(4)));

// bijective XCD-chunked swizzle (m204): each XCD gets a contiguous chunk
__device__ __forceinline__ int xcd_swz(int bid, int nwg)
{
    int q = nwg >> 3, r = nwg & 7;
    int xcd = bid & 7, off = bid >> 3;
    return (xcd < r ? xcd * (q + 1) : r * (q + 1) + (xcd - r) * q) + off;
}

// ---------------------------------------------------------------------------
// prep: fused weights Wp1[64,128], Wp2[128,16]; concatenated biases
// ---------------------------------------------------------------------------
__global__ void prep_kernel(const float* __restrict__ Wq1, const float* __restrict__ bq1,
                            const float* __restrict__ bk1, const float* __restrict__ bv1,
                            const float* __restrict__ bs1, const float* __restrict__ We1,
                            const float* __restrict__ Wq2, const float* __restrict__ bq2,
                            const float* __restrict__ bk2, const float* __restrict__ bv2,
                            const float* __restrict__ bs2, const float* __restrict__ We2,
                            float* __restrict__ Wp1, float* __restrict__ Wp2,
                            float* __restrict__ bcat1, float* __restrict__ bcat2)
{
    int idx = blockIdx.x * blockDim.x + threadIdx.x;
    if (idx < 8192) {                       // Wp1[64,128]
        int m = idx >> 7, c = idx & 127;
        int h = c >> 4, d = c & 15;
        float s = 0.f;
        #pragma unroll
        for (int j = 0; j < 16; ++j)
            s += Wq1[m * 128 + h * 16 + j] * We1[d * 128 + h * 16 + j];
        Wp1[idx] = s;
    } else if (idx < 8320) {                // bp1 -> bcat1[512..640)
        int c = idx - 8192;
        int h = c >> 4, d = c & 15;
        float s = 0.f;
        #pragma unroll
        for (int j = 0; j < 16; ++j)
            s += bq1[h * 16 + j] * We1[d * 128 + h * 16 + j];
        bcat1[512 + c] = s;
    } else if (idx < 10368) {               // Wp2[128,16]
        int i = idx - 8320;
        int m = i >> 4, d = i & 15;
        float s = 0.f;
        for (int j = 0; j < 128; ++j)
            s += Wq2[m * 128 + j] * We2[d * 128 + j];
        Wp2[m * 16 + d] = s;
    } else if (idx < 10384) {               // bp2 -> bcat2[512..528)
        int d = idx - 10368;
        float s = 0.f;
        for (int j = 0; j < 128; ++j)
            s += bq2[j] * We2[d * 128 + j];
        bcat2[512 + d] = s;
    } else if (idx < 10896) {               // bcat1[0..512)
        int i = idx - 10384;
        int seg = i >> 7, c = i & 127;
        const float* b = (seg == 0) ? bq1 : (seg == 1) ? bk1 : (seg == 2) ? bv1 : bs1;
        bcat1[i] = b[c];
    } else if (idx < 11408) {               // bcat2[0..512)
        int i = idx - 10896;
        int seg = i >> 7, c = i & 127;
        const float* b = (seg == 0) ? bq2 : (seg == 1) ? bk2 : (seg == 2) ? bv2 : bs2;
        bcat2[i] = b[c];
    }
}

// ---------------------------------------------------------------------------
// pack: MFMA fragment-ready hi/lo bf16 weight blocks.
//   mat0: gemm1 Wcat[64,640]   blocks 0..79
//   mat1: gemm2 Wcat[128,528]  blocks 80..211
//   mat2: gemm3 Wcat[128,256]  blocks 212..275
//   mat3: W1c[16->32pad,128]   blocks 276..283 (for eaW GEMM)
// ---------------------------------------------------------------------------
__global__ void pack_kernel(const float* __restrict__ Wq1, const float* __restrict__ Wk1,
                            const float* __restrict__ Wv1, const float* __restrict__ Ws1,
                            const float* __restrict__ Wp1,
                            const float* __restrict__ Wq2, const float* __restrict__ Wk2,
                            const float* __restrict__ Wv2, const float* __restrict__ Ws2,
                            const float* __restrict__ Wp2,
                            const float* __restrict__ W1,
                            __bf16* __restrict__ pk)
{
    int b = blockIdx.x;
    int mat, kt, ct;
    if (b < 80)       { mat = 0; kt = b / 40;        ct = b % 40; }
    else if (b < 212) { mat = 1; kt = (b - 80) / 33; ct = (b - 80) % 33; }
    else if (b < 276) { mat = 2; kt = (b - 212) / 16; ct = (b - 212) % 16; }
    else              { mat = 3; kt = 0;             ct = b - 276; }
    __bf16* blkp = pk + (size_t)b * 1024;
    for (int item = threadIdx.x; item < 512; item += 256) {
        int lane = item >> 3, j = item & 7;
        int k = kt * 32 + (lane >> 4) * 8 + j;
        int col = ct * 16 + (lane & 15);
        float v;
        if (mat == 0) {
            int seg = col >> 7, cc = col & 127;
            const float* W = (seg == 0) ? Wq1 : (seg == 1) ? Wk1 : (seg == 2) ? Wv1
                             : (seg == 3) ? Ws1 : Wp1;
            v = W[k * 128 + cc];
        } else if (mat == 1) {
            if (col < 512) {
                int seg = col >> 7, cc = col & 127;
                const float* W = (seg == 0) ? Wq2 : (seg == 1) ? Wk2 : (seg == 2) ? Wv2 : Ws2;
                v = W[k * 128 + cc];
            } else {
                v = Wp2[k * 16 + (col - 512)];
            }
        } else if (mat == 2) {
            v = (col < 128) ? W1[k * 128 + col] : W1[(size_t)(128 + k) * 128 + (col - 128)];
        } else {
            v = (k < 16) ? W1[(size_t)(256 + k) * 128 + col] : 0.f;
        }
        __bf16 h = (__bf16)v;
        __bf16 lo = (__bf16)(v - (float)h);
        blkp[lane * 8 + j] = h;
        blkp[512 + lane * 8 + j] = lo;
    }
}

// ---------------------------------------------------------------------------
// CSR build by dst — count, 3-phase parallel scan, scatter, ea copy
// ---------------------------------------------------------------------------
__global__ void count_kernel(const int* __restrict__ dst, int* __restrict__ counts)
{
    int e = blockIdx.x * blockDim.x + threadIdx.x;
    if (e < NE) atomicAdd(&counts[dst[e]], 1);
}

__global__ void scanA_kernel(const int* __restrict__ counts,
                             int* __restrict__ row_start, int* __restrict__ bsum)
{
    __shared__ int lds[1024];
    int t = threadIdx.x, b = blockIdx.x;
    int i = b * 1024 + t;
    int v = (i < NN) ? counts[i] : 0;
    lds[t] = v;
    __syncthreads();
    for (int off = 1; off < 1024; off <<= 1) {
        int u = (t >= off) ? lds[t - off] : 0;
        __syncthreads();
        lds[t] += u;
        __syncthreads();
    }
    if (i < NN) row_start[i] = lds[t] - v;     // block-local exclusive
    if (t == 1023) bsum[b] = lds[1023];
}

__global__ void scanB_kernel(const int* __restrict__ bsum, int* __restrict__ boff)
{
    int t = threadIdx.x;  // 64 lanes
    int orig = (t < SCAN_B) ? bsum[t] : 0;
    int v = orig;
    #pragma unroll
    for (int off = 1; off < 64; off <<= 1) {
        int u = __shfl_up(v, off, 64);
        if (t >= off) v += u;
    }
    if (t < SCAN_B) boff[t] = v - orig;        // exclusive
}

__global__ void scanC_kernel(int* __restrict__ row_start, const int* __restrict__ boff,
                             int* __restrict__ cursor)
{
    int i = blockIdx.x * 1024 + threadIdx.x;
    if (i < NN) {
        int rs = row_start[i] + boff[blockIdx.x];
        row_start[i] = rs;
        cursor[i] = rs;
    }
    if (i == 0) row_start[NN] = NE;
}

__global__ void scatter_kernel(const int* __restrict__ src, const int* __restrict__ dst,
                               const int* __restrict__ batch,
                               int* __restrict__ cursor, int4* __restrict__ ed4,
                               int* __restrict__ se)
{
    int e = blockIdx.x * blockDim.x + threadIdx.x;
    if (e < NE) {
        int d = dst[e];
        int s = src[e];
        int p = atomicAdd(&cursor[d], 1);
        ed4[p] = make_int4(e, s, d, batch[s]);
        se[p] = s;
    }
}

__global__ void eacopy_kernel(const int4* __restrict__ ed4, const float* __restrict__ ea,
                              float* __restrict__ eac)
{
    int g = blockIdx.x * blockDim.x + threadIdx.x;  // NE*16 threads
    int idx = g >> 4, c = g & 15;
    eac[g] = ea[(size_t)ed4[idx].x * 16 + c];
}

// ---------------------------------------------------------------------------
// MFMA GEMM, split-bf16 3-term. Columns in [CLO,CHI) go to fp16 aux buffer
// (width CHI-CLO); other columns to fp32 out (stride ldo).
// ---------------------------------------------------------------------------
__device__ __forceinline__ void load_split(const float* ap, bool ok,
                                           bf16x8& hv, bf16x8& lv)
{
    float av[8];
    if (ok) {
        float4 f0 = *(const float4*)ap;
        float4 f1 = *(const float4*)(ap + 4);
        av[0] = f0.x; av[1] = f0.y; av[2] = f0.z; av[3] = f0.w;
        av[4] = f1.x; av[5] = f1.y; av[6] = f1.z; av[7] = f1.w;
    } else {
        #pragma unroll
        for (int j = 0; j < 8; ++j) av[j] = 0.f;
    }
    #pragma unroll
    for (int j = 0; j < 8; ++j) {
        __bf16 h = (__bf16)av[j];
        hv[j] = h;
        lv[j] = (__bf16)(av[j] - (float)h);
    }
}

template<int KD, int NCT, bool BIAS, int CLO, int CHI>
__global__ void mfma_gemm_kernel(const float* __restrict__ A, const __bf16* __restrict__ pk,
                                 const float* __restrict__ bias, float* __restrict__ out,
                                 int ldo, _Float16* __restrict__ auxh)
{
    constexpr int NKT = KD / 32;
    constexpr int AUXW = CHI - CLO;
    int t = threadIdx.x, w = t >> 6, l = t & 63;
    int rbase = blockIdx.x * 128 + w * 32;
    int lr = l & 15, kq = l >> 4;
    int r0 = rbase + lr, r1 = rbase + 16 + lr;
    bool ok0 = r0 < NN, ok1 = r1 < NN;
    bf16x8 ah0[NKT], al0[NKT], ah1[NKT], al1[NKT];
    #pragma unroll
    for (int kt = 0; kt < NKT; ++kt) {
        load_split(A + (size_t)r0 * KD + kt * 32 + kq * 8, ok0, ah0[kt], al0[kt]);
        load_split(A + (size_t)r1 * KD + kt * 32 + kq * 8, ok1, ah1[kt], al1[kt]);
    }
    for (int ct = 0; ct < NCT; ++ct) {
        float b = BIAS ? bias[ct * 16 + lr] : 0.f;
        f32x4 acc0 = {b, b, b, b};
        f32x4 acc1 = {b, b, b, b};
        const __bf16* blk = pk + (size_t)ct * 1024;
        #pragma unroll
        for (int kt = 0; kt < NKT; ++kt) {
            bf16x8 bh = *(const bf16x8*)(blk + (size_t)kt * NCT * 1024 + l * 8);
            bf16x8 bl = *(const bf16x8*)(blk + (size_t)kt * NCT * 1024 + 512 + l * 8);
            acc0 = __builtin_amdgcn_mfma_f32_16x16x32_bf16(al0[kt], bh, acc0, 0, 0, 0);
            acc1 = __builtin_amdgcn_mfma_f32_16x16x32_bf16(al1[kt], bh, acc1, 0, 0, 0);
            acc0 = __builtin_amdgcn_mfma_f32_16x16x32_bf16(ah0[kt], bl, acc0, 0, 0, 0);
            acc1 = __builtin_amdgcn_mfma_f32_16x16x32_bf16(ah1[kt], bl, acc1, 0, 0, 0);
            acc0 = __builtin_amdgcn_mfma_f32_16x16x32_bf16(ah0[kt], bh, acc0, 0, 0, 0);
            acc1 = __builtin_amdgcn_mfma_f32_16x16x32_bf16(ah1[kt], bh, acc1, 0, 0, 0);
        }
        int col = ct * 16 + lr;
        bool inAux = (col >= CLO) && (col < CHI);
        #pragma unroll
        for (int i = 0; i < 4; ++i) {
            int ra = rbase + kq * 4 + i;
            int rb = ra + 16;
            if (ra < NN) {
                if (inAux) auxh[(size_t)ra * AUXW + (col - CLO)] = (_Float16)acc0[i];
                else       out[(size_t)ra * ldo + col] = acc0[i];
            }
            if (rb < NN) {
                if (inAux) auxh[(size_t)rb * AUXW + (col - CLO)] = (_Float16)acc1[i];
                else       out[(size_t)rb * ldo + col] = acc1[i];
            }
        }
    }
}

// ---------------------------------------------------------------------------
// eaw: eaWh[E,128] = eac[E,16] @ W1c (split-bf16, K padded to 32). fp16 out.
// Wave = 32 rows; 4 waves/block -> 128 rows/block; NE/128 blocks exactly.
// ---------------------------------------------------------------------------
__global__ void eaw_kernel(const float* __restrict__ eac, const __bf16* __restrict__ pk,
                           _Float16* __restrict__ eaWh)
{
    int t = threadIdx.x, w = t >> 6, l = t & 63;
    int rbase = blockIdx.x * 128 + w * 32;
    int lr = l & 15, kq = l >> 4;
    bf16x8 ah0, al0, ah1, al1;
    if (kq < 2) {
        load_split(eac + (size_t)(rbase + lr) * 16 + kq * 8, true, ah0, al0);
        load_split(eac + (size_t)(rbase + 16 + lr) * 16 + kq * 8, true, ah1, al1);
    } else {
        #pragma unroll
        for (int j = 0; j < 8; ++j) { ah0[j] = (__bf16)0.f; al0[j] = (__bf16)0.f;
                                      ah1[j] = (__bf16)0.f; al1[j] = (__bf16)0.f; }
    }
    #pragma unroll
    for (int ct = 0; ct < 8; ++ct) {
        f32x4 acc0 = {0.f, 0.f, 0.f, 0.f};
        f32x4 acc1 = {0.f, 0.f, 0.f, 0.f};
        const __bf16* blk = pk + (size_t)ct * 1024;
        bf16x8 bh = *(const bf16x8*)(blk + l * 8);
        bf16x8 bl = *(const bf16x8*)(blk + 512 + l * 8);
        acc0 = __builtin_amdgcn_mfma_f32_16x16x32_bf16(al0, bh, acc0, 0, 0, 0);
        acc1 = __builtin_amdgcn_mfma_f32_16x16x32_bf16(al1, bh, acc1, 0, 0, 0);
        acc0 = __builtin_amdgcn_mfma_f32_16x16x32_bf16(ah0, bl, acc0, 0, 0, 0);
        acc1 = __builtin_amdgcn_mfma_f32_16x16x32_bf16(ah1, bl, acc1, 0, 0, 0);
        acc0 = __builtin_amdgcn_mfma_f32_16x16x32_bf16(ah0, bh, acc0, 0, 0, 0);
        acc1 = __builtin_amdgcn_mfma_f32_16x16x32_bf16(ah1, bh, acc1, 0, 0, 0);
        int col = ct * 16 + lr;
        #pragma unroll
        for (int i = 0; i < 4; ++i) {
            int ra = rbase + kq * 4 + i;
            eaWh[(size_t)ra * 128 + col] = (_Float16)acc0[i];
            eaWh[(size_t)(ra + 16) * 128 + col] = (_Float16)acc1[i];
        }
    }
}

// ---------------------------------------------------------------------------
// agg1: wave per node. f32 OUT1 row [Q|-|-|S|P] stride 640; fp16 KVh [K|V] 256.
// lane = h*8 + p; lane owns j = 2p, 2p+1 of head h. 2-way edge unroll.
// ---------------------------------------------------------------------------
__global__ void agg1_kernel(const float* __restrict__ OUT1, const _Float16* __restrict__ KVh,
                            const int* __restrict__ row_start,
                            const int* __restrict__ se, const float* __restrict__ eac,
                            const float* __restrict__ We1, float* __restrict__ h1)
{
    __shared__ float we[16 * 128];
    int t = threadIdx.x;
    for (int i = t; i < 2048; i += 256) we[i] = We1[i];
    __syncthreads();
    int bid = xcd_swz(blockIdx.x, gridDim.x);
    int wv = t >> 6, l = t & 63;
    int n = bid * 4 + wv;
    if (n >= NN) return;
    int h = l >> 3, p = l & 7;
    int j0 = p * 2;
    const float* qb = OUT1 + (size_t)n * 640;
    float2 q = *(const float2*)(qb + h * 16 + j0);
    float2 P = *(const float2*)(qb + 512 + h * 16 + j0);
    float2 accv = make_float2(0.f, 0.f), acce = make_float2(0.f, 0.f);
    float denom = 0.f;
    int e0 = row_start[n], e1 = row_start[n + 1];
    int idx = e0;
    for (; idx + 1 < e1; idx += 2) {
        int sA = se[idx], sB = se[idx + 1];
        const _Float16* kvA = KVh + (size_t)sA * 256;
        const _Float16* kvB = KVh + (size_t)sB * 256;
        h16x2 kAh = *(const h16x2*)(kvA + h * 16 + j0);
        h16x2 vAh = *(const h16x2*)(kvA + 128 + h * 16 + j0);
        float2 eA = *(const float2*)(eac + (size_t)idx * 16 + j0);
        h16x2 kBh = *(const h16x2*)(kvB + h * 16 + j0);
        h16x2 vBh = *(const h16x2*)(kvB + 128 + h * 16 + j0);
        float2 eB = *(const float2*)(eac + (size_t)(idx + 1) * 16 + j0);
        float pa = q.x * (float)kAh[0] + q.y * (float)kAh[1] + P.x * eA.x + P.y * eA.y;
        float pb = q.x * (float)kBh[0] + q.y * (float)kBh[1] + P.x * eB.x + P.y * eB.y;
        pa += __shfl_xor(pa, 1, 64); pb += __shfl_xor(pb, 1, 64);
        pa += __shfl_xor(pa, 2, 64); pb += __shfl_xor(pb, 2, 64);
        pa += __shfl_xor(pa, 4, 64); pb += __shfl_xor(pb, 4, 64);
        float wA = __expf(pa * 0.25f);
        float wB = __expf(pb * 0.25f);
        denom += wA + wB;
        accv.x += wA * (float)vAh[0] + wB * (float)vBh[0];
        accv.y += wA * (float)vAh[1] + wB * (float)vBh[1];
        acce.x += wA * eA.x + wB * eB.x;
        acce.y += wA * eA.y + wB * eB.y;
    }
    if (idx < e1) {
        int s = se[idx];
        const _Float16* kvb = KVh + (size_t)s * 256;
        h16x2 kk = *(const h16x2*)(kvb + h * 16 + j0);
        h16x2 vv = *(const h16x2*)(kvb + 128 + h * 16 + j0);
        float2 ee = *(const float2*)(eac + (size_t)idx * 16 + j0);
        float part = q.x * (float)kk[0] + q.y * (float)kk[1] + P.x * ee.x + P.y * ee.y;
        part += __shfl_xor(part, 1, 64);
        part += __shfl_xor(part, 2, 64);
        part += __shfl_xor(part, 4, 64);
        float w = __expf(part * 0.25f);
        denom += w;
        accv.x += w * (float)vv[0]; accv.y += w * (float)vv[1];
        acce.x += w * ee.x; acce.y += w * ee.y;
    }
    float inv = (denom > 0.f) ? 1.f / denom : 0.f;
    float es0 = 0.f, es1 = 0.f;
    int gbase = h * 8;
    #pragma unroll
    for (int dd = 0; dd < 8; ++dd) {
        float a0 = __shfl(acce.x, gbase + dd, 64);
        float a1 = __shfl(acce.y, gbase + dd, 64);
        es0 += a0 * we[(2 * dd) * 128 + h * 16 + j0]     + a1 * we[(2 * dd + 1) * 128 + h * 16 + j0];
        es1 += a0 * we[(2 * dd) * 128 + h * 16 + j0 + 1] + a1 * we[(2 * dd + 1) * 128 + h * 16 + j0 + 1];
    }
    float2 sk = *(const float2*)(qb + 384 + h * 16 + j0);
    float o0 = (accv.x + es0) * inv + sk.x;
    float o1 = (accv.y + es1) * inv + sk.y;
    o0 = (o0 > 0.f) ? o0 : 0.01f * o0;
    o1 = (o1 > 0.f) ? o1 : 0.01f * o1;
    *(float2*)(h1 + (size_t)n * 128 + h * 16 + j0) = make_float2(o0, o1);
}

// ---------------------------------------------------------------------------
// agg2: wave per node, half-wave per edge. f32 OUT2 [Q|-|-|S|P2] stride 528;
// fp16 KVh [K|V] 256. lane = half*32 + c; lane owns dims {c,c+32,c+64,c+96}.
// ---------------------------------------------------------------------------
__global__ void agg2_kernel(const float* __restrict__ OUT2, const _Float16* __restrict__ KVh,
                            const int* __restrict__ row_start,
                            const int* __restrict__ se, const float* __restrict__ eac,
                            const float* __restrict__ We2, float* __restrict__ h2)
{
    int bid = xcd_swz(blockIdx.x, gridDim.x);
    int t = threadIdx.x;
    int wv = t >> 6, l = t & 63;
    int n = bid * 4 + wv;
    if (n >= NN) return;
    int half = l >> 5, c = l & 31;
    const float* base = OUT2 + (size_t)n * 528;
    float q0 = base[c], q1 = base[32 + c], q2 = base[64 + c], q3 = base[96 + c];
    float p2 = (c < 16) ? base[512 + c] : 0.f;
    float av0 = 0.f, av1 = 0.f, av2 = 0.f, av3 = 0.f, ae = 0.f, denom = 0.f;
    int e0 = row_start[n], e1 = row_start[n + 1];
    for (int idx = e0 + half; idx < e1; idx += 2) {
        int s = se[idx];
        const _Float16* kb = KVh + (size_t)s * 256;
        float k0 = (float)kb[c], k1 = (float)kb[32 + c];
        float k2 = (float)kb[64 + c], k3 = (float)kb[96 + c];
        float v0 = (float)kb[128 + c], v1 = (float)kb[160 + c];
        float v2 = (float)kb[192 + c], v3 = (float)kb[224 + c];
        float eav = (c < 16) ? eac[(size_t)idx * 16 + c] : 0.f;
        float part = q0 * k0 + q1 * k1 + q2 * k2 + q3 * k3 + p2 * eav;
        part += __shfl_xor(part, 1, 64);
        part += __shfl_xor(part, 2, 64);
        part += __shfl_xor(part, 4, 64);
        part += __shfl_xor(part, 8, 64);
        part += __shfl_xor(part, 16, 64);
        float w = __expf(part * 0.08838834764831845f);  // 1/sqrt(128)
        denom += w;
        av0 += w * v0; av1 += w * v1; av2 += w * v2; av3 += w * v3;
        ae += w * eav;
    }
    denom += __shfl_xor(denom, 32, 64);
    av0 += __shfl_xor(av0, 32, 64);
    av1 += __shfl_xor(av1, 32, 64);
    av2 += __shfl_xor(av2, 32, 64);
    av3 += __shfl_xor(av3, 32, 64);
    ae  += __shfl_xor(ae, 32, 64);
    float inv = (denom > 0.f) ? 1.f / denom : 0.f;
    float t0 = 0.f, t1 = 0.f, t2 = 0.f, t3 = 0.f;
    #pragma unroll
    for (int d = 0; d < 16; ++d) {
        float aed = __shfl(ae, d, 64);
        t0 += aed * We2[d * 128 + c];
        t1 += aed * We2[d * 128 + 32 + c];
        t2 += aed * We2[d * 128 + 64 + c];
        t3 += aed * We2[d * 128 + 96 + c];
    }
    if (half == 0) {
        float* hp = h2 + (size_t)n * 128;
        hp[c]      = (av0 + t0) * inv + base[384 + c];
        hp[32 + c] = (av1 + t1) * inv + base[416 + c];
        hp[64 + c] = (av2 + t2) * inv + base[448 + c];
        hp[96 + c] = (av3 + t3) * inv + base[480 + c];
    }
}

// ---------------------------------------------------------------------------
// pooling: sorted batch -> register-accumulated flushes
// ---------------------------------------------------------------------------
__global__ void pool_kernel(const float* __restrict__ h2, const int* __restrict__ batch,
                            float* __restrict__ sums, float* __restrict__ cnt)
{
    int t = threadIdx.x;
    int c = t & 127, half = t >> 7;
    int n0 = blockIdx.x * 64;
    float acc = 0.f, cacc = 0.f;
    int curg = -1;
    for (int r = half; r < 64; r += 2) {
        int n = n0 + r;
        if (n >= NN) break;
        int g = batch[n];
        if (g != curg) {
            if (curg >= 0) {
                atomicAdd(&sums[curg * 128 + c], acc);
                if (c == 0) atomicAdd(&cnt[curg], cacc);
            }
            curg = g; acc = 0.f; cacc = 0.f;
        }
        acc += h2[(size_t)n * 128 + c];
        cacc += 1.f;
    }
    if (curg >= 0) {
        atomicAdd(&sums[curg * 128 + c], acc);
        if (c == 0) atomicAdd(&cnt[curg], cacc);
    }
}

// Gp[g,c] = b1[c] + sum_m pool[g,m] * W1[272+m, c]
__global__ void gp_kernel(const float* __restrict__ sums, const float* __restrict__ cnt,
                          const float* __restrict__ W1, const float* __restrict__ b1,
                          float* __restrict__ Gp)
{
    __shared__ float pr[128];
    int g = blockIdx.x, c = threadIdx.x;
    float inv = 1.f / fmaxf(cnt[g], 1.f);
    pr[c] = sums[g * 128 + c] * inv;
    __syncthreads();
    float acc = b1[c];
    for (int m = 0; m < 128; ++m) acc += pr[m] * W1[(272 + m) * 128 + c];
    Gp[g * 128 + c] = acc;
}

// ---------------------------------------------------------------------------
// final: half-wave per CSR slot; lane owns 4 CONTIGUOUS cols [4c,4c+4).
// hid = A[s] + B[d] + Gp[g] + eaW[idx]; relu; dot W2. Pure gather+add.
// ---------------------------------------------------------------------------
__global__ void edge_out_kernel(const _Float16* __restrict__ ABh, const float* __restrict__ Gp,
                                const int4* __restrict__ ed4, const _Float16* __restrict__ eaWh,
                                const float* __restrict__ W2, const float* __restrict__ b2,
                                float* __restrict__ out)
{
    int t = threadIdx.x;
    int wv = t >> 6, l = t & 63;
    int half = l >> 5, c = l & 31;
    float4 w2r = *(const float4*)(W2 + 4 * c);
    float bias2 = b2[0];
    int bid = xcd_swz(blockIdx.x, gridDim.x);
    int base = bid * 128 + wv * 32;            // NE == gridDim*128 exactly
    for (int it = 0; it < 16; ++it) {
        int idx = base + it * 2 + half;
        int4 q4 = ed4[idx];
        int e = q4.x, s = q4.y, d = q4.z, g = q4.w;
        h16x4 As = *(const h16x4*)(ABh + (size_t)s * 256 + 4 * c);
        h16x4 Bd = *(const h16x4*)(ABh + (size_t)d * 256 + 128 + 4 * c);
        h16x4 ew = *(const h16x4*)(eaWh + (size_t)idx * 128 + 4 * c);
        float4 Gg = *(const float4*)(Gp + g * 128 + 4 * c);
        float h0 = fmaxf((float)As[0] + (float)Bd[0] + Gg.x + (float)ew[0], 0.f);
        float h1 = fmaxf((float)As[1] + (float)Bd[1] + Gg.y + (float)ew[1], 0.f);
        float h2 = fmaxf((float)As[2] + (float)Bd[2] + Gg.z + (float)ew[2], 0.f);
        float h3 = fmaxf((float)As[3] + (float)Bd[3] + Gg.w + (float)ew[3], 0.f);
        float r = h0 * w2r.x + h1 * w2r.y + h2 * w2r.z + h3 * w2r.w;
        r += __shfl_xor(r, 1, 64);
        r += __shfl_xor(r, 2, 64);
        r += __shfl_xor(r, 4, 64);
        r += __shfl_xor(r, 8, 64);
        r += __shfl_xor(r, 16, 64);
        if (c == 0) out[e] = r + bias2;
    }
}

// ---------------------------------------------------------------------------
extern "C" void kernel_launch(void* const* d_in, const int* in_sizes, int n_in,
                              void* d_out, int out_size, void* d_ws, size_t ws_size,
                              hipStream_t stream)
{
    const float* x   = (const float*)d_in[0];
    const int* ei    = (const int*)d_in[1];
    const float* ea  = (const float*)d_in[2];
    const int* batch = (const int*)d_in[3];
    const float* Wq1 = (const float*)d_in[4];  const float* bq1 = (const float*)d_in[5];
    const float* Wk1 = (const float*)d_in[6];  const float* bk1 = (const float*)d_in[7];
    const float* Wv1 = (const float*)d_in[8];  const float* bv1 = (const float*)d_in[9];
    const float* We1 = (const float*)d_in[10];
    const float* Ws1 = (const float*)d_in[11]; const float* bs1 = (const float*)d_in[12];
    const float* Wq2 = (const float*)d_in[13]; const float* bq2 = (const float*)d_in[14];
    const float* Wk2 = (const float*)d_in[15]; const float* bk2 = (const float*)d_in[16];
    const float* Wv2 = (const float*)d_in[17]; const float* bv2 = (const float*)d_in[18];
    const float* We2 = (const float*)d_in[19];
    const float* Ws2 = (const float*)d_in[20]; const float* bs2 = (const float*)d_in[21];
    const float* W1  = (const float*)d_in[22]; const float* b1  = (const float*)d_in[23];
    const float* W2  = (const float*)d_in[24]; const float* b2  = (const float*)d_in[25];

    const int* src = ei;
    const int* dst = ei + NE;

    float* ws = (float*)d_ws;
    size_t off = 0;
    float* OUT  = ws + off; off += (size_t)NN * 640;  // OUT1/OUT2; later ABh + eaWh (exact fit)
    float* h1   = ws + off; off += (size_t)NN * 128;
    float* h2   = ws + off; off += (size_t)NN * 128;
    float* eac  = ws + off; off += (size_t)NE * 16;
    _Float16* KVh = (_Float16*)(ws + off); off += (size_t)NN * 128;  // N x 256 half
    float* sums = ws + off; off += NG * 128;
    float* cntf = ws + off; off += NG;
    float* Gp   = ws + off; off += NG * 128;
    float* Wp1  = ws + off; off += 64 * 128;
    float* Wp2  = ws + off; off += 128 * 16;
    float* bcat1 = ws + off; off += 640;
    float* bcat2 = ws + off; off += 528;
    __bf16* pk  = (__bf16*)(ws + off); off += 284 * 1024 / 2;  // 284 blocks x 1024 bf16
    int* cnt_arr   = (int*)(ws + off); off += NN;
    int* row_start = (int*)(ws + off); off += NN + 1;
    int* cursor    = (int*)(ws + off); off += NN;
    int* se        = (int*)(ws + off); off += NE;
    int* bsum      = (int*)(ws + off); off += 64;
    int* boff      = (int*)(ws + off); off += 64;
    off = (off + 3) & ~(size_t)3;                      // 16B align for int4
    int4* ed4      = (int4*)(ws + off); off += (size_t)NE * 4;
    // alias: after agg2, OUT region = ABh (NN*256 half) ++ eaWh (NE*128 half) = NN*640 floats
    _Float16* ABh  = (_Float16*)OUT;
    _Float16* eaWh = (_Float16*)(OUT + (size_t)NN * 128);

    hipMemsetAsync(cnt_arr, 0, NN * sizeof(int), stream);
    hipMemsetAsync(sums, 0, (NG * 128 + NG) * sizeof(float), stream);

    prep_kernel<<<45, 256, 0, stream>>>(Wq1, bq1, bk1, bv1, bs1, We1,
                                        Wq2, bq2, bk2, bv2, bs2, We2,
                                        Wp1, Wp2, bcat1, bcat2);
    pack_kernel<<<284, 256, 0, stream>>>(Wq1, Wk1, Wv1, Ws1, Wp1,
                                         Wq2, Wk2, Wv2, Ws2, Wp2, W1, pk);
    count_kernel<<<(NE + 255) / 256, 256, 0, stream>>>(dst, cnt_arr);
    scanA_kernel<<<SCAN_B, 1024, 0, stream>>>(cnt_arr, row_start, bsum);
    scanB_kernel<<<1, 64, 0, stream>>>(bsum, boff);
    scanC_kernel<<<SCAN_B, 1024, 0, stream>>>(row_start, boff, cursor);
    scatter_kernel<<<(NE + 255) / 256, 256, 0, stream>>>(src, dst, batch, cursor, ed4, se);
    eacopy_kernel<<<NE * 16 / 256, 256, 0, stream>>>(ed4, ea, eac);

    mfma_gemm_kernel<64, 40, true, 128, 384><<<(NN + 127) / 128, 256, 0, stream>>>(
        x, pk, bcat1, OUT, 640, KVh);
    agg1_kernel<<<(NN + 3) / 4, 256, 0, stream>>>(OUT, KVh, row_start, se, eac, We1, h1);
    mfma_gemm_kernel<128, 33, true, 128, 384><<<(NN + 127) / 128, 256, 0, stream>>>(
        h1, pk + (size_t)80 * 1024, bcat2, OUT, 528, KVh);
    agg2_kernel<<<(NN + 3) / 4, 256, 0, stream>>>(OUT, KVh, row_start, se, eac, We2, h2);
    pool_kernel<<<(NN + 63) / 64, 256, 0, stream>>>(h2, batch, sums, cntf);
    gp_kernel<<<NG, 128, 0, stream>>>(sums, cntf, W1, b1, Gp);
    mfma_gemm_kernel<128, 16, false, 0, 256><<<(NN + 127) / 128, 256, 0, stream>>>(
        h2, pk + (size_t)212 * 1024, nullptr, nullptr, 0, ABh);
    eaw_kernel<<<NE / 128, 256, 0, stream>>>(eac, pk + (size_t)276 * 1024, eaWh);
    edge_out_kernel<<<NE / 128, 256, 0, stream>>>(ABh, Gp, ed4, eaWh,
                                                  W2, b2, (float*)d_out);
}